// Round 13
// baseline (656.687 us; speedup 1.0000x reference)
//
#include <hip/hip_runtime.h>

// ---------------------------------------------------------------------------
// FullModelSnowflake.  R12: attention KSP 4->8 — grid 512->1024 blocks so the
// 8192 wave slots actually fill (grid was the occupancy cap at 36.6%).
// Each wave scans 16 keys; attn_fin_ln merges 8 partials.
// ---------------------------------------------------------------------------

#define B_ 2
#define N_ 1024
#define D_ 128
#define H_ 8
#define DK_ 16
#define L_ 4
#define KG_ 16
#define KLOC_ 8
#define COARSE_ 512
#define NCH_ 16          // candidate chunks (64 candidates each)
#define AW_ 8            // waves per attention block
#define KSP_ 8           // block-level key splits
#define PREC_ 17         // floats per attention partial (sum + 16 acc)
#define MQ_ 16           // queries per merge block

static __device__ __forceinline__ float wave_sum(float v) {
    #pragma unroll
    for (int off = 32; off > 0; off >>= 1) v += __shfl_xor(v, off);
    return v;
}
static __device__ __forceinline__ float half_sum(float v) {
    #pragma unroll
    for (int off = 16; off > 0; off >>= 1) v += __shfl_xor(v, off);
    return v;
}

// ---------------- LDS-staged GEMM body: returns this thread's acc ----------
template <int CIN, bool RELU, bool BIAS_HALF>
static __device__ __forceinline__ float4 gemm_body(
        const float* __restrict__ X, const float* __restrict__ W,
        const float* __restrict__ bias, int wstride, int col0) {
    __shared__ float Xs[8 * CIN];
    __shared__ float Ws[64][128];
    int tid = threadIdx.x;
    int row0 = blockIdx.x * 8;
    constexpr int NX4 = 2 * CIN;
    {
        const float4* xg = (const float4*)(X + (size_t)row0 * CIN);
        float4* xs4 = (float4*)Xs;
        #pragma unroll
        for (int i = 0; i < (NX4 + 255) / 256; ++i) {
            int t = tid + i * 256;
            if ((NX4 % 256 == 0) || t < NX4) xs4[t] = xg[t];
        }
    }
    int col4 = (tid & 31) << 2;
    int rowl = tid >> 5;
    float4 acc;
    if (BIAS_HALF) {
        acc.x = bias[(col0 + col4) >> 1];
        acc.y = bias[(col0 + col4 + 1) >> 1];
        acc.z = bias[(col0 + col4 + 2) >> 1];
        acc.w = bias[(col0 + col4 + 3) >> 1];
    } else {
        acc = *(const float4*)(bias + col0 + col4);
    }
    for (int c0 = 0; c0 < CIN; c0 += 64) {
        __syncthreads();
        #pragma unroll
        for (int i = 0; i < 8; ++i) {
            int flat = tid + i * 256;
            int wr = flat >> 5, wc = (flat & 31) << 2;
            *(float4*)&Ws[wr][wc] =
                *(const float4*)(W + (size_t)(c0 + wr) * wstride + col0 + wc);
        }
        __syncthreads();
        const float* xrow = Xs + rowl * CIN + c0;
        #pragma unroll
        for (int c = 0; c < 64; ++c) {
            float xv = xrow[c];
            float4 w = *(const float4*)&Ws[c][col4];
            acc.x += xv * w.x; acc.y += xv * w.y;
            acc.z += xv * w.z; acc.w += xv * w.w;
        }
    }
    if (RELU) {
        acc.x = fmaxf(acc.x, 0.f); acc.y = fmaxf(acc.y, 0.f);
        acc.z = fmaxf(acc.z, 0.f); acc.w = fmaxf(acc.w, 0.f);
    }
    return acc;
}

template <int CIN, bool RELU, bool BIAS_HALF>
__global__ __launch_bounds__(256) void gemm128_kernel(
        const float* __restrict__ X, const float* __restrict__ W,
        const float* __restrict__ bias, float* __restrict__ Y,
        int wstride, int ystride) {
    int col0 = blockIdx.y * 128;
    float4 acc = gemm_body<CIN, RELU, BIAS_HALF>(X, W, bias, wstride, col0);
    int col4 = (threadIdx.x & 31) << 2;
    int row = blockIdx.x * 8 + (threadIdx.x >> 5);
    *(float4*)(Y + (size_t)row * ystride + col0 + col4) = acc;
}

// GEMM (Cout=128) fused with residual-add + LayerNorm epilogue.
template <int CIN>
__global__ __launch_bounds__(256) void gemm_ln_kernel(
        const float* __restrict__ X, const float* __restrict__ W,
        const float* __restrict__ bias, const float* __restrict__ res,
        const float* __restrict__ g, const float* __restrict__ bt,
        float* __restrict__ Y) {
    float4 acc = gemm_body<CIN, false, false>(X, W, bias, 128, 0);
    int col4 = (threadIdx.x & 31) << 2;
    int row = blockIdx.x * 8 + (threadIdx.x >> 5);
    float4 r = *(const float4*)(res + (size_t)row * D_ + col4);
    acc.x += r.x; acc.y += r.y; acc.z += r.z; acc.w += r.w;
    float mean = half_sum(acc.x + acc.y + acc.z + acc.w) * (1.0f / D_);
    float dx = acc.x - mean, dy = acc.y - mean, dz = acc.z - mean, dw = acc.w - mean;
    float var = half_sum(dx * dx + dy * dy + dz * dz + dw * dw) * (1.0f / D_);
    float rstd = rsqrtf(var + 1e-5f);
    float4 gv = *(const float4*)(g + col4);
    float4 bv = *(const float4*)(bt + col4);
    float4 o;
    o.x = dx * rstd * gv.x + bv.x;
    o.y = dy * rstd * gv.y + bv.y;
    o.z = dz * rstd * gv.z + bv.z;
    o.w = dw * rstd * gv.w + bv.w;
    *(float4*)(Y + (size_t)row * D_ + col4) = o;
}

// fused QKV: 3 W-panels via blockIdx.y
__global__ __launch_bounds__(256) void qkv3_kernel(
        const float* __restrict__ X,
        const float* __restrict__ Wq, const float* __restrict__ bq,
        const float* __restrict__ Wk, const float* __restrict__ bk,
        const float* __restrict__ Wv, const float* __restrict__ bv,
        float* __restrict__ Q, float* __restrict__ K, float* __restrict__ V) {
    const float* W; const float* bias; float* Y;
    if (blockIdx.y == 0)      { W = Wq; bias = bq; Y = Q; }
    else if (blockIdx.y == 1) { W = Wk; bias = bk; Y = K; }
    else                      { W = Wv; bias = bv; Y = V; }
    float4 acc = gemm_body<128, false, false>(X, W, bias, 128, 0);
    int col4 = (threadIdx.x & 31) << 2;
    int row = blockIdx.x * 8 + (threadIdx.x >> 5);
    *(float4*)(Y + (size_t)row * 128 + col4) = acc;
}

// ---------------- KNN pass 1: per-chunk partial top-16 ---------------------
__global__ void knn_part_kernel(const float* __restrict__ coords,
                                float* __restrict__ pd, int* __restrict__ pi) {
    int blk = blockIdx.x;
    int qb = blk & 15;
    int ch = (blk >> 4) & 15;
    int b = blk >> 8;
    int lane = threadIdx.x;
    int q = qb * 64 + lane;
    __shared__ float4 sc[64];
    const float* cb = coords + (size_t)b * N_ * 3;
    {
        int m = ch * 64 + lane;
        float x = cb[m * 3], y = cb[m * 3 + 1], z = cb[m * 3 + 2];
        sc[lane] = make_float4(x, y, z, x * x + y * y + z * z);
    }
    __syncthreads();
    float qx = cb[q * 3], qy = cb[q * 3 + 1], qz = cb[q * 3 + 2];
    float q2 = qx * qx + qy * qy + qz * qz;
    float bd[KG_]; int bi[KG_];
    #pragma unroll
    for (int j = 0; j < KG_; ++j) { bd[j] = 3e38f; bi[j] = 0; }
    for (int j = 0; j < 64; ++j) {
        int m = ch * 64 + j;
        float4 c = sc[j];
        float dot = qx * c.x + qy * c.y + qz * c.z;
        float d = (q2 - 2.0f * dot) + c.w;
        d = (m == q) ? 3e38f : d;
        if (d < bd[KG_ - 1]) {
            #pragma unroll
            for (int jj = KG_ - 1; jj > 0; --jj) {
                bool shf = d < bd[jj - 1];
                bool plc = !shf && (d < bd[jj]);
                bd[jj] = shf ? bd[jj - 1] : (plc ? d : bd[jj]);
                bi[jj] = shf ? bi[jj - 1] : (plc ? m : bi[jj]);
            }
            if (d < bd[0]) { bd[0] = d; bi[0] = m; }
        }
    }
    size_t base = (((size_t)b * N_ + q) * NCH_ + ch) * KG_;
    #pragma unroll
    for (int j = 0; j < KG_; ++j) { pd[base + j] = bd[j]; pi[base + j] = bi[j]; }
}

// ---------------- KNN pass 2: LDS-staged merge of 16 sorted lists ----------
__global__ __launch_bounds__(256) void knn_merge_kernel(
        const float* __restrict__ pd, const int* __restrict__ pi,
        int* __restrict__ knn) {
    __shared__ float sd[MQ_][NCH_ * KG_ + 1];
    __shared__ int   si[MQ_][NCH_ * KG_ + 1];
    size_t qg0 = (size_t)blockIdx.x * MQ_;
    size_t base = qg0 * NCH_ * KG_;
    for (int i = threadIdx.x; i < MQ_ * NCH_ * KG_; i += 256) {
        int r = i >> 8, cix = i & 255;
        sd[r][cix] = pd[base + i];
        si[r][cix] = pi[base + i];
    }
    __syncthreads();
    int t = threadIdx.x;
    if (t < MQ_) {
        const float* cd0 = sd[t];
        const int* ci0 = si[t];
        float bd[KG_]; int bi[KG_];
        #pragma unroll
        for (int j = 0; j < KG_; ++j) { bd[j] = 3e38f; bi[j] = 0; }
        for (int ch = 0; ch < NCH_; ++ch) {
            for (int e = 0; e < KG_; ++e) {
                float d = cd0[ch * KG_ + e];
                if (d >= bd[KG_ - 1]) break;
                int m = ci0[ch * KG_ + e];
                #pragma unroll
                for (int jj = KG_ - 1; jj > 0; --jj) {
                    bool shf = d < bd[jj - 1];
                    bool plc = !shf && (d < bd[jj]);
                    bd[jj] = shf ? bd[jj - 1] : (plc ? d : bd[jj]);
                    bi[jj] = shf ? bi[jj - 1] : (plc ? m : bi[jj]);
                }
                if (d < bd[0]) { bd[0] = d; bi[0] = m; }
            }
        }
        int* o = knn + (qg0 + t) * KG_;
        #pragma unroll
        for (int j = 0; j < KG_; ++j) o[j] = bi[j];
    }
}

// ---------------- local KNN pass 1 (k=8) -----------------------------------
__global__ void loc_part_kernel(const float* __restrict__ part,
                                const float* __restrict__ pred,
                                float* __restrict__ pd, int* __restrict__ pi,
                                int Nq) {
    int qb = blockIdx.x, ch = blockIdx.y, b = blockIdx.z;
    int lane = threadIdx.x;
    int q = qb * 64 + lane;
    __shared__ float4 sc[64];
    const float* pb = part + (size_t)b * N_ * 3;
    {
        int m = ch * 64 + lane;
        float x = pb[m * 3], y = pb[m * 3 + 1], z = pb[m * 3 + 2];
        sc[lane] = make_float4(x, y, z, x * x + y * y + z * z);
    }
    __syncthreads();
    const float* pr = pred + ((size_t)b * Nq + q) * 3;
    float qx = pr[0], qy = pr[1], qz = pr[2];
    float q2 = qx * qx + qy * qy + qz * qz;
    float bd[KLOC_]; int bi[KLOC_];
    #pragma unroll
    for (int j = 0; j < KLOC_; ++j) { bd[j] = 3e38f; bi[j] = 0; }
    for (int j = 0; j < 64; ++j) {
        float4 c = sc[j];
        float dot = qx * c.x + qy * c.y + qz * c.z;
        float d = (q2 - 2.0f * dot) + c.w;
        if (d < bd[KLOC_ - 1]) {
            int m = ch * 64 + j;
            #pragma unroll
            for (int jj = KLOC_ - 1; jj > 0; --jj) {
                bool shf = d < bd[jj - 1];
                bool plc = !shf && (d < bd[jj]);
                bd[jj] = shf ? bd[jj - 1] : (plc ? d : bd[jj]);
                bi[jj] = shf ? bi[jj - 1] : (plc ? m : bi[jj]);
            }
            if (d < bd[0]) { bd[0] = d; bi[0] = m; }
        }
    }
    size_t base = (((size_t)b * Nq + q) * NCH_ + ch) * KLOC_;
    #pragma unroll
    for (int j = 0; j < KLOC_; ++j) { pd[base + j] = bd[j]; pi[base + j] = bi[j]; }
}

// ---------------- local KNN pass 2: LDS-staged merge + mean + comb ---------
__global__ __launch_bounds__(256) void loc_merge_kernel(
        const float* __restrict__ part, const float* __restrict__ pred,
        const float* __restrict__ pd, const int* __restrict__ pi,
        float* __restrict__ comb, int Nq) {
    __shared__ float sd[MQ_][NCH_ * KLOC_ + 1];
    __shared__ int   si[MQ_][NCH_ * KLOC_ + 1];
    size_t qg0 = (size_t)blockIdx.x * MQ_;
    size_t base = qg0 * NCH_ * KLOC_;
    for (int i = threadIdx.x; i < MQ_ * NCH_ * KLOC_; i += 256) {
        int r = i >> 7, cix = i & 127;
        sd[r][cix] = pd[base + i];
        si[r][cix] = pi[base + i];
    }
    __syncthreads();
    int t = threadIdx.x;
    if (t < MQ_) {
        const float* cd0 = sd[t];
        const int* ci0 = si[t];
        float bd[KLOC_]; int bi[KLOC_];
        #pragma unroll
        for (int j = 0; j < KLOC_; ++j) { bd[j] = 3e38f; bi[j] = 0; }
        for (int ch = 0; ch < NCH_; ++ch) {
            for (int e = 0; e < KLOC_; ++e) {
                float d = cd0[ch * KLOC_ + e];
                if (d >= bd[KLOC_ - 1]) break;
                int m = ci0[ch * KLOC_ + e];
                #pragma unroll
                for (int jj = KLOC_ - 1; jj > 0; --jj) {
                    bool shf = d < bd[jj - 1];
                    bool plc = !shf && (d < bd[jj]);
                    bd[jj] = shf ? bd[jj - 1] : (plc ? d : bd[jj]);
                    bi[jj] = shf ? bi[jj - 1] : (plc ? m : bi[jj]);
                }
                if (d < bd[0]) { bd[0] = d; bi[0] = m; }
            }
        }
        size_t qg = qg0 + t;
        int b = (int)(qg / Nq);
        const float* pb = part + (size_t)b * N_ * 3;
        float sx = 0.f, sy = 0.f, sz = 0.f;
        #pragma unroll
        for (int j = 0; j < KLOC_; ++j) {
            int m = bi[j];
            sx += pb[m * 3]; sy += pb[m * 3 + 1]; sz += pb[m * 3 + 2];
        }
        const float* pr = pred + qg * 3;
        float* o = comb + qg * 6;
        o[0] = pr[0]; o[1] = pr[1]; o[2] = pr[2];
        o[3] = sx * (1.0f / KLOC_); o[4] = sy * (1.0f / KLOC_); o[5] = sz * (1.0f / KLOC_);
    }
}

// ---------------- GCN aggregation: (x + sum_nb) / (k+1) --------------------
__global__ void gcn_agg_kernel(const float* __restrict__ x,
                               const int* __restrict__ knn,
                               float* __restrict__ agg, int C) {
    int i = blockIdx.x * blockDim.x + threadIdx.x;
    if (i >= B_ * N_ * C) return;
    int c = i % C;
    int n = (i / C) % N_;
    int b = i / (C * N_);
    const int* id = knn + ((size_t)b * N_ + n) * KG_;
    float s = x[((size_t)b * N_ + n) * C + c];
    #pragma unroll
    for (int j = 0; j < KG_; ++j) s += x[((size_t)b * N_ + id[j]) * C + c];
    agg[i] = s * (1.0f / (KG_ + 1));
}

// ---------------- linear: 4 outputs per thread (small cases) ---------------
template <bool RELU>
__global__ void linear4_kernel(const float* __restrict__ X,
                               const float* __restrict__ W,
                               const float* __restrict__ bias,
                               float* __restrict__ Y,
                               int rows, int Cin, int Cout) {
    int co4 = Cout >> 2;
    int idx = blockIdx.x * blockDim.x + threadIdx.x;
    if (idx >= rows * co4) return;
    int r = idx / co4, o4 = (idx - r * co4) << 2;
    const float* x = X + (size_t)r * Cin;
    float4 acc = *(const float4*)(bias + o4);
    #pragma unroll 4
    for (int c = 0; c < Cin; ++c) {
        float xv = x[c];
        float4 w = *(const float4*)(W + (size_t)c * Cout + o4);
        acc.x += xv * w.x; acc.y += xv * w.y; acc.z += xv * w.z; acc.w += xv * w.w;
    }
    if (RELU) {
        acc.x = fmaxf(acc.x, 0.f); acc.y = fmaxf(acc.y, 0.f);
        acc.z = fmaxf(acc.z, 0.f); acc.w = fmaxf(acc.w, 0.f);
    }
    *(float4*)(Y + (size_t)r * Cout + o4) = acc;
}

// ---------------- attention: no-max softmax, KSP=8, two-round merge --------
__global__ __launch_bounds__(512) void attn_part(
        const float* __restrict__ q,
        const float* __restrict__ k,
        const float* __restrict__ v,
        const float* __restrict__ coords,
        const float* __restrict__ alphap, int layer,
        float* __restrict__ pp) {
    int bh = blockIdx.x & 15;          // b*8 + h
    int t = blockIdx.x >> 4;           // nb*KSP + ks
    int ks = t & (KSP_ - 1);
    int nb = t >> 3;                   // log2(KSP_) = 3
    int h = bh & 7;
    int b = bh >> 3;
    int wid = threadIdx.x >> 6;
    int lane = threadIdx.x & 63;
    int n0 = nb * 128 + lane;          // second query: n0 + 64
    float alpha = alphap[layer];
    const float* qp0 = q + ((size_t)(b * N_ + n0) * D_ + h * DK_);
    const float* qp1 = qp0 + (size_t)64 * D_;
    float qv0[DK_], qv1[DK_];
    #pragma unroll
    for (int d = 0; d < DK_; ++d) { qv0[d] = qp0[d]; qv1[d] = qp1[d]; }
    const float* cb = coords + (size_t)b * N_ * 3;
    float c0x = cb[n0 * 3], c0y = cb[n0 * 3 + 1], c0z = cb[n0 * 3 + 2];
    float c1x = cb[(n0 + 64) * 3], c1y = cb[(n0 + 64) * 3 + 1], c1z = cb[(n0 + 64) * 3 + 2];
    const float* kb = k + (size_t)b * N_ * D_ + h * DK_;
    const float* vb = v + (size_t)b * N_ * D_ + h * DK_;
    float sm0 = 0.f, sm1 = 0.f;
    float a0[DK_], a1[DK_];
    #pragma unroll
    for (int d = 0; d < DK_; ++d) { a0[d] = 0.f; a1[d] = 0.f; }
    int kbase = ks * 128 + wid * 16;   // 16 keys per wave
    #pragma unroll 4
    for (int j = 0; j < 16; ++j) {
        int m = kbase + j;
        const float4* kr = (const float4*)(kb + (size_t)m * D_);
        float4 k0 = kr[0], k1 = kr[1], k2 = kr[2], k3 = kr[3];
        float d0 = qv0[0] * k0.x + qv0[1] * k0.y + qv0[2] * k0.z + qv0[3] * k0.w
                 + qv0[4] * k1.x + qv0[5] * k1.y + qv0[6] * k1.z + qv0[7] * k1.w
                 + qv0[8] * k2.x + qv0[9] * k2.y + qv0[10] * k2.z + qv0[11] * k2.w
                 + qv0[12] * k3.x + qv0[13] * k3.y + qv0[14] * k3.z + qv0[15] * k3.w;
        float d1 = qv1[0] * k0.x + qv1[1] * k0.y + qv1[2] * k0.z + qv1[3] * k0.w
                 + qv1[4] * k1.x + qv1[5] * k1.y + qv1[6] * k1.z + qv1[7] * k1.w
                 + qv1[8] * k2.x + qv1[9] * k2.y + qv1[10] * k2.z + qv1[11] * k2.w
                 + qv1[12] * k3.x + qv1[13] * k3.y + qv1[14] * k3.z + qv1[15] * k3.w;
        float wx = cb[m * 3], wy = cb[m * 3 + 1], wz = cb[m * 3 + 2];
        float p0 = __expf(d0 * 0.25f + alpha * (wx * c0x + wy * c0y + wz * c0z));
        float p1 = __expf(d1 * 0.25f + alpha * (wx * c1x + wy * c1y + wz * c1z));
        sm0 += p0; sm1 += p1;
        const float4* vr = (const float4*)(vb + (size_t)m * D_);
        float4 v0 = vr[0], v1 = vr[1], v2 = vr[2], v3 = vr[3];
        a0[0] += p0 * v0.x;  a0[1] += p0 * v0.y;  a0[2] += p0 * v0.z;  a0[3] += p0 * v0.w;
        a0[4] += p0 * v1.x;  a0[5] += p0 * v1.y;  a0[6] += p0 * v1.z;  a0[7] += p0 * v1.w;
        a0[8] += p0 * v2.x;  a0[9] += p0 * v2.y;  a0[10] += p0 * v2.z; a0[11] += p0 * v2.w;
        a0[12] += p0 * v3.x; a0[13] += p0 * v3.y; a0[14] += p0 * v3.z; a0[15] += p0 * v3.w;
        a1[0] += p1 * v0.x;  a1[1] += p1 * v0.y;  a1[2] += p1 * v0.z;  a1[3] += p1 * v0.w;
        a1[4] += p1 * v1.x;  a1[5] += p1 * v1.y;  a1[6] += p1 * v1.z;  a1[7] += p1 * v1.w;
        a1[8] += p1 * v2.x;  a1[9] += p1 * v2.y;  a1[10] += p1 * v2.z; a1[11] += p1 * v2.w;
        a1[12] += p1 * v3.x; a1[13] += p1 * v3.y; a1[14] += p1 * v3.z; a1[15] += p1 * v3.w;
    }
    // ---- two-round merge: a0 (queries 0..63) then a1 (queries 64..127) ----
    __shared__ float ssum[AW_][128];
    __shared__ float sacc[64][AW_ * DK_ + 1];    // 33KB, reused both rounds
    ssum[wid][lane] = sm0;      ssum[wid][lane + 64] = sm1;
    int qi = threadIdx.x & 63;                   // query within round
    int dq = threadIdx.x >> 6;                   // 0..7, 2 d's each
    // round 1
    #pragma unroll
    for (int d = 0; d < DK_; ++d) sacc[lane][wid * DK_ + d] = a0[d];
    __syncthreads();
    {
        int n = nb * 128 + qi;
        float* o = pp + (((size_t)bh * N_ + n) * KSP_ + ks) * PREC_;
        if (dq == 0) {
            float gsum = 0.f;
            #pragma unroll
            for (int w = 0; w < AW_; ++w) gsum += ssum[w][qi];
            o[0] = gsum;
        }
        #pragma unroll
        for (int dd = 0; dd < 2; ++dd) {
            int d = dq * 2 + dd;
            float a = 0.f;
            #pragma unroll
            for (int w = 0; w < AW_; ++w) a += sacc[qi][w * DK_ + d];
            o[1 + d] = a;
        }
    }
    __syncthreads();
    // round 2
    #pragma unroll
    for (int d = 0; d < DK_; ++d) sacc[lane][wid * DK_ + d] = a1[d];
    __syncthreads();
    {
        int n = nb * 128 + 64 + qi;
        float* o = pp + (((size_t)bh * N_ + n) * KSP_ + ks) * PREC_;
        if (dq == 0) {
            float gsum = 0.f;
            #pragma unroll
            for (int w = 0; w < AW_; ++w) gsum += ssum[w][qi + 64];
            o[0] = gsum;
        }
        #pragma unroll
        for (int dd = 0; dd < 2; ++dd) {
            int d = dq * 2 + dd;
            float a = 0.f;
            #pragma unroll
            for (int w = 0; w < AW_; ++w) a += sacc[qi][w * DK_ + d];
            o[1 + d] = a;
        }
    }
}

// ---------------- fused attn final-merge + residual + LayerNorm ------------
__global__ void attn_fin_ln(const float* __restrict__ pp,
                            const float* __restrict__ xin,
                            const float* __restrict__ g,
                            const float* __restrict__ bt,
                            float* __restrict__ xout) {
    int row = blockIdx.x * 4 + (threadIdx.x >> 6);   // b*N + n
    int lane = threadIdx.x & 63;
    int b = row >> 10, n = row & (N_ - 1);
    float v0, v1;
    {
        int c = lane;
        int h = c >> 4, d = c & 15;
        const float* p = pp + (((size_t)(b * 8 + h) * N_ + n) * KSP_) * PREC_;
        float gsum = 0.f, a = 0.f;
        #pragma unroll
        for (int s = 0; s < KSP_; ++s) {
            gsum += p[s * PREC_];
            a += p[s * PREC_ + 1 + d];
        }
        v0 = a / gsum + xin[(size_t)row * D_ + c];
    }
    {
        int c = lane + 64;
        int h = c >> 4, d = c & 15;
        const float* p = pp + (((size_t)(b * 8 + h) * N_ + n) * KSP_) * PREC_;
        float gsum = 0.f, a = 0.f;
        #pragma unroll
        for (int s = 0; s < KSP_; ++s) {
            gsum += p[s * PREC_];
            a += p[s * PREC_ + 1 + d];
        }
        v1 = a / gsum + xin[(size_t)row * D_ + c];
    }
    float mean = wave_sum(v0 + v1) * (1.0f / D_);
    float d0 = v0 - mean, d1 = v1 - mean;
    float var = wave_sum(d0 * d0 + d1 * d1) * (1.0f / D_);
    float rstd = rsqrtf(var + 1e-5f);
    float* orow = xout + (size_t)row * D_;
    orow[lane] = d0 * rstd * g[lane] + bt[lane];
    orow[lane + 64] = d1 * rstd * g[lane + 64] + bt[lane + 64];
}

// ---------------- column mean over N (global feature) ----------------------
__global__ void colmean_kernel(const float* __restrict__ x,
                               float* __restrict__ gc) {
    int b = blockIdx.x;
    int d = threadIdx.x & 127;
    int sl = threadIdx.x >> 7;
    __shared__ float part[4][128];
    float s = 0.f;
    const float* xb = x + (size_t)b * N_ * D_;
    for (int n = sl * 256; n < sl * 256 + 256; ++n) s += xb[(size_t)n * D_ + d];
    part[sl][d] = s;
    __syncthreads();
    if (sl == 0)
        gc[b * D_ + d] = (part[0][d] + part[1][d] + part[2][d] + part[3][d]) * (1.0f / N_);
}

// ---------------- child = pred + (h . cw + cb), interleaved x2 -------------
__global__ void child_kernel(const float* __restrict__ h,
                             const float* __restrict__ cw,
                             const float* __restrict__ cb,
                             const float* __restrict__ pred,
                             float* __restrict__ outp, int Nq) {
    int idx = blockIdx.x * blockDim.x + threadIdx.x;
    if (idx >= B_ * Nq * 6) return;
    int p = idx % 3;
    int t = (idx / 3) & 1;
    int n = (idx / 6) % Nq;
    int b = idx / (6 * Nq);
    const float* hr = h + ((size_t)b * Nq + n) * 256;
    float acc = cb[p];
    #pragma unroll 4
    for (int o = 0; o < 128; ++o) acc += hr[o * 2 + t] * cw[p * 128 + o];
    outp[idx] = pred[((size_t)b * Nq + n) * 3 + p] + acc;
}

// ---------------------------------------------------------------------------
static inline int cdiv(int a, int b) { return (a + b - 1) / b; }

extern "C" void kernel_launch(void* const* d_in, const int* in_sizes, int n_in,
                              void* d_out, int out_size, void* d_ws, size_t ws_size,
                              hipStream_t stream) {
    (void)in_sizes; (void)n_in; (void)out_size; (void)ws_size;
    const float* coords = (const float*)d_in[0];
    const float* gcn_w0 = (const float*)d_in[1];
    const float* gcn_b0 = (const float*)d_in[2];
    const float* gcn_w1 = (const float*)d_in[3];
    const float* gcn_b1 = (const float*)d_in[4];
    const float* enc_fw = (const float*)d_in[5];
    const float* enc_fb = (const float*)d_in[6];
    const float* t_wq   = (const float*)d_in[7];
    const float* t_bq   = (const float*)d_in[8];
    const float* t_wk   = (const float*)d_in[9];
    const float* t_bk   = (const float*)d_in[10];
    const float* t_wv   = (const float*)d_in[11];
    const float* t_bv   = (const float*)d_in[12];
    const float* t_alpha= (const float*)d_in[13];
    const float* t_f1w  = (const float*)d_in[14];
    const float* t_f1b  = (const float*)d_in[15];
    const float* t_f2w  = (const float*)d_in[16];
    const float* t_f2b  = (const float*)d_in[17];
    const float* t_ln1g = (const float*)d_in[18];
    const float* t_ln1b = (const float*)d_in[19];
    const float* t_ln2g = (const float*)d_in[20];
    const float* t_ln2b = (const float*)d_in[21];
    const float* dec_w1 = (const float*)d_in[22];
    const float* dec_b1 = (const float*)d_in[23];
    const float* dec_w2 = (const float*)d_in[24];
    const float* dec_b2 = (const float*)d_in[25];
    const float* st_sw1 = (const float*)d_in[26];
    const float* st_sb1 = (const float*)d_in[27];
    const float* st_sw2 = (const float*)d_in[28];
    const float* st_sb2 = (const float*)d_in[29];
    const float* st_dw  = (const float*)d_in[30];
    const float* st_db  = (const float*)d_in[31];
    const float* st_cw  = (const float*)d_in[32];
    const float* st_cb  = (const float*)d_in[33];
    float* out = (float*)d_out;

    // ---- workspace carve ----
    char* ws = (char*)d_ws;
    size_t off = 0;
    auto alloc = [&](size_t bytes) -> void* {
        void* p = ws + off;
        off += (bytes + 255) & ~(size_t)255;
        return p;
    };
    int*   knn   = (int*)  alloc((size_t)B_ * N_ * KG_ * 4);
    float* ppd   = (float*)alloc((size_t)B_ * 2048 * NCH_ * KG_ * 4);
    int*   ppi   = (int*)  alloc((size_t)B_ * 2048 * NCH_ * KG_ * 4);
    float* app   = (float*)alloc((size_t)B_ * H_ * N_ * KSP_ * PREC_ * 4);
    float* agg   = (float*)alloc((size_t)B_ * N_ * 64 * 4);
    float* x64   = (float*)alloc((size_t)B_ * N_ * 64 * 4);
    float* xb    = (float*)alloc((size_t)B_ * N_ * D_ * 4);
    float* x     = (float*)alloc((size_t)B_ * N_ * D_ * 4);
    float* q     = (float*)alloc((size_t)B_ * N_ * D_ * 4);
    float* k     = (float*)alloc((size_t)B_ * N_ * D_ * 4);
    float* v     = (float*)alloc((size_t)B_ * N_ * D_ * 4);
    float* ffh   = (float*)alloc((size_t)B_ * N_ * 512 * 4);
    float* gc    = (float*)alloc((size_t)B_ * D_ * 4);
    float* dech  = (float*)alloc((size_t)B_ * D_ * 4);
    float* pts0  = (float*)alloc((size_t)B_ * COARSE_ * 3 * 4);
    float* pts1  = (float*)alloc((size_t)B_ * 1024 * 3 * 4);
    float* pts2  = (float*)alloc((size_t)B_ * 2048 * 3 * 4);
    float* comb  = (float*)alloc((size_t)B_ * 2048 * 6 * 4);
    float* seedh = (float*)alloc((size_t)B_ * 2048 * 128 * 4);
    float* seed  = (float*)alloc((size_t)B_ * 2048 * 128 * 4);
    float* hb    = (float*)alloc((size_t)B_ * 2048 * 256 * 4);

    const int rows = B_ * N_;   // 2048

    // ---- graph encoder ----
    knn_part_kernel<<<B_ * NCH_ * 16, 64, 0, stream>>>(coords, ppd, ppi);
    knn_merge_kernel<<<B_ * N_ / MQ_, 256, 0, stream>>>(ppd, ppi, knn);
    gcn_agg_kernel<<<cdiv(rows * 3, 256), 256, 0, stream>>>(coords, knn, agg, 3);
    linear4_kernel<true><<<cdiv(rows * 16, 256), 256, 0, stream>>>(agg, gcn_w0, gcn_b0, x64, rows, 3, 64);
    gcn_agg_kernel<<<cdiv(rows * 64, 256), 256, 0, stream>>>(x64, knn, agg, 64);
    gemm128_kernel<64, true, false><<<dim3(rows / 8, 1), 256, 0, stream>>>(agg, gcn_w1, gcn_b1, xb, 128, 128);
    gemm128_kernel<128, false, false><<<dim3(rows / 8, 1), 256, 0, stream>>>(xb, enc_fw, enc_fb, x, 128, 128);

    // ---- transformer ----
    for (int i = 0; i < L_; ++i) {
        qkv3_kernel<<<dim3(rows / 8, 3), 256, 0, stream>>>(
            x, t_wq + i * 16384, t_bq + i * 128, t_wk + i * 16384, t_bk + i * 128,
            t_wv + i * 16384, t_bv + i * 128, q, k, v);
        attn_part<<<B_ * H_ * (N_ / 128) * KSP_, 512, 0, stream>>>(q, k, v, coords, t_alpha, i, app);
        attn_fin_ln<<<rows / 4, 256, 0, stream>>>(app, x, t_ln1g + i * 128, t_ln1b + i * 128, x);
        gemm128_kernel<128, true, false><<<dim3(rows / 8, 4), 256, 0, stream>>>(x, t_f1w + i * 128 * 512, t_f1b + i * 512, ffh, 512, 512);
        gemm_ln_kernel<512><<<rows / 8, 256, 0, stream>>>(ffh, t_f2w + i * 512 * 128, t_f2b + i * 128, x, t_ln2g + i * 128, t_ln2b + i * 128, x);
    }

    // ---- decoder coarse ----
    colmean_kernel<<<B_, 512, 0, stream>>>(x, gc);
    linear4_kernel<true><<<cdiv(B_ * 32, 256), 256, 0, stream>>>(gc, dec_w1, dec_b1, dech, B_, 128, 128);
    linear4_kernel<false><<<cdiv(B_ * 384, 256), 256, 0, stream>>>(dech, dec_w2, dec_b2, pts0, B_, 128, 1536);

    // ---- refine stages ----
    const float* pred = pts0;
    float* outs[3] = { pts1, pts2, out };
    int Nq = COARSE_;
    for (int s = 0; s < 3; ++s) {
        loc_part_kernel<<<dim3(Nq / 64, NCH_, B_), 64, 0, stream>>>(coords, pred, ppd, ppi, Nq);
        loc_merge_kernel<<<(B_ * Nq) / MQ_, 256, 0, stream>>>(coords, pred, ppd, ppi, comb, Nq);
        int srows = B_ * Nq;
        linear4_kernel<true><<<cdiv(srows * 32, 256), 256, 0, stream>>>(comb, st_sw1 + s * 6 * 128, st_sb1 + s * 128, seedh, srows, 6, 128);
        gemm128_kernel<128, false, false><<<dim3(srows / 8, 1), 256, 0, stream>>>(seedh, st_sw2 + s * 128 * 128, st_sb2 + s * 128, seed, 128, 128);
        gemm128_kernel<128, true, true><<<dim3(srows / 8, 2), 256, 0, stream>>>(seed, st_dw + s * 128 * 256, st_db + s * 128, hb, 256, 256);
        child_kernel<<<cdiv(srows * 6, 256), 256, 0, stream>>>(hb, st_cw + s * 3 * 128, st_cb + s * 3, pred, outs[s], Nq);
        pred = outs[s];
        Nq <<= 1;
    }
}

// Round 14
// 549.957 us; speedup vs baseline: 1.1941x; 1.1941x over previous
//
#include <hip/hip_runtime.h>

// ---------------------------------------------------------------------------
// FullModelSnowflake.  R13: KSP back to 4 (8 regressed: merge fixed-costs
// dominated); Q/K/V stored head-major so attn's Q loads coalesce and each
// block's K/V slice is contiguous; K/V cooperatively staged into LDS (union
// with merge buffers, 37KB) so the key loop reads LDS instead of L1.
// ---------------------------------------------------------------------------

#define B_ 2
#define N_ 1024
#define D_ 128
#define H_ 8
#define DK_ 16
#define L_ 4
#define KG_ 16
#define KLOC_ 8
#define COARSE_ 512
#define NCH_ 16          // candidate chunks (64 candidates each)
#define AW_ 8            // waves per attention block
#define KSP_ 4           // block-level key splits
#define PREC_ 17         // floats per attention partial (sum + 16 acc)
#define MQ_ 16           // queries per merge block

static __device__ __forceinline__ float wave_sum(float v) {
    #pragma unroll
    for (int off = 32; off > 0; off >>= 1) v += __shfl_xor(v, off);
    return v;
}
static __device__ __forceinline__ float half_sum(float v) {
    #pragma unroll
    for (int off = 16; off > 0; off >>= 1) v += __shfl_xor(v, off);
    return v;
}

// ---------------- LDS-staged GEMM body: returns this thread's acc ----------
template <int CIN, bool RELU, bool BIAS_HALF>
static __device__ __forceinline__ float4 gemm_body(
        const float* __restrict__ X, const float* __restrict__ W,
        const float* __restrict__ bias, int wstride, int col0) {
    __shared__ float Xs[8 * CIN];
    __shared__ float Ws[64][128];
    int tid = threadIdx.x;
    int row0 = blockIdx.x * 8;
    constexpr int NX4 = 2 * CIN;
    {
        const float4* xg = (const float4*)(X + (size_t)row0 * CIN);
        float4* xs4 = (float4*)Xs;
        #pragma unroll
        for (int i = 0; i < (NX4 + 255) / 256; ++i) {
            int t = tid + i * 256;
            if ((NX4 % 256 == 0) || t < NX4) xs4[t] = xg[t];
        }
    }
    int col4 = (tid & 31) << 2;
    int rowl = tid >> 5;
    float4 acc;
    if (BIAS_HALF) {
        acc.x = bias[(col0 + col4) >> 1];
        acc.y = bias[(col0 + col4 + 1) >> 1];
        acc.z = bias[(col0 + col4 + 2) >> 1];
        acc.w = bias[(col0 + col4 + 3) >> 1];
    } else {
        acc = *(const float4*)(bias + col0 + col4);
    }
    for (int c0 = 0; c0 < CIN; c0 += 64) {
        __syncthreads();
        #pragma unroll
        for (int i = 0; i < 8; ++i) {
            int flat = tid + i * 256;
            int wr = flat >> 5, wc = (flat & 31) << 2;
            *(float4*)&Ws[wr][wc] =
                *(const float4*)(W + (size_t)(c0 + wr) * wstride + col0 + wc);
        }
        __syncthreads();
        const float* xrow = Xs + rowl * CIN + c0;
        #pragma unroll
        for (int c = 0; c < 64; ++c) {
            float xv = xrow[c];
            float4 w = *(const float4*)&Ws[c][col4];
            acc.x += xv * w.x; acc.y += xv * w.y;
            acc.z += xv * w.z; acc.w += xv * w.w;
        }
    }
    if (RELU) {
        acc.x = fmaxf(acc.x, 0.f); acc.y = fmaxf(acc.y, 0.f);
        acc.z = fmaxf(acc.z, 0.f); acc.w = fmaxf(acc.w, 0.f);
    }
    return acc;
}

template <int CIN, bool RELU, bool BIAS_HALF>
__global__ __launch_bounds__(256) void gemm128_kernel(
        const float* __restrict__ X, const float* __restrict__ W,
        const float* __restrict__ bias, float* __restrict__ Y,
        int wstride, int ystride) {
    int col0 = blockIdx.y * 128;
    float4 acc = gemm_body<CIN, RELU, BIAS_HALF>(X, W, bias, wstride, col0);
    int col4 = (threadIdx.x & 31) << 2;
    int row = blockIdx.x * 8 + (threadIdx.x >> 5);
    *(float4*)(Y + (size_t)row * ystride + col0 + col4) = acc;
}

// GEMM (Cout=128) fused with residual-add + LayerNorm epilogue.
template <int CIN>
__global__ __launch_bounds__(256) void gemm_ln_kernel(
        const float* __restrict__ X, const float* __restrict__ W,
        const float* __restrict__ bias, const float* __restrict__ res,
        const float* __restrict__ g, const float* __restrict__ bt,
        float* __restrict__ Y) {
    float4 acc = gemm_body<CIN, false, false>(X, W, bias, 128, 0);
    int col4 = (threadIdx.x & 31) << 2;
    int row = blockIdx.x * 8 + (threadIdx.x >> 5);
    float4 r = *(const float4*)(res + (size_t)row * D_ + col4);
    acc.x += r.x; acc.y += r.y; acc.z += r.z; acc.w += r.w;
    float mean = half_sum(acc.x + acc.y + acc.z + acc.w) * (1.0f / D_);
    float dx = acc.x - mean, dy = acc.y - mean, dz = acc.z - mean, dw = acc.w - mean;
    float var = half_sum(dx * dx + dy * dy + dz * dz + dw * dw) * (1.0f / D_);
    float rstd = rsqrtf(var + 1e-5f);
    float4 gv = *(const float4*)(g + col4);
    float4 bv = *(const float4*)(bt + col4);
    float4 o;
    o.x = dx * rstd * gv.x + bv.x;
    o.y = dy * rstd * gv.y + bv.y;
    o.z = dz * rstd * gv.z + bv.z;
    o.w = dw * rstd * gv.w + bv.w;
    *(float4*)(Y + (size_t)row * D_ + col4) = o;
}

// fused QKV: 3 W-panels via blockIdx.y; outputs stored HEAD-MAJOR
// [bh][n][16] so attention's Q loads coalesce and K/V slices are contiguous.
__global__ __launch_bounds__(256) void qkv3_kernel(
        const float* __restrict__ X,
        const float* __restrict__ Wq, const float* __restrict__ bq,
        const float* __restrict__ Wk, const float* __restrict__ bk,
        const float* __restrict__ Wv, const float* __restrict__ bv,
        float* __restrict__ Q, float* __restrict__ K, float* __restrict__ V) {
    const float* W; const float* bias; float* Y;
    if (blockIdx.y == 0)      { W = Wq; bias = bq; Y = Q; }
    else if (blockIdx.y == 1) { W = Wk; bias = bk; Y = K; }
    else                      { W = Wv; bias = bv; Y = V; }
    float4 acc = gemm_body<128, false, false>(X, W, bias, 128, 0);
    int col4 = (threadIdx.x & 31) << 2;
    int row = blockIdx.x * 8 + (threadIdx.x >> 5);
    int b = row >> 10, n = row & (N_ - 1);
    int h = col4 >> 4, d = col4 & 15;
    *(float4*)(Y + (((size_t)(b * 8 + h) * N_ + n) << 4) + d) = acc;
}

// ---------------- KNN pass 1: per-chunk partial top-16 ---------------------
__global__ void knn_part_kernel(const float* __restrict__ coords,
                                float* __restrict__ pd, int* __restrict__ pi) {
    int blk = blockIdx.x;
    int qb = blk & 15;
    int ch = (blk >> 4) & 15;
    int b = blk >> 8;
    int lane = threadIdx.x;
    int q = qb * 64 + lane;
    __shared__ float4 sc[64];
    const float* cb = coords + (size_t)b * N_ * 3;
    {
        int m = ch * 64 + lane;
        float x = cb[m * 3], y = cb[m * 3 + 1], z = cb[m * 3 + 2];
        sc[lane] = make_float4(x, y, z, x * x + y * y + z * z);
    }
    __syncthreads();
    float qx = cb[q * 3], qy = cb[q * 3 + 1], qz = cb[q * 3 + 2];
    float q2 = qx * qx + qy * qy + qz * qz;
    float bd[KG_]; int bi[KG_];
    #pragma unroll
    for (int j = 0; j < KG_; ++j) { bd[j] = 3e38f; bi[j] = 0; }
    for (int j = 0; j < 64; ++j) {
        int m = ch * 64 + j;
        float4 c = sc[j];
        float dot = qx * c.x + qy * c.y + qz * c.z;
        float d = (q2 - 2.0f * dot) + c.w;
        d = (m == q) ? 3e38f : d;
        if (d < bd[KG_ - 1]) {
            #pragma unroll
            for (int jj = KG_ - 1; jj > 0; --jj) {
                bool shf = d < bd[jj - 1];
                bool plc = !shf && (d < bd[jj]);
                bd[jj] = shf ? bd[jj - 1] : (plc ? d : bd[jj]);
                bi[jj] = shf ? bi[jj - 1] : (plc ? m : bi[jj]);
            }
            if (d < bd[0]) { bd[0] = d; bi[0] = m; }
        }
    }
    size_t base = (((size_t)b * N_ + q) * NCH_ + ch) * KG_;
    #pragma unroll
    for (int j = 0; j < KG_; ++j) { pd[base + j] = bd[j]; pi[base + j] = bi[j]; }
}

// ---------------- KNN pass 2: LDS-staged merge of 16 sorted lists ----------
__global__ __launch_bounds__(256) void knn_merge_kernel(
        const float* __restrict__ pd, const int* __restrict__ pi,
        int* __restrict__ knn) {
    __shared__ float sd[MQ_][NCH_ * KG_ + 1];
    __shared__ int   si[MQ_][NCH_ * KG_ + 1];
    size_t qg0 = (size_t)blockIdx.x * MQ_;
    size_t base = qg0 * NCH_ * KG_;
    for (int i = threadIdx.x; i < MQ_ * NCH_ * KG_; i += 256) {
        int r = i >> 8, cix = i & 255;
        sd[r][cix] = pd[base + i];
        si[r][cix] = pi[base + i];
    }
    __syncthreads();
    int t = threadIdx.x;
    if (t < MQ_) {
        const float* cd0 = sd[t];
        const int* ci0 = si[t];
        float bd[KG_]; int bi[KG_];
        #pragma unroll
        for (int j = 0; j < KG_; ++j) { bd[j] = 3e38f; bi[j] = 0; }
        for (int ch = 0; ch < NCH_; ++ch) {
            for (int e = 0; e < KG_; ++e) {
                float d = cd0[ch * KG_ + e];
                if (d >= bd[KG_ - 1]) break;
                int m = ci0[ch * KG_ + e];
                #pragma unroll
                for (int jj = KG_ - 1; jj > 0; --jj) {
                    bool shf = d < bd[jj - 1];
                    bool plc = !shf && (d < bd[jj]);
                    bd[jj] = shf ? bd[jj - 1] : (plc ? d : bd[jj]);
                    bi[jj] = shf ? bi[jj - 1] : (plc ? m : bi[jj]);
                }
                if (d < bd[0]) { bd[0] = d; bi[0] = m; }
            }
        }
        int* o = knn + (qg0 + t) * KG_;
        #pragma unroll
        for (int j = 0; j < KG_; ++j) o[j] = bi[j];
    }
}

// ---------------- local KNN pass 1 (k=8) -----------------------------------
__global__ void loc_part_kernel(const float* __restrict__ part,
                                const float* __restrict__ pred,
                                float* __restrict__ pd, int* __restrict__ pi,
                                int Nq) {
    int qb = blockIdx.x, ch = blockIdx.y, b = blockIdx.z;
    int lane = threadIdx.x;
    int q = qb * 64 + lane;
    __shared__ float4 sc[64];
    const float* pb = part + (size_t)b * N_ * 3;
    {
        int m = ch * 64 + lane;
        float x = pb[m * 3], y = pb[m * 3 + 1], z = pb[m * 3 + 2];
        sc[lane] = make_float4(x, y, z, x * x + y * y + z * z);
    }
    __syncthreads();
    const float* pr = pred + ((size_t)b * Nq + q) * 3;
    float qx = pr[0], qy = pr[1], qz = pr[2];
    float q2 = qx * qx + qy * qy + qz * qz;
    float bd[KLOC_]; int bi[KLOC_];
    #pragma unroll
    for (int j = 0; j < KLOC_; ++j) { bd[j] = 3e38f; bi[j] = 0; }
    for (int j = 0; j < 64; ++j) {
        float4 c = sc[j];
        float dot = qx * c.x + qy * c.y + qz * c.z;
        float d = (q2 - 2.0f * dot) + c.w;
        if (d < bd[KLOC_ - 1]) {
            int m = ch * 64 + j;
            #pragma unroll
            for (int jj = KLOC_ - 1; jj > 0; --jj) {
                bool shf = d < bd[jj - 1];
                bool plc = !shf && (d < bd[jj]);
                bd[jj] = shf ? bd[jj - 1] : (plc ? d : bd[jj]);
                bi[jj] = shf ? bi[jj - 1] : (plc ? m : bi[jj]);
            }
            if (d < bd[0]) { bd[0] = d; bi[0] = m; }
        }
    }
    size_t base = (((size_t)b * Nq + q) * NCH_ + ch) * KLOC_;
    #pragma unroll
    for (int j = 0; j < KLOC_; ++j) { pd[base + j] = bd[j]; pi[base + j] = bi[j]; }
}

// ---------------- local KNN pass 2: LDS-staged merge + mean + comb ---------
__global__ __launch_bounds__(256) void loc_merge_kernel(
        const float* __restrict__ part, const float* __restrict__ pred,
        const float* __restrict__ pd, const int* __restrict__ pi,
        float* __restrict__ comb, int Nq) {
    __shared__ float sd[MQ_][NCH_ * KLOC_ + 1];
    __shared__ int   si[MQ_][NCH_ * KLOC_ + 1];
    size_t qg0 = (size_t)blockIdx.x * MQ_;
    size_t base = qg0 * NCH_ * KLOC_;
    for (int i = threadIdx.x; i < MQ_ * NCH_ * KLOC_; i += 256) {
        int r = i >> 7, cix = i & 127;
        sd[r][cix] = pd[base + i];
        si[r][cix] = pi[base + i];
    }
    __syncthreads();
    int t = threadIdx.x;
    if (t < MQ_) {
        const float* cd0 = sd[t];
        const int* ci0 = si[t];
        float bd[KLOC_]; int bi[KLOC_];
        #pragma unroll
        for (int j = 0; j < KLOC_; ++j) { bd[j] = 3e38f; bi[j] = 0; }
        for (int ch = 0; ch < NCH_; ++ch) {
            for (int e = 0; e < KLOC_; ++e) {
                float d = cd0[ch * KLOC_ + e];
                if (d >= bd[KLOC_ - 1]) break;
                int m = ci0[ch * KLOC_ + e];
                #pragma unroll
                for (int jj = KLOC_ - 1; jj > 0; --jj) {
                    bool shf = d < bd[jj - 1];
                    bool plc = !shf && (d < bd[jj]);
                    bd[jj] = shf ? bd[jj - 1] : (plc ? d : bd[jj]);
                    bi[jj] = shf ? bi[jj - 1] : (plc ? m : bi[jj]);
                }
                if (d < bd[0]) { bd[0] = d; bi[0] = m; }
            }
        }
        size_t qg = qg0 + t;
        int b = (int)(qg / Nq);
        const float* pb = part + (size_t)b * N_ * 3;
        float sx = 0.f, sy = 0.f, sz = 0.f;
        #pragma unroll
        for (int j = 0; j < KLOC_; ++j) {
            int m = bi[j];
            sx += pb[m * 3]; sy += pb[m * 3 + 1]; sz += pb[m * 3 + 2];
        }
        const float* pr = pred + qg * 3;
        float* o = comb + qg * 6;
        o[0] = pr[0]; o[1] = pr[1]; o[2] = pr[2];
        o[3] = sx * (1.0f / KLOC_); o[4] = sy * (1.0f / KLOC_); o[5] = sz * (1.0f / KLOC_);
    }
}

// ---------------- GCN aggregation: (x + sum_nb) / (k+1) --------------------
__global__ void gcn_agg_kernel(const float* __restrict__ x,
                               const int* __restrict__ knn,
                               float* __restrict__ agg, int C) {
    int i = blockIdx.x * blockDim.x + threadIdx.x;
    if (i >= B_ * N_ * C) return;
    int c = i % C;
    int n = (i / C) % N_;
    int b = i / (C * N_);
    const int* id = knn + ((size_t)b * N_ + n) * KG_;
    float s = x[((size_t)b * N_ + n) * C + c];
    #pragma unroll
    for (int j = 0; j < KG_; ++j) s += x[((size_t)b * N_ + id[j]) * C + c];
    agg[i] = s * (1.0f / (KG_ + 1));
}

// ---------------- linear: 4 outputs per thread (small cases) ---------------
template <bool RELU>
__global__ void linear4_kernel(const float* __restrict__ X,
                               const float* __restrict__ W,
                               const float* __restrict__ bias,
                               float* __restrict__ Y,
                               int rows, int Cin, int Cout) {
    int co4 = Cout >> 2;
    int idx = blockIdx.x * blockDim.x + threadIdx.x;
    if (idx >= rows * co4) return;
    int r = idx / co4, o4 = (idx - r * co4) << 2;
    const float* x = X + (size_t)r * Cin;
    float4 acc = *(const float4*)(bias + o4);
    #pragma unroll 4
    for (int c = 0; c < Cin; ++c) {
        float xv = x[c];
        float4 w = *(const float4*)(W + (size_t)c * Cout + o4);
        acc.x += xv * w.x; acc.y += xv * w.y; acc.z += xv * w.z; acc.w += xv * w.w;
    }
    if (RELU) {
        acc.x = fmaxf(acc.x, 0.f); acc.y = fmaxf(acc.y, 0.f);
        acc.z = fmaxf(acc.z, 0.f); acc.w = fmaxf(acc.w, 0.f);
    }
    *(float4*)(Y + (size_t)r * Cout + o4) = acc;
}

// ---------------- attention: head-major QKV, LDS-staged K/V ----------------
// Block covers keys [ks*256,(ks+1)*256): stage K+V (32KB, coalesced) into
// LDS, key loop reads LDS broadcasts.  Merge buffers union the stage buffer
// (barrier separates the phases).
__global__ __launch_bounds__(512) void attn_part(
        const float* __restrict__ q,
        const float* __restrict__ k,
        const float* __restrict__ v,
        const float* __restrict__ coords,
        const float* __restrict__ alphap, int layer,
        float* __restrict__ pp) {
    __shared__ float smem[9280];                 // stage 8192 | merge 9280
    float* kst = smem;                           // [256][16]
    float* vst = smem + 4096;                    // [256][16]
    float* ssum = smem;                          // [8][128]   (merge phase)
    float* sacc = smem + 1024;                   // [64][129]
    int bh = blockIdx.x & 15;          // b*8 + h
    int t = blockIdx.x >> 4;           // nb*KSP + ks
    int ks = t & (KSP_ - 1);
    int nb = t >> 2;                   // log2(KSP_) = 2
    int b = bh >> 3;
    int wid = threadIdx.x >> 6;
    int lane = threadIdx.x & 63;
    int n0 = nb * 128 + lane;          // second query: n0 + 64
    float alpha = alphap[layer];
    // ---- stage K/V slice (contiguous head-major) ----
    {
        const float4* kg = (const float4*)(k + (((size_t)bh * N_ + ks * 256) << 4));
        const float4* vg = (const float4*)(v + (((size_t)bh * N_ + ks * 256) << 4));
        float4* ks4 = (float4*)kst;
        float4* vs4 = (float4*)vst;
        #pragma unroll
        for (int i = 0; i < 2; ++i) {
            int idx = threadIdx.x + i * 512;
            ks4[idx] = kg[idx];
            vs4[idx] = vg[idx];
        }
    }
    const float* qp0 = q + (((size_t)bh * N_ + n0) << 4);
    const float* qp1 = qp0 + (64 << 4);
    float qv0[DK_], qv1[DK_];
    #pragma unroll
    for (int d = 0; d < DK_; ++d) { qv0[d] = qp0[d]; qv1[d] = qp1[d]; }
    const float* cb = coords + (size_t)b * N_ * 3;
    float c0x = cb[n0 * 3], c0y = cb[n0 * 3 + 1], c0z = cb[n0 * 3 + 2];
    float c1x = cb[(n0 + 64) * 3], c1y = cb[(n0 + 64) * 3 + 1], c1z = cb[(n0 + 64) * 3 + 2];
    float sm0 = 0.f, sm1 = 0.f;
    float a0[DK_], a1[DK_];
    #pragma unroll
    for (int d = 0; d < DK_; ++d) { a0[d] = 0.f; a1[d] = 0.f; }
    __syncthreads();                             // stage visible
    int mbase = ks * 256 + wid * 32;             // global key index base
    int lbase = wid * 32;                        // stage-local base
    #pragma unroll 4
    for (int j = 0; j < 32; ++j) {
        const float4* kr = (const float4*)(kst + ((lbase + j) << 4));
        float4 k0 = kr[0], k1 = kr[1], k2 = kr[2], k3 = kr[3];
        float d0 = qv0[0] * k0.x + qv0[1] * k0.y + qv0[2] * k0.z + qv0[3] * k0.w
                 + qv0[4] * k1.x + qv0[5] * k1.y + qv0[6] * k1.z + qv0[7] * k1.w
                 + qv0[8] * k2.x + qv0[9] * k2.y + qv0[10] * k2.z + qv0[11] * k2.w
                 + qv0[12] * k3.x + qv0[13] * k3.y + qv0[14] * k3.z + qv0[15] * k3.w;
        float d1 = qv1[0] * k0.x + qv1[1] * k0.y + qv1[2] * k0.z + qv1[3] * k0.w
                 + qv1[4] * k1.x + qv1[5] * k1.y + qv1[6] * k1.z + qv1[7] * k1.w
                 + qv1[8] * k2.x + qv1[9] * k2.y + qv1[10] * k2.z + qv1[11] * k2.w
                 + qv1[12] * k3.x + qv1[13] * k3.y + qv1[14] * k3.z + qv1[15] * k3.w;
        int m = mbase + j;
        float wx = cb[m * 3], wy = cb[m * 3 + 1], wz = cb[m * 3 + 2];
        float p0 = __expf(d0 * 0.25f + alpha * (wx * c0x + wy * c0y + wz * c0z));
        float p1 = __expf(d1 * 0.25f + alpha * (wx * c1x + wy * c1y + wz * c1z));
        sm0 += p0; sm1 += p1;
        const float4* vr = (const float4*)(vst + ((lbase + j) << 4));
        float4 v0 = vr[0], v1 = vr[1], v2 = vr[2], v3 = vr[3];
        a0[0] += p0 * v0.x;  a0[1] += p0 * v0.y;  a0[2] += p0 * v0.z;  a0[3] += p0 * v0.w;
        a0[4] += p0 * v1.x;  a0[5] += p0 * v1.y;  a0[6] += p0 * v1.z;  a0[7] += p0 * v1.w;
        a0[8] += p0 * v2.x;  a0[9] += p0 * v2.y;  a0[10] += p0 * v2.z; a0[11] += p0 * v2.w;
        a0[12] += p0 * v3.x; a0[13] += p0 * v3.y; a0[14] += p0 * v3.z; a0[15] += p0 * v3.w;
        a1[0] += p1 * v0.x;  a1[1] += p1 * v0.y;  a1[2] += p1 * v0.z;  a1[3] += p1 * v0.w;
        a1[4] += p1 * v1.x;  a1[5] += p1 * v1.y;  a1[6] += p1 * v1.z;  a1[7] += p1 * v1.w;
        a1[8] += p1 * v2.x;  a1[9] += p1 * v2.y;  a1[10] += p1 * v2.z; a1[11] += p1 * v2.w;
        a1[12] += p1 * v3.x; a1[13] += p1 * v3.y; a1[14] += p1 * v3.z; a1[15] += p1 * v3.w;
    }
    __syncthreads();                             // done reading stage
    // ---- two-round merge (reuses smem) ----
    ssum[wid * 128 + lane] = sm0;
    ssum[wid * 128 + lane + 64] = sm1;
    int qi = threadIdx.x & 63;
    int dq = threadIdx.x >> 6;                   // 0..7, 2 d's each
    #pragma unroll
    for (int d = 0; d < DK_; ++d) sacc[lane * 129 + wid * DK_ + d] = a0[d];
    __syncthreads();
    {
        int n = nb * 128 + qi;
        float* o = pp + (((size_t)bh * N_ + n) * KSP_ + ks) * PREC_;
        if (dq == 0) {
            float gsum = 0.f;
            #pragma unroll
            for (int w = 0; w < AW_; ++w) gsum += ssum[w * 128 + qi];
            o[0] = gsum;
        }
        #pragma unroll
        for (int dd = 0; dd < 2; ++dd) {
            int d = dq * 2 + dd;
            float a = 0.f;
            #pragma unroll
            for (int w = 0; w < AW_; ++w) a += sacc[qi * 129 + w * DK_ + d];
            o[1 + d] = a;
        }
    }
    __syncthreads();
    #pragma unroll
    for (int d = 0; d < DK_; ++d) sacc[lane * 129 + wid * DK_ + d] = a1[d];
    __syncthreads();
    {
        int n = nb * 128 + 64 + qi;
        float* o = pp + (((size_t)bh * N_ + n) * KSP_ + ks) * PREC_;
        if (dq == 0) {
            float gsum = 0.f;
            #pragma unroll
            for (int w = 0; w < AW_; ++w) gsum += ssum[w * 128 + qi + 64];
            o[0] = gsum;
        }
        #pragma unroll
        for (int dd = 0; dd < 2; ++dd) {
            int d = dq * 2 + dd;
            float a = 0.f;
            #pragma unroll
            for (int w = 0; w < AW_; ++w) a += sacc[qi * 129 + w * DK_ + d];
            o[1 + d] = a;
        }
    }
}

// ---------------- fused attn final-merge + residual + LayerNorm ------------
__global__ void attn_fin_ln(const float* __restrict__ pp,
                            const float* __restrict__ xin,
                            const float* __restrict__ g,
                            const float* __restrict__ bt,
                            float* __restrict__ xout) {
    int row = blockIdx.x * 4 + (threadIdx.x >> 6);   // b*N + n
    int lane = threadIdx.x & 63;
    int b = row >> 10, n = row & (N_ - 1);
    float v0, v1;
    {
        int c = lane;
        int h = c >> 4, d = c & 15;
        const float* p = pp + (((size_t)(b * 8 + h) * N_ + n) * KSP_) * PREC_;
        float gsum = 0.f, a = 0.f;
        #pragma unroll
        for (int s = 0; s < KSP_; ++s) {
            gsum += p[s * PREC_];
            a += p[s * PREC_ + 1 + d];
        }
        v0 = a / gsum + xin[(size_t)row * D_ + c];
    }
    {
        int c = lane + 64;
        int h = c >> 4, d = c & 15;
        const float* p = pp + (((size_t)(b * 8 + h) * N_ + n) * KSP_) * PREC_;
        float gsum = 0.f, a = 0.f;
        #pragma unroll
        for (int s = 0; s < KSP_; ++s) {
            gsum += p[s * PREC_];
            a += p[s * PREC_ + 1 + d];
        }
        v1 = a / gsum + xin[(size_t)row * D_ + c];
    }
    float mean = wave_sum(v0 + v1) * (1.0f / D_);
    float d0 = v0 - mean, d1 = v1 - mean;
    float var = wave_sum(d0 * d0 + d1 * d1) * (1.0f / D_);
    float rstd = rsqrtf(var + 1e-5f);
    float* orow = xout + (size_t)row * D_;
    orow[lane] = d0 * rstd * g[lane] + bt[lane];
    orow[lane + 64] = d1 * rstd * g[lane + 64] + bt[lane + 64];
}

// ---------------- column mean over N (global feature) ----------------------
__global__ void colmean_kernel(const float* __restrict__ x,
                               float* __restrict__ gc) {
    int b = blockIdx.x;
    int d = threadIdx.x & 127;
    int sl = threadIdx.x >> 7;
    __shared__ float part[4][128];
    float s = 0.f;
    const float* xb = x + (size_t)b * N_ * D_;
    for (int n = sl * 256; n < sl * 256 + 256; ++n) s += xb[(size_t)n * D_ + d];
    part[sl][d] = s;
    __syncthreads();
    if (sl == 0)
        gc[b * D_ + d] = (part[0][d] + part[1][d] + part[2][d] + part[3][d]) * (1.0f / N_);
}

// ---------------- child = pred + (h . cw + cb), interleaved x2 -------------
__global__ void child_kernel(const float* __restrict__ h,
                             const float* __restrict__ cw,
                             const float* __restrict__ cb,
                             const float* __restrict__ pred,
                             float* __restrict__ outp, int Nq) {
    int idx = blockIdx.x * blockDim.x + threadIdx.x;
    if (idx >= B_ * Nq * 6) return;
    int p = idx % 3;
    int t = (idx / 3) & 1;
    int n = (idx / 6) % Nq;
    int b = idx / (6 * Nq);
    const float* hr = h + ((size_t)b * Nq + n) * 256;
    float acc = cb[p];
    #pragma unroll 4
    for (int o = 0; o < 128; ++o) acc += hr[o * 2 + t] * cw[p * 128 + o];
    outp[idx] = pred[((size_t)b * Nq + n) * 3 + p] + acc;
}

// ---------------------------------------------------------------------------
static inline int cdiv(int a, int b) { return (a + b - 1) / b; }

extern "C" void kernel_launch(void* const* d_in, const int* in_sizes, int n_in,
                              void* d_out, int out_size, void* d_ws, size_t ws_size,
                              hipStream_t stream) {
    (void)in_sizes; (void)n_in; (void)out_size; (void)ws_size;
    const float* coords = (const float*)d_in[0];
    const float* gcn_w0 = (const float*)d_in[1];
    const float* gcn_b0 = (const float*)d_in[2];
    const float* gcn_w1 = (const float*)d_in[3];
    const float* gcn_b1 = (const float*)d_in[4];
    const float* enc_fw = (const float*)d_in[5];
    const float* enc_fb = (const float*)d_in[6];
    const float* t_wq   = (const float*)d_in[7];
    const float* t_bq   = (const float*)d_in[8];
    const float* t_wk   = (const float*)d_in[9];
    const float* t_bk   = (const float*)d_in[10];
    const float* t_wv   = (const float*)d_in[11];
    const float* t_bv   = (const float*)d_in[12];
    const float* t_alpha= (const float*)d_in[13];
    const float* t_f1w  = (const float*)d_in[14];
    const float* t_f1b  = (const float*)d_in[15];
    const float* t_f2w  = (const float*)d_in[16];
    const float* t_f2b  = (const float*)d_in[17];
    const float* t_ln1g = (const float*)d_in[18];
    const float* t_ln1b = (const float*)d_in[19];
    const float* t_ln2g = (const float*)d_in[20];
    const float* t_ln2b = (const float*)d_in[21];
    const float* dec_w1 = (const float*)d_in[22];
    const float* dec_b1 = (const float*)d_in[23];
    const float* dec_w2 = (const float*)d_in[24];
    const float* dec_b2 = (const float*)d_in[25];
    const float* st_sw1 = (const float*)d_in[26];
    const float* st_sb1 = (const float*)d_in[27];
    const float* st_sw2 = (const float*)d_in[28];
    const float* st_sb2 = (const float*)d_in[29];
    const float* st_dw  = (const float*)d_in[30];
    const float* st_db  = (const float*)d_in[31];
    const float* st_cw  = (const float*)d_in[32];
    const float* st_cb  = (const float*)d_in[33];
    float* out = (float*)d_out;

    // ---- workspace carve ----
    char* ws = (char*)d_ws;
    size_t off = 0;
    auto alloc = [&](size_t bytes) -> void* {
        void* p = ws + off;
        off += (bytes + 255) & ~(size_t)255;
        return p;
    };
    int*   knn   = (int*)  alloc((size_t)B_ * N_ * KG_ * 4);
    float* ppd   = (float*)alloc((size_t)B_ * 2048 * NCH_ * KG_ * 4);
    int*   ppi   = (int*)  alloc((size_t)B_ * 2048 * NCH_ * KG_ * 4);
    float* app   = (float*)alloc((size_t)B_ * H_ * N_ * KSP_ * PREC_ * 4);
    float* agg   = (float*)alloc((size_t)B_ * N_ * 64 * 4);
    float* x64   = (float*)alloc((size_t)B_ * N_ * 64 * 4);
    float* xb    = (float*)alloc((size_t)B_ * N_ * D_ * 4);
    float* x     = (float*)alloc((size_t)B_ * N_ * D_ * 4);
    float* q     = (float*)alloc((size_t)B_ * N_ * D_ * 4);
    float* k     = (float*)alloc((size_t)B_ * N_ * D_ * 4);
    float* v     = (float*)alloc((size_t)B_ * N_ * D_ * 4);
    float* ffh   = (float*)alloc((size_t)B_ * N_ * 512 * 4);
    float* gc    = (float*)alloc((size_t)B_ * D_ * 4);
    float* dech  = (float*)alloc((size_t)B_ * D_ * 4);
    float* pts0  = (float*)alloc((size_t)B_ * COARSE_ * 3 * 4);
    float* pts1  = (float*)alloc((size_t)B_ * 1024 * 3 * 4);
    float* pts2  = (float*)alloc((size_t)B_ * 2048 * 3 * 4);
    float* comb  = (float*)alloc((size_t)B_ * 2048 * 6 * 4);
    float* seedh = (float*)alloc((size_t)B_ * 2048 * 128 * 4);
    float* seed  = (float*)alloc((size_t)B_ * 2048 * 128 * 4);
    float* hb    = (float*)alloc((size_t)B_ * 2048 * 256 * 4);

    const int rows = B_ * N_;   // 2048

    // ---- graph encoder ----
    knn_part_kernel<<<B_ * NCH_ * 16, 64, 0, stream>>>(coords, ppd, ppi);
    knn_merge_kernel<<<B_ * N_ / MQ_, 256, 0, stream>>>(ppd, ppi, knn);
    gcn_agg_kernel<<<cdiv(rows * 3, 256), 256, 0, stream>>>(coords, knn, agg, 3);
    linear4_kernel<true><<<cdiv(rows * 16, 256), 256, 0, stream>>>(agg, gcn_w0, gcn_b0, x64, rows, 3, 64);
    gcn_agg_kernel<<<cdiv(rows * 64, 256), 256, 0, stream>>>(x64, knn, agg, 64);
    gemm128_kernel<64, true, false><<<dim3(rows / 8, 1), 256, 0, stream>>>(agg, gcn_w1, gcn_b1, xb, 128, 128);
    gemm128_kernel<128, false, false><<<dim3(rows / 8, 1), 256, 0, stream>>>(xb, enc_fw, enc_fb, x, 128, 128);

    // ---- transformer ----
    for (int i = 0; i < L_; ++i) {
        qkv3_kernel<<<dim3(rows / 8, 3), 256, 0, stream>>>(
            x, t_wq + i * 16384, t_bq + i * 128, t_wk + i * 16384, t_bk + i * 128,
            t_wv + i * 16384, t_bv + i * 128, q, k, v);
        attn_part<<<B_ * H_ * (N_ / 128) * KSP_, 512, 0, stream>>>(q, k, v, coords, t_alpha, i, app);
        attn_fin_ln<<<rows / 4, 256, 0, stream>>>(app, x, t_ln1g + i * 128, t_ln1b + i * 128, x);
        gemm128_kernel<128, true, false><<<dim3(rows / 8, 4), 256, 0, stream>>>(x, t_f1w + i * 128 * 512, t_f1b + i * 512, ffh, 512, 512);
        gemm_ln_kernel<512><<<rows / 8, 256, 0, stream>>>(ffh, t_f2w + i * 512 * 128, t_f2b + i * 128, x, t_ln2g + i * 128, t_ln2b + i * 128, x);
    }

    // ---- decoder coarse ----
    colmean_kernel<<<B_, 512, 0, stream>>>(x, gc);
    linear4_kernel<true><<<cdiv(B_ * 32, 256), 256, 0, stream>>>(gc, dec_w1, dec_b1, dech, B_, 128, 128);
    linear4_kernel<false><<<cdiv(B_ * 384, 256), 256, 0, stream>>>(dech, dec_w2, dec_b2, pts0, B_, 128, 1536);

    // ---- refine stages ----
    const float* pred = pts0;
    float* outs[3] = { pts1, pts2, out };
    int Nq = COARSE_;
    for (int s = 0; s < 3; ++s) {
        loc_part_kernel<<<dim3(Nq / 64, NCH_, B_), 64, 0, stream>>>(coords, pred, ppd, ppi, Nq);
        loc_merge_kernel<<<(B_ * Nq) / MQ_, 256, 0, stream>>>(coords, pred, ppd, ppi, comb, Nq);
        int srows = B_ * Nq;
        linear4_kernel<true><<<cdiv(srows * 32, 256), 256, 0, stream>>>(comb, st_sw1 + s * 6 * 128, st_sb1 + s * 128, seedh, srows, 6, 128);
        gemm128_kernel<128, false, false><<<dim3(srows / 8, 1), 256, 0, stream>>>(seedh, st_sw2 + s * 128 * 128, st_sb2 + s * 128, seed, 128, 128);
        gemm128_kernel<128, true, true><<<dim3(srows / 8, 2), 256, 0, stream>>>(seed, st_dw + s * 128 * 256, st_db + s * 128, hb, 256, 256);
        child_kernel<<<cdiv(srows * 6, 256), 256, 0, stream>>>(hb, st_cw + s * 3 * 128, st_cb + s * 3, pred, outs[s], Nq);
        pred = outs[s];
        Nq <<= 1;
    }
}

// Round 15
// 500.616 us; speedup vs baseline: 1.3118x; 1.0986x over previous
//
#include <hip/hip_runtime.h>

// ---------------------------------------------------------------------------
// FullModelSnowflake.  R14: wave-parallel KNN merges — one wave per query,
// candidates in registers, k rounds of butterfly min-extraction on the
// lexicographic (dist,idx) key.  Replaces the 1.3%-occupancy thread-serial
// merges (knn_merge was 42us, the largest dispatch).
// ---------------------------------------------------------------------------

#define B_ 2
#define N_ 1024
#define D_ 128
#define H_ 8
#define DK_ 16
#define L_ 4
#define KG_ 16
#define KLOC_ 8
#define COARSE_ 512
#define NCH_ 16          // candidate chunks (64 candidates each)
#define AW_ 8            // waves per attention block
#define KSP_ 4           // block-level key splits
#define PREC_ 17         // floats per attention partial (sum + 16 acc)

static __device__ __forceinline__ float wave_sum(float v) {
    #pragma unroll
    for (int off = 32; off > 0; off >>= 1) v += __shfl_xor(v, off);
    return v;
}
static __device__ __forceinline__ float half_sum(float v) {
    #pragma unroll
    for (int off = 16; off > 0; off >>= 1) v += __shfl_xor(v, off);
    return v;
}

// ---------------- LDS-staged GEMM body: returns this thread's acc ----------
template <int CIN, bool RELU, bool BIAS_HALF>
static __device__ __forceinline__ float4 gemm_body(
        const float* __restrict__ X, const float* __restrict__ W,
        const float* __restrict__ bias, int wstride, int col0) {
    __shared__ float Xs[8 * CIN];
    __shared__ float Ws[64][128];
    int tid = threadIdx.x;
    int row0 = blockIdx.x * 8;
    constexpr int NX4 = 2 * CIN;
    {
        const float4* xg = (const float4*)(X + (size_t)row0 * CIN);
        float4* xs4 = (float4*)Xs;
        #pragma unroll
        for (int i = 0; i < (NX4 + 255) / 256; ++i) {
            int t = tid + i * 256;
            if ((NX4 % 256 == 0) || t < NX4) xs4[t] = xg[t];
        }
    }
    int col4 = (tid & 31) << 2;
    int rowl = tid >> 5;
    float4 acc;
    if (BIAS_HALF) {
        acc.x = bias[(col0 + col4) >> 1];
        acc.y = bias[(col0 + col4 + 1) >> 1];
        acc.z = bias[(col0 + col4 + 2) >> 1];
        acc.w = bias[(col0 + col4 + 3) >> 1];
    } else {
        acc = *(const float4*)(bias + col0 + col4);
    }
    for (int c0 = 0; c0 < CIN; c0 += 64) {
        __syncthreads();
        #pragma unroll
        for (int i = 0; i < 8; ++i) {
            int flat = tid + i * 256;
            int wr = flat >> 5, wc = (flat & 31) << 2;
            *(float4*)&Ws[wr][wc] =
                *(const float4*)(W + (size_t)(c0 + wr) * wstride + col0 + wc);
        }
        __syncthreads();
        const float* xrow = Xs + rowl * CIN + c0;
        #pragma unroll
        for (int c = 0; c < 64; ++c) {
            float xv = xrow[c];
            float4 w = *(const float4*)&Ws[c][col4];
            acc.x += xv * w.x; acc.y += xv * w.y;
            acc.z += xv * w.z; acc.w += xv * w.w;
        }
    }
    if (RELU) {
        acc.x = fmaxf(acc.x, 0.f); acc.y = fmaxf(acc.y, 0.f);
        acc.z = fmaxf(acc.z, 0.f); acc.w = fmaxf(acc.w, 0.f);
    }
    return acc;
}

template <int CIN, bool RELU, bool BIAS_HALF>
__global__ __launch_bounds__(256) void gemm128_kernel(
        const float* __restrict__ X, const float* __restrict__ W,
        const float* __restrict__ bias, float* __restrict__ Y,
        int wstride, int ystride) {
    int col0 = blockIdx.y * 128;
    float4 acc = gemm_body<CIN, RELU, BIAS_HALF>(X, W, bias, wstride, col0);
    int col4 = (threadIdx.x & 31) << 2;
    int row = blockIdx.x * 8 + (threadIdx.x >> 5);
    *(float4*)(Y + (size_t)row * ystride + col0 + col4) = acc;
}

// GEMM (Cout=128) fused with residual-add + LayerNorm epilogue.
template <int CIN>
__global__ __launch_bounds__(256) void gemm_ln_kernel(
        const float* __restrict__ X, const float* __restrict__ W,
        const float* __restrict__ bias, const float* __restrict__ res,
        const float* __restrict__ g, const float* __restrict__ bt,
        float* __restrict__ Y) {
    float4 acc = gemm_body<CIN, false, false>(X, W, bias, 128, 0);
    int col4 = (threadIdx.x & 31) << 2;
    int row = blockIdx.x * 8 + (threadIdx.x >> 5);
    float4 r = *(const float4*)(res + (size_t)row * D_ + col4);
    acc.x += r.x; acc.y += r.y; acc.z += r.z; acc.w += r.w;
    float mean = half_sum(acc.x + acc.y + acc.z + acc.w) * (1.0f / D_);
    float dx = acc.x - mean, dy = acc.y - mean, dz = acc.z - mean, dw = acc.w - mean;
    float var = half_sum(dx * dx + dy * dy + dz * dz + dw * dw) * (1.0f / D_);
    float rstd = rsqrtf(var + 1e-5f);
    float4 gv = *(const float4*)(g + col4);
    float4 bv = *(const float4*)(bt + col4);
    float4 o;
    o.x = dx * rstd * gv.x + bv.x;
    o.y = dy * rstd * gv.y + bv.y;
    o.z = dz * rstd * gv.z + bv.z;
    o.w = dw * rstd * gv.w + bv.w;
    *(float4*)(Y + (size_t)row * D_ + col4) = o;
}

// fused QKV: 3 W-panels via blockIdx.y; outputs stored HEAD-MAJOR [bh][n][16]
__global__ __launch_bounds__(256) void qkv3_kernel(
        const float* __restrict__ X,
        const float* __restrict__ Wq, const float* __restrict__ bq,
        const float* __restrict__ Wk, const float* __restrict__ bk,
        const float* __restrict__ Wv, const float* __restrict__ bv,
        float* __restrict__ Q, float* __restrict__ K, float* __restrict__ V) {
    const float* W; const float* bias; float* Y;
    if (blockIdx.y == 0)      { W = Wq; bias = bq; Y = Q; }
    else if (blockIdx.y == 1) { W = Wk; bias = bk; Y = K; }
    else                      { W = Wv; bias = bv; Y = V; }
    float4 acc = gemm_body<128, false, false>(X, W, bias, 128, 0);
    int col4 = (threadIdx.x & 31) << 2;
    int row = blockIdx.x * 8 + (threadIdx.x >> 5);
    int b = row >> 10, n = row & (N_ - 1);
    int h = col4 >> 4, d = col4 & 15;
    *(float4*)(Y + (((size_t)(b * 8 + h) * N_ + n) << 4) + d) = acc;
}

// ---------------- KNN pass 1: per-chunk partial top-16 ---------------------
__global__ void knn_part_kernel(const float* __restrict__ coords,
                                float* __restrict__ pd, int* __restrict__ pi) {
    int blk = blockIdx.x;
    int qb = blk & 15;
    int ch = (blk >> 4) & 15;
    int b = blk >> 8;
    int lane = threadIdx.x;
    int q = qb * 64 + lane;
    __shared__ float4 sc[64];
    const float* cb = coords + (size_t)b * N_ * 3;
    {
        int m = ch * 64 + lane;
        float x = cb[m * 3], y = cb[m * 3 + 1], z = cb[m * 3 + 2];
        sc[lane] = make_float4(x, y, z, x * x + y * y + z * z);
    }
    __syncthreads();
    float qx = cb[q * 3], qy = cb[q * 3 + 1], qz = cb[q * 3 + 2];
    float q2 = qx * qx + qy * qy + qz * qz;
    float bd[KG_]; int bi[KG_];
    #pragma unroll
    for (int j = 0; j < KG_; ++j) { bd[j] = 3e38f; bi[j] = 0; }
    for (int j = 0; j < 64; ++j) {
        int m = ch * 64 + j;
        float4 c = sc[j];
        float dot = qx * c.x + qy * c.y + qz * c.z;
        float d = (q2 - 2.0f * dot) + c.w;
        d = (m == q) ? 3e38f : d;
        if (d < bd[KG_ - 1]) {
            #pragma unroll
            for (int jj = KG_ - 1; jj > 0; --jj) {
                bool shf = d < bd[jj - 1];
                bool plc = !shf && (d < bd[jj]);
                bd[jj] = shf ? bd[jj - 1] : (plc ? d : bd[jj]);
                bi[jj] = shf ? bi[jj - 1] : (plc ? m : bi[jj]);
            }
            if (d < bd[0]) { bd[0] = d; bi[0] = m; }
        }
    }
    size_t base = (((size_t)b * N_ + q) * NCH_ + ch) * KG_;
    #pragma unroll
    for (int j = 0; j < KG_; ++j) { pd[base + j] = bd[j]; pi[base + j] = bi[j]; }
}

// ---------------- KNN pass 2: wave-parallel min-extraction merge -----------
// One wave per query: lane holds 4 of the 256 candidates in registers;
// 16 rounds of {lane-local min, butterfly min on (d,idx), invalidate}.
__global__ __launch_bounds__(256) void knn_merge_kernel(
        const float* __restrict__ pd, const int* __restrict__ pi,
        int* __restrict__ knn) {
    int wid = threadIdx.x >> 6;
    int lane = threadIdx.x & 63;
    size_t q = (size_t)blockIdx.x * 4 + wid;
    const float* cd = pd + q * (NCH_ * KG_);
    const int* ci = pi + q * (NCH_ * KG_);
    float ld[4]; int li[4];
    #pragma unroll
    for (int j = 0; j < 4; ++j) { ld[j] = cd[lane + j * 64]; li[j] = ci[lane + j * 64]; }
    int* o = knn + q * KG_;
    #pragma unroll
    for (int r = 0; r < KG_; ++r) {
        float dm = ld[0]; int im = li[0];
        #pragma unroll
        for (int j = 1; j < 4; ++j) {
            bool lt = (ld[j] < dm) || (ld[j] == dm && li[j] < im);
            dm = lt ? ld[j] : dm; im = lt ? li[j] : im;
        }
        #pragma unroll
        for (int off = 32; off > 0; off >>= 1) {
            float d2 = __shfl_xor(dm, off); int i2 = __shfl_xor(im, off);
            bool lt = (d2 < dm) || (d2 == dm && i2 < im);
            dm = lt ? d2 : dm; im = lt ? i2 : im;
        }
        if (lane == 0) o[r] = im;
        #pragma unroll
        for (int j = 0; j < 4; ++j) if (li[j] == im) ld[j] = 3e38f;
    }
}

// ---------------- local KNN pass 1 (k=8) -----------------------------------
__global__ void loc_part_kernel(const float* __restrict__ part,
                                const float* __restrict__ pred,
                                float* __restrict__ pd, int* __restrict__ pi,
                                int Nq) {
    int qb = blockIdx.x, ch = blockIdx.y, b = blockIdx.z;
    int lane = threadIdx.x;
    int q = qb * 64 + lane;
    __shared__ float4 sc[64];
    const float* pb = part + (size_t)b * N_ * 3;
    {
        int m = ch * 64 + lane;
        float x = pb[m * 3], y = pb[m * 3 + 1], z = pb[m * 3 + 2];
        sc[lane] = make_float4(x, y, z, x * x + y * y + z * z);
    }
    __syncthreads();
    const float* pr = pred + ((size_t)b * Nq + q) * 3;
    float qx = pr[0], qy = pr[1], qz = pr[2];
    float q2 = qx * qx + qy * qy + qz * qz;
    float bd[KLOC_]; int bi[KLOC_];
    #pragma unroll
    for (int j = 0; j < KLOC_; ++j) { bd[j] = 3e38f; bi[j] = 0; }
    for (int j = 0; j < 64; ++j) {
        float4 c = sc[j];
        float dot = qx * c.x + qy * c.y + qz * c.z;
        float d = (q2 - 2.0f * dot) + c.w;
        if (d < bd[KLOC_ - 1]) {
            int m = ch * 64 + j;
            #pragma unroll
            for (int jj = KLOC_ - 1; jj > 0; --jj) {
                bool shf = d < bd[jj - 1];
                bool plc = !shf && (d < bd[jj]);
                bd[jj] = shf ? bd[jj - 1] : (plc ? d : bd[jj]);
                bi[jj] = shf ? bi[jj - 1] : (plc ? m : bi[jj]);
            }
            if (d < bd[0]) { bd[0] = d; bi[0] = m; }
        }
    }
    size_t base = (((size_t)b * Nq + q) * NCH_ + ch) * KLOC_;
    #pragma unroll
    for (int j = 0; j < KLOC_; ++j) { pd[base + j] = bd[j]; pi[base + j] = bi[j]; }
}

// ---------------- local KNN pass 2: wave-parallel merge + mean + comb ------
// One wave per query: lane holds 2 of 128 candidates; 8 extraction rounds.
// Neighbor coords accumulated via broadcast (same-address) loads on all
// lanes so no runtime-indexed array is needed.
__global__ __launch_bounds__(256) void loc_merge_kernel(
        const float* __restrict__ part, const float* __restrict__ pred,
        const float* __restrict__ pd, const int* __restrict__ pi,
        float* __restrict__ comb, int Nq) {
    int wid = threadIdx.x >> 6;
    int lane = threadIdx.x & 63;
    size_t q = (size_t)blockIdx.x * 4 + wid;
    const float* cd = pd + q * (NCH_ * KLOC_);
    const int* ci = pi + q * (NCH_ * KLOC_);
    float ld0 = cd[lane], ld1 = cd[lane + 64];
    int li0 = ci[lane], li1 = ci[lane + 64];
    int b = (int)(q / Nq);
    const float* pb = part + (size_t)b * N_ * 3;
    float sx = 0.f, sy = 0.f, sz = 0.f;
    #pragma unroll
    for (int r = 0; r < KLOC_; ++r) {
        float dm = ld0; int im = li0;
        {
            bool lt = (ld1 < dm) || (ld1 == dm && li1 < im);
            dm = lt ? ld1 : dm; im = lt ? li1 : im;
        }
        #pragma unroll
        for (int off = 32; off > 0; off >>= 1) {
            float d2 = __shfl_xor(dm, off); int i2 = __shfl_xor(im, off);
            bool lt = (d2 < dm) || (d2 == dm && i2 < im);
            dm = lt ? d2 : dm; im = lt ? i2 : im;
        }
        sx += pb[im * 3]; sy += pb[im * 3 + 1]; sz += pb[im * 3 + 2];
        if (li0 == im) ld0 = 3e38f;
        if (li1 == im) ld1 = 3e38f;
    }
    if (lane == 0) {
        const float* pr = pred + q * 3;
        float* o = comb + q * 6;
        o[0] = pr[0]; o[1] = pr[1]; o[2] = pr[2];
        o[3] = sx * (1.0f / KLOC_); o[4] = sy * (1.0f / KLOC_); o[5] = sz * (1.0f / KLOC_);
    }
}

// ---------------- GCN aggregation: (x + sum_nb) / (k+1) --------------------
__global__ void gcn_agg_kernel(const float* __restrict__ x,
                               const int* __restrict__ knn,
                               float* __restrict__ agg, int C) {
    int i = blockIdx.x * blockDim.x + threadIdx.x;
    if (i >= B_ * N_ * C) return;
    int c = i % C;
    int n = (i / C) % N_;
    int b = i / (C * N_);
    const int* id = knn + ((size_t)b * N_ + n) * KG_;
    float s = x[((size_t)b * N_ + n) * C + c];
    #pragma unroll
    for (int j = 0; j < KG_; ++j) s += x[((size_t)b * N_ + id[j]) * C + c];
    agg[i] = s * (1.0f / (KG_ + 1));
}

// ---------------- linear: 4 outputs per thread (small cases) ---------------
template <bool RELU>
__global__ void linear4_kernel(const float* __restrict__ X,
                               const float* __restrict__ W,
                               const float* __restrict__ bias,
                               float* __restrict__ Y,
                               int rows, int Cin, int Cout) {
    int co4 = Cout >> 2;
    int idx = blockIdx.x * blockDim.x + threadIdx.x;
    if (idx >= rows * co4) return;
    int r = idx / co4, o4 = (idx - r * co4) << 2;
    const float* x = X + (size_t)r * Cin;
    float4 acc = *(const float4*)(bias + o4);
    #pragma unroll 4
    for (int c = 0; c < Cin; ++c) {
        float xv = x[c];
        float4 w = *(const float4*)(W + (size_t)c * Cout + o4);
        acc.x += xv * w.x; acc.y += xv * w.y; acc.z += xv * w.z; acc.w += xv * w.w;
    }
    if (RELU) {
        acc.x = fmaxf(acc.x, 0.f); acc.y = fmaxf(acc.y, 0.f);
        acc.z = fmaxf(acc.z, 0.f); acc.w = fmaxf(acc.w, 0.f);
    }
    *(float4*)(Y + (size_t)r * Cout + o4) = acc;
}

// ---------------- attention: head-major QKV, LDS-staged K/V ----------------
__global__ __launch_bounds__(512) void attn_part(
        const float* __restrict__ q,
        const float* __restrict__ k,
        const float* __restrict__ v,
        const float* __restrict__ coords,
        const float* __restrict__ alphap, int layer,
        float* __restrict__ pp) {
    __shared__ float smem[9280];                 // stage 8192 | merge 9280
    float* kst = smem;                           // [256][16]
    float* vst = smem + 4096;                    // [256][16]
    float* ssum = smem;                          // [8][128]   (merge phase)
    float* sacc = smem + 1024;                   // [64][129]
    int bh = blockIdx.x & 15;          // b*8 + h
    int t = blockIdx.x >> 4;           // nb*KSP + ks
    int ks = t & (KSP_ - 1);
    int nb = t >> 2;                   // log2(KSP_) = 2
    int b = bh >> 3;
    int wid = threadIdx.x >> 6;
    int lane = threadIdx.x & 63;
    int n0 = nb * 128 + lane;          // second query: n0 + 64
    float alpha = alphap[layer];
    // ---- stage K/V slice (contiguous head-major) ----
    {
        const float4* kg = (const float4*)(k + (((size_t)bh * N_ + ks * 256) << 4));
        const float4* vg = (const float4*)(v + (((size_t)bh * N_ + ks * 256) << 4));
        float4* ks4 = (float4*)kst;
        float4* vs4 = (float4*)vst;
        #pragma unroll
        for (int i = 0; i < 2; ++i) {
            int idx = threadIdx.x + i * 512;
            ks4[idx] = kg[idx];
            vs4[idx] = vg[idx];
        }
    }
    const float* qp0 = q + (((size_t)bh * N_ + n0) << 4);
    const float* qp1 = qp0 + (64 << 4);
    float qv0[DK_], qv1[DK_];
    #pragma unroll
    for (int d = 0; d < DK_; ++d) { qv0[d] = qp0[d]; qv1[d] = qp1[d]; }
    const float* cb = coords + (size_t)b * N_ * 3;
    float c0x = cb[n0 * 3], c0y = cb[n0 * 3 + 1], c0z = cb[n0 * 3 + 2];
    float c1x = cb[(n0 + 64) * 3], c1y = cb[(n0 + 64) * 3 + 1], c1z = cb[(n0 + 64) * 3 + 2];
    float sm0 = 0.f, sm1 = 0.f;
    float a0[DK_], a1[DK_];
    #pragma unroll
    for (int d = 0; d < DK_; ++d) { a0[d] = 0.f; a1[d] = 0.f; }
    __syncthreads();                             // stage visible
    int mbase = ks * 256 + wid * 32;             // global key index base
    int lbase = wid * 32;                        // stage-local base
    #pragma unroll 4
    for (int j = 0; j < 32; ++j) {
        const float4* kr = (const float4*)(kst + ((lbase + j) << 4));
        float4 k0 = kr[0], k1 = kr[1], k2 = kr[2], k3 = kr[3];
        float d0 = qv0[0] * k0.x + qv0[1] * k0.y + qv0[2] * k0.z + qv0[3] * k0.w
                 + qv0[4] * k1.x + qv0[5] * k1.y + qv0[6] * k1.z + qv0[7] * k1.w
                 + qv0[8] * k2.x + qv0[9] * k2.y + qv0[10] * k2.z + qv0[11] * k2.w
                 + qv0[12] * k3.x + qv0[13] * k3.y + qv0[14] * k3.z + qv0[15] * k3.w;
        float d1 = qv1[0] * k0.x + qv1[1] * k0.y + qv1[2] * k0.z + qv1[3] * k0.w
                 + qv1[4] * k1.x + qv1[5] * k1.y + qv1[6] * k1.z + qv1[7] * k1.w
                 + qv1[8] * k2.x + qv1[9] * k2.y + qv1[10] * k2.z + qv1[11] * k2.w
                 + qv1[12] * k3.x + qv1[13] * k3.y + qv1[14] * k3.z + qv1[15] * k3.w;
        int m = mbase + j;
        float wx = cb[m * 3], wy = cb[m * 3 + 1], wz = cb[m * 3 + 2];
        float p0 = __expf(d0 * 0.25f + alpha * (wx * c0x + wy * c0y + wz * c0z));
        float p1 = __expf(d1 * 0.25f + alpha * (wx * c1x + wy * c1y + wz * c1z));
        sm0 += p0; sm1 += p1;
        const float4* vr = (const float4*)(vst + ((lbase + j) << 4));
        float4 v0 = vr[0], v1 = vr[1], v2 = vr[2], v3 = vr[3];
        a0[0] += p0 * v0.x;  a0[1] += p0 * v0.y;  a0[2] += p0 * v0.z;  a0[3] += p0 * v0.w;
        a0[4] += p0 * v1.x;  a0[5] += p0 * v1.y;  a0[6] += p0 * v1.z;  a0[7] += p0 * v1.w;
        a0[8] += p0 * v2.x;  a0[9] += p0 * v2.y;  a0[10] += p0 * v2.z; a0[11] += p0 * v2.w;
        a0[12] += p0 * v3.x; a0[13] += p0 * v3.y; a0[14] += p0 * v3.z; a0[15] += p0 * v3.w;
        a1[0] += p1 * v0.x;  a1[1] += p1 * v0.y;  a1[2] += p1 * v0.z;  a1[3] += p1 * v0.w;
        a1[4] += p1 * v1.x;  a1[5] += p1 * v1.y;  a1[6] += p1 * v1.z;  a1[7] += p1 * v1.w;
        a1[8] += p1 * v2.x;  a1[9] += p1 * v2.y;  a1[10] += p1 * v2.z; a1[11] += p1 * v2.w;
        a1[12] += p1 * v3.x; a1[13] += p1 * v3.y; a1[14] += p1 * v3.z; a1[15] += p1 * v3.w;
    }
    __syncthreads();                             // done reading stage
    // ---- two-round merge (reuses smem) ----
    ssum[wid * 128 + lane] = sm0;
    ssum[wid * 128 + lane + 64] = sm1;
    int qi = threadIdx.x & 63;
    int dq = threadIdx.x >> 6;                   // 0..7, 2 d's each
    #pragma unroll
    for (int d = 0; d < DK_; ++d) sacc[lane * 129 + wid * DK_ + d] = a0[d];
    __syncthreads();
    {
        int n = nb * 128 + qi;
        float* o = pp + (((size_t)bh * N_ + n) * KSP_ + ks) * PREC_;
        if (dq == 0) {
            float gsum = 0.f;
            #pragma unroll
            for (int w = 0; w < AW_; ++w) gsum += ssum[w * 128 + qi];
            o[0] = gsum;
        }
        #pragma unroll
        for (int dd = 0; dd < 2; ++dd) {
            int d = dq * 2 + dd;
            float a = 0.f;
            #pragma unroll
            for (int w = 0; w < AW_; ++w) a += sacc[qi * 129 + w * DK_ + d];
            o[1 + d] = a;
        }
    }
    __syncthreads();
    #pragma unroll
    for (int d = 0; d < DK_; ++d) sacc[lane * 129 + wid * DK_ + d] = a1[d];
    __syncthreads();
    {
        int n = nb * 128 + 64 + qi;
        float* o = pp + (((size_t)bh * N_ + n) * KSP_ + ks) * PREC_;
        if (dq == 0) {
            float gsum = 0.f;
            #pragma unroll
            for (int w = 0; w < AW_; ++w) gsum += ssum[w * 128 + qi + 64];
            o[0] = gsum;
        }
        #pragma unroll
        for (int dd = 0; dd < 2; ++dd) {
            int d = dq * 2 + dd;
            float a = 0.f;
            #pragma unroll
            for (int w = 0; w < AW_; ++w) a += sacc[qi * 129 + w * DK_ + d];
            o[1 + d] = a;
        }
    }
}

// ---------------- fused attn final-merge + residual + LayerNorm ------------
__global__ void attn_fin_ln(const float* __restrict__ pp,
                            const float* __restrict__ xin,
                            const float* __restrict__ g,
                            const float* __restrict__ bt,
                            float* __restrict__ xout) {
    int row = blockIdx.x * 4 + (threadIdx.x >> 6);   // b*N + n
    int lane = threadIdx.x & 63;
    int b = row >> 10, n = row & (N_ - 1);
    float v0, v1;
    {
        int c = lane;
        int h = c >> 4, d = c & 15;
        const float* p = pp + (((size_t)(b * 8 + h) * N_ + n) * KSP_) * PREC_;
        float gsum = 0.f, a = 0.f;
        #pragma unroll
        for (int s = 0; s < KSP_; ++s) {
            gsum += p[s * PREC_];
            a += p[s * PREC_ + 1 + d];
        }
        v0 = a / gsum + xin[(size_t)row * D_ + c];
    }
    {
        int c = lane + 64;
        int h = c >> 4, d = c & 15;
        const float* p = pp + (((size_t)(b * 8 + h) * N_ + n) * KSP_) * PREC_;
        float gsum = 0.f, a = 0.f;
        #pragma unroll
        for (int s = 0; s < KSP_; ++s) {
            gsum += p[s * PREC_];
            a += p[s * PREC_ + 1 + d];
        }
        v1 = a / gsum + xin[(size_t)row * D_ + c];
    }
    float mean = wave_sum(v0 + v1) * (1.0f / D_);
    float d0 = v0 - mean, d1 = v1 - mean;
    float var = wave_sum(d0 * d0 + d1 * d1) * (1.0f / D_);
    float rstd = rsqrtf(var + 1e-5f);
    float* orow = xout + (size_t)row * D_;
    orow[lane] = d0 * rstd * g[lane] + bt[lane];
    orow[lane + 64] = d1 * rstd * g[lane + 64] + bt[lane + 64];
}

// ---------------- column mean over N (global feature) ----------------------
__global__ void colmean_kernel(const float* __restrict__ x,
                               float* __restrict__ gc) {
    int b = blockIdx.x;
    int d = threadIdx.x & 127;
    int sl = threadIdx.x >> 7;
    __shared__ float part[4][128];
    float s = 0.f;
    const float* xb = x + (size_t)b * N_ * D_;
    for (int n = sl * 256; n < sl * 256 + 256; ++n) s += xb[(size_t)n * D_ + d];
    part[sl][d] = s;
    __syncthreads();
    if (sl == 0)
        gc[b * D_ + d] = (part[0][d] + part[1][d] + part[2][d] + part[3][d]) * (1.0f / N_);
}

// ---------------- child = pred + (h . cw + cb), interleaved x2 -------------
__global__ void child_kernel(const float* __restrict__ h,
                             const float* __restrict__ cw,
                             const float* __restrict__ cb,
                             const float* __restrict__ pred,
                             float* __restrict__ outp, int Nq) {
    int idx = blockIdx.x * blockDim.x + threadIdx.x;
    if (idx >= B_ * Nq * 6) return;
    int p = idx % 3;
    int t = (idx / 3) & 1;
    int n = (idx / 6) % Nq;
    int b = idx / (6 * Nq);
    const float* hr = h + ((size_t)b * Nq + n) * 256;
    float acc = cb[p];
    #pragma unroll 4
    for (int o = 0; o < 128; ++o) acc += hr[o * 2 + t] * cw[p * 128 + o];
    outp[idx] = pred[((size_t)b * Nq + n) * 3 + p] + acc;
}

// ---------------------------------------------------------------------------
static inline int cdiv(int a, int b) { return (a + b - 1) / b; }

extern "C" void kernel_launch(void* const* d_in, const int* in_sizes, int n_in,
                              void* d_out, int out_size, void* d_ws, size_t ws_size,
                              hipStream_t stream) {
    (void)in_sizes; (void)n_in; (void)out_size; (void)ws_size;
    const float* coords = (const float*)d_in[0];
    const float* gcn_w0 = (const float*)d_in[1];
    const float* gcn_b0 = (const float*)d_in[2];
    const float* gcn_w1 = (const float*)d_in[3];
    const float* gcn_b1 = (const float*)d_in[4];
    const float* enc_fw = (const float*)d_in[5];
    const float* enc_fb = (const float*)d_in[6];
    const float* t_wq   = (const float*)d_in[7];
    const float* t_bq   = (const float*)d_in[8];
    const float* t_wk   = (const float*)d_in[9];
    const float* t_bk   = (const float*)d_in[10];
    const float* t_wv   = (const float*)d_in[11];
    const float* t_bv   = (const float*)d_in[12];
    const float* t_alpha= (const float*)d_in[13];
    const float* t_f1w  = (const float*)d_in[14];
    const float* t_f1b  = (const float*)d_in[15];
    const float* t_f2w  = (const float*)d_in[16];
    const float* t_f2b  = (const float*)d_in[17];
    const float* t_ln1g = (const float*)d_in[18];
    const float* t_ln1b = (const float*)d_in[19];
    const float* t_ln2g = (const float*)d_in[20];
    const float* t_ln2b = (const float*)d_in[21];
    const float* dec_w1 = (const float*)d_in[22];
    const float* dec_b1 = (const float*)d_in[23];
    const float* dec_w2 = (const float*)d_in[24];
    const float* dec_b2 = (const float*)d_in[25];
    const float* st_sw1 = (const float*)d_in[26];
    const float* st_sb1 = (const float*)d_in[27];
    const float* st_sw2 = (const float*)d_in[28];
    const float* st_sb2 = (const float*)d_in[29];
    const float* st_dw  = (const float*)d_in[30];
    const float* st_db  = (const float*)d_in[31];
    const float* st_cw  = (const float*)d_in[32];
    const float* st_cb  = (const float*)d_in[33];
    float* out = (float*)d_out;

    // ---- workspace carve ----
    char* ws = (char*)d_ws;
    size_t off = 0;
    auto alloc = [&](size_t bytes) -> void* {
        void* p = ws + off;
        off += (bytes + 255) & ~(size_t)255;
        return p;
    };
    int*   knn   = (int*)  alloc((size_t)B_ * N_ * KG_ * 4);
    float* ppd   = (float*)alloc((size_t)B_ * 2048 * NCH_ * KG_ * 4);
    int*   ppi   = (int*)  alloc((size_t)B_ * 2048 * NCH_ * KG_ * 4);
    float* app   = (float*)alloc((size_t)B_ * H_ * N_ * KSP_ * PREC_ * 4);
    float* agg   = (float*)alloc((size_t)B_ * N_ * 64 * 4);
    float* x64   = (float*)alloc((size_t)B_ * N_ * 64 * 4);
    float* xb    = (float*)alloc((size_t)B_ * N_ * D_ * 4);
    float* x     = (float*)alloc((size_t)B_ * N_ * D_ * 4);
    float* q     = (float*)alloc((size_t)B_ * N_ * D_ * 4);
    float* k     = (float*)alloc((size_t)B_ * N_ * D_ * 4);
    float* v     = (float*)alloc((size_t)B_ * N_ * D_ * 4);
    float* ffh   = (float*)alloc((size_t)B_ * N_ * 512 * 4);
    float* gc    = (float*)alloc((size_t)B_ * D_ * 4);
    float* dech  = (float*)alloc((size_t)B_ * D_ * 4);
    float* pts0  = (float*)alloc((size_t)B_ * COARSE_ * 3 * 4);
    float* pts1  = (float*)alloc((size_t)B_ * 1024 * 3 * 4);
    float* pts2  = (float*)alloc((size_t)B_ * 2048 * 3 * 4);
    float* comb  = (float*)alloc((size_t)B_ * 2048 * 6 * 4);
    float* seedh = (float*)alloc((size_t)B_ * 2048 * 128 * 4);
    float* seed  = (float*)alloc((size_t)B_ * 2048 * 128 * 4);
    float* hb    = (float*)alloc((size_t)B_ * 2048 * 256 * 4);

    const int rows = B_ * N_;   // 2048

    // ---- graph encoder ----
    knn_part_kernel<<<B_ * NCH_ * 16, 64, 0, stream>>>(coords, ppd, ppi);
    knn_merge_kernel<<<B_ * N_ / 4, 256, 0, stream>>>(ppd, ppi, knn);
    gcn_agg_kernel<<<cdiv(rows * 3, 256), 256, 0, stream>>>(coords, knn, agg, 3);
    linear4_kernel<true><<<cdiv(rows * 16, 256), 256, 0, stream>>>(agg, gcn_w0, gcn_b0, x64, rows, 3, 64);
    gcn_agg_kernel<<<cdiv(rows * 64, 256), 256, 0, stream>>>(x64, knn, agg, 64);
    gemm128_kernel<64, true, false><<<dim3(rows / 8, 1), 256, 0, stream>>>(agg, gcn_w1, gcn_b1, xb, 128, 128);
    gemm128_kernel<128, false, false><<<dim3(rows / 8, 1), 256, 0, stream>>>(xb, enc_fw, enc_fb, x, 128, 128);

    // ---- transformer ----
    for (int i = 0; i < L_; ++i) {
        qkv3_kernel<<<dim3(rows / 8, 3), 256, 0, stream>>>(
            x, t_wq + i * 16384, t_bq + i * 128, t_wk + i * 16384, t_bk + i * 128,
            t_wv + i * 16384, t_bv + i * 128, q, k, v);
        attn_part<<<B_ * H_ * (N_ / 128) * KSP_, 512, 0, stream>>>(q, k, v, coords, t_alpha, i, app);
        attn_fin_ln<<<rows / 4, 256, 0, stream>>>(app, x, t_ln1g + i * 128, t_ln1b + i * 128, x);
        gemm128_kernel<128, true, false><<<dim3(rows / 8, 4), 256, 0, stream>>>(x, t_f1w + i * 128 * 512, t_f1b + i * 512, ffh, 512, 512);
        gemm_ln_kernel<512><<<rows / 8, 256, 0, stream>>>(ffh, t_f2w + i * 512 * 128, t_f2b + i * 128, x, t_ln2g + i * 128, t_ln2b + i * 128, x);
    }

    // ---- decoder coarse ----
    colmean_kernel<<<B_, 512, 0, stream>>>(x, gc);
    linear4_kernel<true><<<cdiv(B_ * 32, 256), 256, 0, stream>>>(gc, dec_w1, dec_b1, dech, B_, 128, 128);
    linear4_kernel<false><<<cdiv(B_ * 384, 256), 256, 0, stream>>>(dech, dec_w2, dec_b2, pts0, B_, 128, 1536);

    // ---- refine stages ----
    const float* pred = pts0;
    float* outs[3] = { pts1, pts2, out };
    int Nq = COARSE_;
    for (int s = 0; s < 3; ++s) {
        loc_part_kernel<<<dim3(Nq / 64, NCH_, B_), 64, 0, stream>>>(coords, pred, ppd, ppi, Nq);
        loc_merge_kernel<<<(B_ * Nq) / 4, 256, 0, stream>>>(coords, pred, ppd, ppi, comb, Nq);
        int srows = B_ * Nq;
        linear4_kernel<true><<<cdiv(srows * 32, 256), 256, 0, stream>>>(comb, st_sw1 + s * 6 * 128, st_sb1 + s * 128, seedh, srows, 6, 128);
        gemm128_kernel<128, false, false><<<dim3(srows / 8, 1), 256, 0, stream>>>(seedh, st_sw2 + s * 128 * 128, st_sb2 + s * 128, seed, 128, 128);
        gemm128_kernel<128, true, true><<<dim3(srows / 8, 2), 256, 0, stream>>>(seed, st_dw + s * 128 * 256, st_db + s * 128, hb, 256, 256);
        child_kernel<<<cdiv(srows * 6, 256), 256, 0, stream>>>(hb, st_cw + s * 3 * 128, st_cb + s * 3, pred, outs[s], Nq);
        pred = outs[s];
        Nq <<= 1;
    }
}

// Round 16
// 495.401 us; speedup vs baseline: 1.3256x; 1.0105x over previous
//
#include <hip/hip_runtime.h>

// ---------------------------------------------------------------------------
// FullModelSnowflake.  R15: attention 4 queries/lane (block covers 256
// queries) — key loop was LDS-issue bound (256 ds_read_b128/wave); each
// read now serves 4 queries.  Grid 256, KSP=4, 4-round merge.
// ---------------------------------------------------------------------------

#define B_ 2
#define N_ 1024
#define D_ 128
#define H_ 8
#define DK_ 16
#define L_ 4
#define KG_ 16
#define KLOC_ 8
#define COARSE_ 512
#define NCH_ 16          // candidate chunks (64 candidates each)
#define AW_ 8            // waves per attention block
#define KSP_ 4           // block-level key splits
#define PREC_ 17         // floats per attention partial (sum + 16 acc)
#define QPL_ 4           // queries per lane

static __device__ __forceinline__ float wave_sum(float v) {
    #pragma unroll
    for (int off = 32; off > 0; off >>= 1) v += __shfl_xor(v, off);
    return v;
}
static __device__ __forceinline__ float half_sum(float v) {
    #pragma unroll
    for (int off = 16; off > 0; off >>= 1) v += __shfl_xor(v, off);
    return v;
}

// ---------------- LDS-staged GEMM body: returns this thread's acc ----------
template <int CIN, bool RELU, bool BIAS_HALF>
static __device__ __forceinline__ float4 gemm_body(
        const float* __restrict__ X, const float* __restrict__ W,
        const float* __restrict__ bias, int wstride, int col0) {
    __shared__ float Xs[8 * CIN];
    __shared__ float Ws[64][128];
    int tid = threadIdx.x;
    int row0 = blockIdx.x * 8;
    constexpr int NX4 = 2 * CIN;
    {
        const float4* xg = (const float4*)(X + (size_t)row0 * CIN);
        float4* xs4 = (float4*)Xs;
        #pragma unroll
        for (int i = 0; i < (NX4 + 255) / 256; ++i) {
            int t = tid + i * 256;
            if ((NX4 % 256 == 0) || t < NX4) xs4[t] = xg[t];
        }
    }
    int col4 = (tid & 31) << 2;
    int rowl = tid >> 5;
    float4 acc;
    if (BIAS_HALF) {
        acc.x = bias[(col0 + col4) >> 1];
        acc.y = bias[(col0 + col4 + 1) >> 1];
        acc.z = bias[(col0 + col4 + 2) >> 1];
        acc.w = bias[(col0 + col4 + 3) >> 1];
    } else {
        acc = *(const float4*)(bias + col0 + col4);
    }
    for (int c0 = 0; c0 < CIN; c0 += 64) {
        __syncthreads();
        #pragma unroll
        for (int i = 0; i < 8; ++i) {
            int flat = tid + i * 256;
            int wr = flat >> 5, wc = (flat & 31) << 2;
            *(float4*)&Ws[wr][wc] =
                *(const float4*)(W + (size_t)(c0 + wr) * wstride + col0 + wc);
        }
        __syncthreads();
        const float* xrow = Xs + rowl * CIN + c0;
        #pragma unroll
        for (int c = 0; c < 64; ++c) {
            float xv = xrow[c];
            float4 w = *(const float4*)&Ws[c][col4];
            acc.x += xv * w.x; acc.y += xv * w.y;
            acc.z += xv * w.z; acc.w += xv * w.w;
        }
    }
    if (RELU) {
        acc.x = fmaxf(acc.x, 0.f); acc.y = fmaxf(acc.y, 0.f);
        acc.z = fmaxf(acc.z, 0.f); acc.w = fmaxf(acc.w, 0.f);
    }
    return acc;
}

template <int CIN, bool RELU, bool BIAS_HALF>
__global__ __launch_bounds__(256) void gemm128_kernel(
        const float* __restrict__ X, const float* __restrict__ W,
        const float* __restrict__ bias, float* __restrict__ Y,
        int wstride, int ystride) {
    int col0 = blockIdx.y * 128;
    float4 acc = gemm_body<CIN, RELU, BIAS_HALF>(X, W, bias, wstride, col0);
    int col4 = (threadIdx.x & 31) << 2;
    int row = blockIdx.x * 8 + (threadIdx.x >> 5);
    *(float4*)(Y + (size_t)row * ystride + col0 + col4) = acc;
}

// GEMM (Cout=128) fused with residual-add + LayerNorm epilogue.
template <int CIN>
__global__ __launch_bounds__(256) void gemm_ln_kernel(
        const float* __restrict__ X, const float* __restrict__ W,
        const float* __restrict__ bias, const float* __restrict__ res,
        const float* __restrict__ g, const float* __restrict__ bt,
        float* __restrict__ Y) {
    float4 acc = gemm_body<CIN, false, false>(X, W, bias, 128, 0);
    int col4 = (threadIdx.x & 31) << 2;
    int row = blockIdx.x * 8 + (threadIdx.x >> 5);
    float4 r = *(const float4*)(res + (size_t)row * D_ + col4);
    acc.x += r.x; acc.y += r.y; acc.z += r.z; acc.w += r.w;
    float mean = half_sum(acc.x + acc.y + acc.z + acc.w) * (1.0f / D_);
    float dx = acc.x - mean, dy = acc.y - mean, dz = acc.z - mean, dw = acc.w - mean;
    float var = half_sum(dx * dx + dy * dy + dz * dz + dw * dw) * (1.0f / D_);
    float rstd = rsqrtf(var + 1e-5f);
    float4 gv = *(const float4*)(g + col4);
    float4 bv = *(const float4*)(bt + col4);
    float4 o;
    o.x = dx * rstd * gv.x + bv.x;
    o.y = dy * rstd * gv.y + bv.y;
    o.z = dz * rstd * gv.z + bv.z;
    o.w = dw * rstd * gv.w + bv.w;
    *(float4*)(Y + (size_t)row * D_ + col4) = o;
}

// fused QKV: 3 W-panels via blockIdx.y; outputs stored HEAD-MAJOR [bh][n][16]
__global__ __launch_bounds__(256) void qkv3_kernel(
        const float* __restrict__ X,
        const float* __restrict__ Wq, const float* __restrict__ bq,
        const float* __restrict__ Wk, const float* __restrict__ bk,
        const float* __restrict__ Wv, const float* __restrict__ bv,
        float* __restrict__ Q, float* __restrict__ K, float* __restrict__ V) {
    const float* W; const float* bias; float* Y;
    if (blockIdx.y == 0)      { W = Wq; bias = bq; Y = Q; }
    else if (blockIdx.y == 1) { W = Wk; bias = bk; Y = K; }
    else                      { W = Wv; bias = bv; Y = V; }
    float4 acc = gemm_body<128, false, false>(X, W, bias, 128, 0);
    int col4 = (threadIdx.x & 31) << 2;
    int row = blockIdx.x * 8 + (threadIdx.x >> 5);
    int b = row >> 10, n = row & (N_ - 1);
    int h = col4 >> 4, d = col4 & 15;
    *(float4*)(Y + (((size_t)(b * 8 + h) * N_ + n) << 4) + d) = acc;
}

// ---------------- KNN pass 1: per-chunk partial top-16 ---------------------
__global__ void knn_part_kernel(const float* __restrict__ coords,
                                float* __restrict__ pd, int* __restrict__ pi) {
    int blk = blockIdx.x;
    int qb = blk & 15;
    int ch = (blk >> 4) & 15;
    int b = blk >> 8;
    int lane = threadIdx.x;
    int q = qb * 64 + lane;
    __shared__ float4 sc[64];
    const float* cb = coords + (size_t)b * N_ * 3;
    {
        int m = ch * 64 + lane;
        float x = cb[m * 3], y = cb[m * 3 + 1], z = cb[m * 3 + 2];
        sc[lane] = make_float4(x, y, z, x * x + y * y + z * z);
    }
    __syncthreads();
    float qx = cb[q * 3], qy = cb[q * 3 + 1], qz = cb[q * 3 + 2];
    float q2 = qx * qx + qy * qy + qz * qz;
    float bd[KG_]; int bi[KG_];
    #pragma unroll
    for (int j = 0; j < KG_; ++j) { bd[j] = 3e38f; bi[j] = 0; }
    for (int j = 0; j < 64; ++j) {
        int m = ch * 64 + j;
        float4 c = sc[j];
        float dot = qx * c.x + qy * c.y + qz * c.z;
        float d = (q2 - 2.0f * dot) + c.w;
        d = (m == q) ? 3e38f : d;
        if (d < bd[KG_ - 1]) {
            #pragma unroll
            for (int jj = KG_ - 1; jj > 0; --jj) {
                bool shf = d < bd[jj - 1];
                bool plc = !shf && (d < bd[jj]);
                bd[jj] = shf ? bd[jj - 1] : (plc ? d : bd[jj]);
                bi[jj] = shf ? bi[jj - 1] : (plc ? m : bi[jj]);
            }
            if (d < bd[0]) { bd[0] = d; bi[0] = m; }
        }
    }
    size_t base = (((size_t)b * N_ + q) * NCH_ + ch) * KG_;
    #pragma unroll
    for (int j = 0; j < KG_; ++j) { pd[base + j] = bd[j]; pi[base + j] = bi[j]; }
}

// ---------------- KNN pass 2: wave-parallel min-extraction merge -----------
__global__ __launch_bounds__(256) void knn_merge_kernel(
        const float* __restrict__ pd, const int* __restrict__ pi,
        int* __restrict__ knn) {
    int wid = threadIdx.x >> 6;
    int lane = threadIdx.x & 63;
    size_t q = (size_t)blockIdx.x * 4 + wid;
    const float* cd = pd + q * (NCH_ * KG_);
    const int* ci = pi + q * (NCH_ * KG_);
    float ld[4]; int li[4];
    #pragma unroll
    for (int j = 0; j < 4; ++j) { ld[j] = cd[lane + j * 64]; li[j] = ci[lane + j * 64]; }
    int* o = knn + q * KG_;
    #pragma unroll
    for (int r = 0; r < KG_; ++r) {
        float dm = ld[0]; int im = li[0];
        #pragma unroll
        for (int j = 1; j < 4; ++j) {
            bool lt = (ld[j] < dm) || (ld[j] == dm && li[j] < im);
            dm = lt ? ld[j] : dm; im = lt ? li[j] : im;
        }
        #pragma unroll
        for (int off = 32; off > 0; off >>= 1) {
            float d2 = __shfl_xor(dm, off); int i2 = __shfl_xor(im, off);
            bool lt = (d2 < dm) || (d2 == dm && i2 < im);
            dm = lt ? d2 : dm; im = lt ? i2 : im;
        }
        if (lane == 0) o[r] = im;
        #pragma unroll
        for (int j = 0; j < 4; ++j) if (li[j] == im) ld[j] = 3e38f;
    }
}

// ---------------- local KNN pass 1 (k=8) -----------------------------------
__global__ void loc_part_kernel(const float* __restrict__ part,
                                const float* __restrict__ pred,
                                float* __restrict__ pd, int* __restrict__ pi,
                                int Nq) {
    int qb = blockIdx.x, ch = blockIdx.y, b = blockIdx.z;
    int lane = threadIdx.x;
    int q = qb * 64 + lane;
    __shared__ float4 sc[64];
    const float* pb = part + (size_t)b * N_ * 3;
    {
        int m = ch * 64 + lane;
        float x = pb[m * 3], y = pb[m * 3 + 1], z = pb[m * 3 + 2];
        sc[lane] = make_float4(x, y, z, x * x + y * y + z * z);
    }
    __syncthreads();
    const float* pr = pred + ((size_t)b * Nq + q) * 3;
    float qx = pr[0], qy = pr[1], qz = pr[2];
    float q2 = qx * qx + qy * qy + qz * qz;
    float bd[KLOC_]; int bi[KLOC_];
    #pragma unroll
    for (int j = 0; j < KLOC_; ++j) { bd[j] = 3e38f; bi[j] = 0; }
    for (int j = 0; j < 64; ++j) {
        float4 c = sc[j];
        float dot = qx * c.x + qy * c.y + qz * c.z;
        float d = (q2 - 2.0f * dot) + c.w;
        if (d < bd[KLOC_ - 1]) {
            int m = ch * 64 + j;
            #pragma unroll
            for (int jj = KLOC_ - 1; jj > 0; --jj) {
                bool shf = d < bd[jj - 1];
                bool plc = !shf && (d < bd[jj]);
                bd[jj] = shf ? bd[jj - 1] : (plc ? d : bd[jj]);
                bi[jj] = shf ? bi[jj - 1] : (plc ? m : bi[jj]);
            }
            if (d < bd[0]) { bd[0] = d; bi[0] = m; }
        }
    }
    size_t base = (((size_t)b * Nq + q) * NCH_ + ch) * KLOC_;
    #pragma unroll
    for (int j = 0; j < KLOC_; ++j) { pd[base + j] = bd[j]; pi[base + j] = bi[j]; }
}

// ---------------- local KNN pass 2: wave-parallel merge + mean + comb ------
__global__ __launch_bounds__(256) void loc_merge_kernel(
        const float* __restrict__ part, const float* __restrict__ pred,
        const float* __restrict__ pd, const int* __restrict__ pi,
        float* __restrict__ comb, int Nq) {
    int wid = threadIdx.x >> 6;
    int lane = threadIdx.x & 63;
    size_t q = (size_t)blockIdx.x * 4 + wid;
    const float* cd = pd + q * (NCH_ * KLOC_);
    const int* ci = pi + q * (NCH_ * KLOC_);
    float ld0 = cd[lane], ld1 = cd[lane + 64];
    int li0 = ci[lane], li1 = ci[lane + 64];
    int b = (int)(q / Nq);
    const float* pb = part + (size_t)b * N_ * 3;
    float sx = 0.f, sy = 0.f, sz = 0.f;
    #pragma unroll
    for (int r = 0; r < KLOC_; ++r) {
        float dm = ld0; int im = li0;
        {
            bool lt = (ld1 < dm) || (ld1 == dm && li1 < im);
            dm = lt ? ld1 : dm; im = lt ? li1 : im;
        }
        #pragma unroll
        for (int off = 32; off > 0; off >>= 1) {
            float d2 = __shfl_xor(dm, off); int i2 = __shfl_xor(im, off);
            bool lt = (d2 < dm) || (d2 == dm && i2 < im);
            dm = lt ? d2 : dm; im = lt ? i2 : im;
        }
        sx += pb[im * 3]; sy += pb[im * 3 + 1]; sz += pb[im * 3 + 2];
        if (li0 == im) ld0 = 3e38f;
        if (li1 == im) ld1 = 3e38f;
    }
    if (lane == 0) {
        const float* pr = pred + q * 3;
        float* o = comb + q * 6;
        o[0] = pr[0]; o[1] = pr[1]; o[2] = pr[2];
        o[3] = sx * (1.0f / KLOC_); o[4] = sy * (1.0f / KLOC_); o[5] = sz * (1.0f / KLOC_);
    }
}

// ---------------- GCN aggregation: (x + sum_nb) / (k+1) --------------------
__global__ void gcn_agg_kernel(const float* __restrict__ x,
                               const int* __restrict__ knn,
                               float* __restrict__ agg, int C) {
    int i = blockIdx.x * blockDim.x + threadIdx.x;
    if (i >= B_ * N_ * C) return;
    int c = i % C;
    int n = (i / C) % N_;
    int b = i / (C * N_);
    const int* id = knn + ((size_t)b * N_ + n) * KG_;
    float s = x[((size_t)b * N_ + n) * C + c];
    #pragma unroll
    for (int j = 0; j < KG_; ++j) s += x[((size_t)b * N_ + id[j]) * C + c];
    agg[i] = s * (1.0f / (KG_ + 1));
}

// ---------------- linear: 4 outputs per thread (small cases) ---------------
template <bool RELU>
__global__ void linear4_kernel(const float* __restrict__ X,
                               const float* __restrict__ W,
                               const float* __restrict__ bias,
                               float* __restrict__ Y,
                               int rows, int Cin, int Cout) {
    int co4 = Cout >> 2;
    int idx = blockIdx.x * blockDim.x + threadIdx.x;
    if (idx >= rows * co4) return;
    int r = idx / co4, o4 = (idx - r * co4) << 2;
    const float* x = X + (size_t)r * Cin;
    float4 acc = *(const float4*)(bias + o4);
    #pragma unroll 4
    for (int c = 0; c < Cin; ++c) {
        float xv = x[c];
        float4 w = *(const float4*)(W + (size_t)c * Cout + o4);
        acc.x += xv * w.x; acc.y += xv * w.y; acc.z += xv * w.z; acc.w += xv * w.w;
    }
    if (RELU) {
        acc.x = fmaxf(acc.x, 0.f); acc.y = fmaxf(acc.y, 0.f);
        acc.z = fmaxf(acc.z, 0.f); acc.w = fmaxf(acc.w, 0.f);
    }
    *(float4*)(Y + (size_t)r * Cout + o4) = acc;
}

// ---------------- attention: 4 queries/lane, LDS-staged K/V ----------------
// Block covers 256 queries x 256 keys.  Each ds_read serves 4 queries.
__global__ __launch_bounds__(512) void attn_part(
        const float* __restrict__ q,
        const float* __restrict__ k,
        const float* __restrict__ v,
        const float* __restrict__ coords,
        const float* __restrict__ alphap, int layer,
        float* __restrict__ pp) {
    __shared__ float smem[10304];    // stage 8192 | merge: ssum 2048 + sacc 8256
    float* kst = smem;               // [256][16]
    float* vst = smem + 4096;        // [256][16]
    float* ssum = smem;              // [8][256]   (merge phase)
    float* sacc = smem + 2048;       // [64][129]
    int bh = blockIdx.x & 15;        // b*8 + h
    int t = blockIdx.x >> 4;         // nb*KSP + ks
    int ks = t & (KSP_ - 1);
    int nb = t >> 2;                 // [0, 4)
    int b = bh >> 3;
    int wid = threadIdx.x >> 6;
    int lane = threadIdx.x & 63;
    float alpha = alphap[layer];
    // ---- stage K/V slice (contiguous head-major) ----
    {
        const float4* kg = (const float4*)(k + (((size_t)bh * N_ + ks * 256) << 4));
        const float4* vg = (const float4*)(v + (((size_t)bh * N_ + ks * 256) << 4));
        float4* ks4 = (float4*)kst;
        float4* vs4 = (float4*)vst;
        #pragma unroll
        for (int i = 0; i < 2; ++i) {
            int idx = threadIdx.x + i * 512;
            ks4[idx] = kg[idx];
            vs4[idx] = vg[idx];
        }
    }
    int n0 = nb * 256 + lane;        // queries n0 + u*64, u=0..3
    const float* cb = coords + (size_t)b * N_ * 3;
    float qv[QPL_][DK_];
    float cx[QPL_], cy[QPL_], cz[QPL_];
    #pragma unroll
    for (int u = 0; u < QPL_; ++u) {
        const float* qp = q + (((size_t)bh * N_ + n0 + u * 64) << 4);
        #pragma unroll
        for (int d = 0; d < DK_; ++d) qv[u][d] = qp[d];
        int nn = n0 + u * 64;
        cx[u] = cb[nn * 3]; cy[u] = cb[nn * 3 + 1]; cz[u] = cb[nn * 3 + 2];
    }
    float sm[QPL_];
    float acc[QPL_][DK_];
    #pragma unroll
    for (int u = 0; u < QPL_; ++u) {
        sm[u] = 0.f;
        #pragma unroll
        for (int d = 0; d < DK_; ++d) acc[u][d] = 0.f;
    }
    __syncthreads();                 // stage visible
    int mbase = ks * 256 + wid * 32; // global key index base
    int lbase = wid * 32;            // stage-local base
    #pragma unroll 2
    for (int j = 0; j < 32; ++j) {
        float kk[16];
        {
            const float4* kr = (const float4*)(kst + ((lbase + j) << 4));
            *(float4*)&kk[0] = kr[0]; *(float4*)&kk[4] = kr[1];
            *(float4*)&kk[8] = kr[2]; *(float4*)&kk[12] = kr[3];
        }
        int m = mbase + j;
        float wx = cb[m * 3], wy = cb[m * 3 + 1], wz = cb[m * 3 + 2];
        float p[QPL_];
        #pragma unroll
        for (int u = 0; u < QPL_; ++u) {
            float dot = 0.f;
            #pragma unroll
            for (int d = 0; d < DK_; ++d) dot += qv[u][d] * kk[d];
            p[u] = __expf(dot * 0.25f + alpha * (wx * cx[u] + wy * cy[u] + wz * cz[u]));
            sm[u] += p[u];
        }
        float vv[16];
        {
            const float4* vr = (const float4*)(vst + ((lbase + j) << 4));
            *(float4*)&vv[0] = vr[0]; *(float4*)&vv[4] = vr[1];
            *(float4*)&vv[8] = vr[2]; *(float4*)&vv[12] = vr[3];
        }
        #pragma unroll
        for (int u = 0; u < QPL_; ++u)
            #pragma unroll
            for (int d = 0; d < DK_; ++d) acc[u][d] += p[u] * vv[d];
    }
    __syncthreads();                 // done reading stage
    // ---- 4-round merge (reuses smem) ----
    #pragma unroll
    for (int u = 0; u < QPL_; ++u) ssum[wid * 256 + u * 64 + lane] = sm[u];
    int qi = threadIdx.x & 63;
    int dq = threadIdx.x >> 6;       // 0..7, 2 d's each
    #pragma unroll
    for (int r = 0; r < QPL_; ++r) {
        #pragma unroll
        for (int d = 0; d < DK_; ++d) sacc[lane * 129 + wid * DK_ + d] = acc[r][d];
        __syncthreads();
        int n = nb * 256 + r * 64 + qi;
        float* o = pp + (((size_t)bh * N_ + n) * KSP_ + ks) * PREC_;
        if (dq == 0) {
            float gsum = 0.f;
            #pragma unroll
            for (int w = 0; w < AW_; ++w) gsum += ssum[w * 256 + r * 64 + qi];
            o[0] = gsum;
        }
        #pragma unroll
        for (int dd = 0; dd < 2; ++dd) {
            int d = dq * 2 + dd;
            float a = 0.f;
            #pragma unroll
            for (int w = 0; w < AW_; ++w) a += sacc[qi * 129 + w * DK_ + d];
            o[1 + d] = a;
        }
        __syncthreads();
    }
}

// ---------------- fused attn final-merge + residual + LayerNorm ------------
__global__ void attn_fin_ln(const float* __restrict__ pp,
                            const float* __restrict__ xin,
                            const float* __restrict__ g,
                            const float* __restrict__ bt,
                            float* __restrict__ xout) {
    int row = blockIdx.x * 4 + (threadIdx.x >> 6);   // b*N + n
    int lane = threadIdx.x & 63;
    int b = row >> 10, n = row & (N_ - 1);
    float v0, v1;
    {
        int c = lane;
        int h = c >> 4, d = c & 15;
        const float* p = pp + (((size_t)(b * 8 + h) * N_ + n) * KSP_) * PREC_;
        float gsum = 0.f, a = 0.f;
        #pragma unroll
        for (int s = 0; s < KSP_; ++s) {
            gsum += p[s * PREC_];
            a += p[s * PREC_ + 1 + d];
        }
        v0 = a / gsum + xin[(size_t)row * D_ + c];
    }
    {
        int c = lane + 64;
        int h = c >> 4, d = c & 15;
        const float* p = pp + (((size_t)(b * 8 + h) * N_ + n) * KSP_) * PREC_;
        float gsum = 0.f, a = 0.f;
        #pragma unroll
        for (int s = 0; s < KSP_; ++s) {
            gsum += p[s * PREC_];
            a += p[s * PREC_ + 1 + d];
        }
        v1 = a / gsum + xin[(size_t)row * D_ + c];
    }
    float mean = wave_sum(v0 + v1) * (1.0f / D_);
    float d0 = v0 - mean, d1 = v1 - mean;
    float var = wave_sum(d0 * d0 + d1 * d1) * (1.0f / D_);
    float rstd = rsqrtf(var + 1e-5f);
    float* orow = xout + (size_t)row * D_;
    orow[lane] = d0 * rstd * g[lane] + bt[lane];
    orow[lane + 64] = d1 * rstd * g[lane + 64] + bt[lane + 64];
}

// ---------------- column mean over N (global feature) ----------------------
__global__ void colmean_kernel(const float* __restrict__ x,
                               float* __restrict__ gc) {
    int b = blockIdx.x;
    int d = threadIdx.x & 127;
    int sl = threadIdx.x >> 7;
    __shared__ float part[4][128];
    float s = 0.f;
    const float* xb = x + (size_t)b * N_ * D_;
    for (int n = sl * 256; n < sl * 256 + 256; ++n) s += xb[(size_t)n * D_ + d];
    part[sl][d] = s;
    __syncthreads();
    if (sl == 0)
        gc[b * D_ + d] = (part[0][d] + part[1][d] + part[2][d] + part[3][d]) * (1.0f / N_);
}

// ---------------- child = pred + (h . cw + cb), interleaved x2 -------------
__global__ void child_kernel(const float* __restrict__ h,
                             const float* __restrict__ cw,
                             const float* __restrict__ cb,
                             const float* __restrict__ pred,
                             float* __restrict__ outp, int Nq) {
    int idx = blockIdx.x * blockDim.x + threadIdx.x;
    if (idx >= B_ * Nq * 6) return;
    int p = idx % 3;
    int t = (idx / 3) & 1;
    int n = (idx / 6) % Nq;
    int b = idx / (6 * Nq);
    const float* hr = h + ((size_t)b * Nq + n) * 256;
    float acc = cb[p];
    #pragma unroll 4
    for (int o = 0; o < 128; ++o) acc += hr[o * 2 + t] * cw[p * 128 + o];
    outp[idx] = pred[((size_t)b * Nq + n) * 3 + p] + acc;
}

// ---------------------------------------------------------------------------
static inline int cdiv(int a, int b) { return (a + b - 1) / b; }

extern "C" void kernel_launch(void* const* d_in, const int* in_sizes, int n_in,
                              void* d_out, int out_size, void* d_ws, size_t ws_size,
                              hipStream_t stream) {
    (void)in_sizes; (void)n_in; (void)out_size; (void)ws_size;
    const float* coords = (const float*)d_in[0];
    const float* gcn_w0 = (const float*)d_in[1];
    const float* gcn_b0 = (const float*)d_in[2];
    const float* gcn_w1 = (const float*)d_in[3];
    const float* gcn_b1 = (const float*)d_in[4];
    const float* enc_fw = (const float*)d_in[5];
    const float* enc_fb = (const float*)d_in[6];
    const float* t_wq   = (const float*)d_in[7];
    const float* t_bq   = (const float*)d_in[8];
    const float* t_wk   = (const float*)d_in[9];
    const float* t_bk   = (const float*)d_in[10];
    const float* t_wv   = (const float*)d_in[11];
    const float* t_bv   = (const float*)d_in[12];
    const float* t_alpha= (const float*)d_in[13];
    const float* t_f1w  = (const float*)d_in[14];
    const float* t_f1b  = (const float*)d_in[15];
    const float* t_f2w  = (const float*)d_in[16];
    const float* t_f2b  = (const float*)d_in[17];
    const float* t_ln1g = (const float*)d_in[18];
    const float* t_ln1b = (const float*)d_in[19];
    const float* t_ln2g = (const float*)d_in[20];
    const float* t_ln2b = (const float*)d_in[21];
    const float* dec_w1 = (const float*)d_in[22];
    const float* dec_b1 = (const float*)d_in[23];
    const float* dec_w2 = (const float*)d_in[24];
    const float* dec_b2 = (const float*)d_in[25];
    const float* st_sw1 = (const float*)d_in[26];
    const float* st_sb1 = (const float*)d_in[27];
    const float* st_sw2 = (const float*)d_in[28];
    const float* st_sb2 = (const float*)d_in[29];
    const float* st_dw  = (const float*)d_in[30];
    const float* st_db  = (const float*)d_in[31];
    const float* st_cw  = (const float*)d_in[32];
    const float* st_cb  = (const float*)d_in[33];
    float* out = (float*)d_out;

    // ---- workspace carve ----
    char* ws = (char*)d_ws;
    size_t off = 0;
    auto alloc = [&](size_t bytes) -> void* {
        void* p = ws + off;
        off += (bytes + 255) & ~(size_t)255;
        return p;
    };
    int*   knn   = (int*)  alloc((size_t)B_ * N_ * KG_ * 4);
    float* ppd   = (float*)alloc((size_t)B_ * 2048 * NCH_ * KG_ * 4);
    int*   ppi   = (int*)  alloc((size_t)B_ * 2048 * NCH_ * KG_ * 4);
    float* app   = (float*)alloc((size_t)B_ * H_ * N_ * KSP_ * PREC_ * 4);
    float* agg   = (float*)alloc((size_t)B_ * N_ * 64 * 4);
    float* x64   = (float*)alloc((size_t)B_ * N_ * 64 * 4);
    float* xb    = (float*)alloc((size_t)B_ * N_ * D_ * 4);
    float* x     = (float*)alloc((size_t)B_ * N_ * D_ * 4);
    float* q     = (float*)alloc((size_t)B_ * N_ * D_ * 4);
    float* k     = (float*)alloc((size_t)B_ * N_ * D_ * 4);
    float* v     = (float*)alloc((size_t)B_ * N_ * D_ * 4);
    float* ffh   = (float*)alloc((size_t)B_ * N_ * 512 * 4);
    float* gc    = (float*)alloc((size_t)B_ * D_ * 4);
    float* dech  = (float*)alloc((size_t)B_ * D_ * 4);
    float* pts0  = (float*)alloc((size_t)B_ * COARSE_ * 3 * 4);
    float* pts1  = (float*)alloc((size_t)B_ * 1024 * 3 * 4);
    float* pts2  = (float*)alloc((size_t)B_ * 2048 * 3 * 4);
    float* comb  = (float*)alloc((size_t)B_ * 2048 * 6 * 4);
    float* seedh = (float*)alloc((size_t)B_ * 2048 * 128 * 4);
    float* seed  = (float*)alloc((size_t)B_ * 2048 * 128 * 4);
    float* hb    = (float*)alloc((size_t)B_ * 2048 * 256 * 4);

    const int rows = B_ * N_;   // 2048

    // ---- graph encoder ----
    knn_part_kernel<<<B_ * NCH_ * 16, 64, 0, stream>>>(coords, ppd, ppi);
    knn_merge_kernel<<<B_ * N_ / 4, 256, 0, stream>>>(ppd, ppi, knn);
    gcn_agg_kernel<<<cdiv(rows * 3, 256), 256, 0, stream>>>(coords, knn, agg, 3);
    linear4_kernel<true><<<cdiv(rows * 16, 256), 256, 0, stream>>>(agg, gcn_w0, gcn_b0, x64, rows, 3, 64);
    gcn_agg_kernel<<<cdiv(rows * 64, 256), 256, 0, stream>>>(x64, knn, agg, 64);
    gemm128_kernel<64, true, false><<<dim3(rows / 8, 1), 256, 0, stream>>>(agg, gcn_w1, gcn_b1, xb, 128, 128);
    gemm128_kernel<128, false, false><<<dim3(rows / 8, 1), 256, 0, stream>>>(xb, enc_fw, enc_fb, x, 128, 128);

    // ---- transformer ----
    for (int i = 0; i < L_; ++i) {
        qkv3_kernel<<<dim3(rows / 8, 3), 256, 0, stream>>>(
            x, t_wq + i * 16384, t_bq + i * 128, t_wk + i * 16384, t_bk + i * 128,
            t_wv + i * 16384, t_bv + i * 128, q, k, v);
        attn_part<<<B_ * H_ * (N_ / 256) * KSP_, 512, 0, stream>>>(q, k, v, coords, t_alpha, i, app);
        attn_fin_ln<<<rows / 4, 256, 0, stream>>>(app, x, t_ln1g + i * 128, t_ln1b + i * 128, x);
        gemm128_kernel<128, true, false><<<dim3(rows / 8, 4), 256, 0, stream>>>(x, t_f1w + i * 128 * 512, t_f1b + i * 512, ffh, 512, 512);
        gemm_ln_kernel<512><<<rows / 8, 256, 0, stream>>>(ffh, t_f2w + i * 512 * 128, t_f2b + i * 128, x, t_ln2g + i * 128, t_ln2b + i * 128, x);
    }

    // ---- decoder coarse ----
    colmean_kernel<<<B_, 512, 0, stream>>>(x, gc);
    linear4_kernel<true><<<cdiv(B_ * 32, 256), 256, 0, stream>>>(gc, dec_w1, dec_b1, dech, B_, 128, 128);
    linear4_kernel<false><<<cdiv(B_ * 384, 256), 256, 0, stream>>>(dech, dec_w2, dec_b2, pts0, B_, 128, 1536);

    // ---- refine stages ----
    const float* pred = pts0;
    float* outs[3] = { pts1, pts2, out };
    int Nq = COARSE_;
    for (int s = 0; s < 3; ++s) {
        loc_part_kernel<<<dim3(Nq / 64, NCH_, B_), 64, 0, stream>>>(coords, pred, ppd, ppi, Nq);
        loc_merge_kernel<<<(B_ * Nq) / 4, 256, 0, stream>>>(coords, pred, ppd, ppi, comb, Nq);
        int srows = B_ * Nq;
        linear4_kernel<true><<<cdiv(srows * 32, 256), 256, 0, stream>>>(comb, st_sw1 + s * 6 * 128, st_sb1 + s * 128, seedh, srows, 6, 128);
        gemm128_kernel<128, false, false><<<dim3(srows / 8, 1), 256, 0, stream>>>(seedh, st_sw2 + s * 128 * 128, st_sb2 + s * 128, seed, 128, 128);
        gemm128_kernel<128, true, true><<<dim3(srows / 8, 2), 256, 0, stream>>>(seed, st_dw + s * 128 * 256, st_db + s * 128, hb, 256, 256);
        child_kernel<<<cdiv(srows * 6, 256), 256, 0, stream>>>(hb, st_cw + s * 3 * 128, st_cb + s * 3, pred, outs[s], Nq);
        pred = outs[s];
        Nq <<= 1;
    }
}

// Round 17
// 487.135 us; speedup vs baseline: 1.3481x; 1.0170x over previous
//
#include <hip/hip_runtime.h>

// ---------------------------------------------------------------------------
// FullModelSnowflake.  R16: fuse attn final-merge + residual + LayerNorm into
// the FFN1 GEMM's X-staging phase (saves 1 launch + 1MB round-trip per layer;
// LN rows written to xb for gemm_ln's residual).  48 -> 44 launches.
// ---------------------------------------------------------------------------

#define B_ 2
#define N_ 1024
#define D_ 128
#define H_ 8
#define DK_ 16
#define L_ 4
#define KG_ 16
#define KLOC_ 8
#define COARSE_ 512
#define NCH_ 16          // candidate chunks (64 candidates each)
#define AW_ 8            // waves per attention block
#define KSP_ 4           // block-level key splits
#define PREC_ 17         // floats per attention partial (sum + 16 acc)
#define QPL_ 4           // queries per lane

static __device__ __forceinline__ float wave_sum(float v) {
    #pragma unroll
    for (int off = 32; off > 0; off >>= 1) v += __shfl_xor(v, off);
    return v;
}
static __device__ __forceinline__ float half_sum(float v) {
    #pragma unroll
    for (int off = 16; off > 0; off >>= 1) v += __shfl_xor(v, off);
    return v;
}

// ---------------- LDS-staged GEMM body: returns this thread's acc ----------
template <int CIN, bool RELU, bool BIAS_HALF>
static __device__ __forceinline__ float4 gemm_body(
        const float* __restrict__ X, const float* __restrict__ W,
        const float* __restrict__ bias, int wstride, int col0) {
    __shared__ float Xs[8 * CIN];
    __shared__ float Ws[64][128];
    int tid = threadIdx.x;
    int row0 = blockIdx.x * 8;
    constexpr int NX4 = 2 * CIN;
    {
        const float4* xg = (const float4*)(X + (size_t)row0 * CIN);
        float4* xs4 = (float4*)Xs;
        #pragma unroll
        for (int i = 0; i < (NX4 + 255) / 256; ++i) {
            int t = tid + i * 256;
            if ((NX4 % 256 == 0) || t < NX4) xs4[t] = xg[t];
        }
    }
    int col4 = (tid & 31) << 2;
    int rowl = tid >> 5;
    float4 acc;
    if (BIAS_HALF) {
        acc.x = bias[(col0 + col4) >> 1];
        acc.y = bias[(col0 + col4 + 1) >> 1];
        acc.z = bias[(col0 + col4 + 2) >> 1];
        acc.w = bias[(col0 + col4 + 3) >> 1];
    } else {
        acc = *(const float4*)(bias + col0 + col4);
    }
    for (int c0 = 0; c0 < CIN; c0 += 64) {
        __syncthreads();
        #pragma unroll
        for (int i = 0; i < 8; ++i) {
            int flat = tid + i * 256;
            int wr = flat >> 5, wc = (flat & 31) << 2;
            *(float4*)&Ws[wr][wc] =
                *(const float4*)(W + (size_t)(c0 + wr) * wstride + col0 + wc);
        }
        __syncthreads();
        const float* xrow = Xs + rowl * CIN + c0;
        #pragma unroll
        for (int c = 0; c < 64; ++c) {
            float xv = xrow[c];
            float4 w = *(const float4*)&Ws[c][col4];
            acc.x += xv * w.x; acc.y += xv * w.y;
            acc.z += xv * w.z; acc.w += xv * w.w;
        }
    }
    if (RELU) {
        acc.x = fmaxf(acc.x, 0.f); acc.y = fmaxf(acc.y, 0.f);
        acc.z = fmaxf(acc.z, 0.f); acc.w = fmaxf(acc.w, 0.f);
    }
    return acc;
}

template <int CIN, bool RELU, bool BIAS_HALF>
__global__ __launch_bounds__(256) void gemm128_kernel(
        const float* __restrict__ X, const float* __restrict__ W,
        const float* __restrict__ bias, float* __restrict__ Y,
        int wstride, int ystride) {
    int col0 = blockIdx.y * 128;
    float4 acc = gemm_body<CIN, RELU, BIAS_HALF>(X, W, bias, wstride, col0);
    int col4 = (threadIdx.x & 31) << 2;
    int row = blockIdx.x * 8 + (threadIdx.x >> 5);
    *(float4*)(Y + (size_t)row * ystride + col0 + col4) = acc;
}

// GEMM (Cout=128) fused with residual-add + LayerNorm epilogue.
template <int CIN>
__global__ __launch_bounds__(256) void gemm_ln_kernel(
        const float* __restrict__ X, const float* __restrict__ W,
        const float* __restrict__ bias, const float* __restrict__ res,
        const float* __restrict__ g, const float* __restrict__ bt,
        float* __restrict__ Y) {
    float4 acc = gemm_body<CIN, false, false>(X, W, bias, 128, 0);
    int col4 = (threadIdx.x & 31) << 2;
    int row = blockIdx.x * 8 + (threadIdx.x >> 5);
    float4 r = *(const float4*)(res + (size_t)row * D_ + col4);
    acc.x += r.x; acc.y += r.y; acc.z += r.z; acc.w += r.w;
    float mean = half_sum(acc.x + acc.y + acc.z + acc.w) * (1.0f / D_);
    float dx = acc.x - mean, dy = acc.y - mean, dz = acc.z - mean, dw = acc.w - mean;
    float var = half_sum(dx * dx + dy * dy + dz * dz + dw * dw) * (1.0f / D_);
    float rstd = rsqrtf(var + 1e-5f);
    float4 gv = *(const float4*)(g + col4);
    float4 bv = *(const float4*)(bt + col4);
    float4 o;
    o.x = dx * rstd * gv.x + bv.x;
    o.y = dy * rstd * gv.y + bv.y;
    o.z = dz * rstd * gv.z + bv.z;
    o.w = dw * rstd * gv.w + bv.w;
    *(float4*)(Y + (size_t)row * D_ + col4) = o;
}

// FFN1 GEMM with fused attn-final-merge + residual + LN in the X-stage.
// Reads app (attn partials) + xin (pre-LN x); stages LN rows in LDS; panel 0
// also writes LN rows to xln (residual input of the following gemm_ln).
__global__ __launch_bounds__(256) void gemm_ffn1_kernel(
        const float* __restrict__ pp, const float* __restrict__ xin,
        const float* __restrict__ g, const float* __restrict__ bt,
        const float* __restrict__ W, const float* __restrict__ bias,
        float* __restrict__ xln, float* __restrict__ Y) {
    __shared__ float Xs[8 * 128];
    __shared__ float Ws[64][128];
    int tid = threadIdx.x;
    int row0 = blockIdx.x * 8;
    int col0 = blockIdx.y * 128;
    int col4 = (tid & 31) << 2;
    int rowl = tid >> 5;
    // ---- stage X = LN(attn_merge + xin) ----
    {
        int row = row0 + rowl;
        int b = row >> 10, n = row & (N_ - 1);
        int h = col4 >> 4, d0 = col4 & 15;
        const float* p = pp + (((size_t)(b * 8 + h) * N_ + n) * KSP_) * PREC_;
        float gsum = 0.f, a0 = 0.f, a1 = 0.f, a2 = 0.f, a3 = 0.f;
        #pragma unroll
        for (int s = 0; s < KSP_; ++s) {
            const float* ps = p + s * PREC_;
            gsum += ps[0];
            a0 += ps[1 + d0]; a1 += ps[2 + d0]; a2 += ps[3 + d0]; a3 += ps[4 + d0];
        }
        float inv = 1.0f / gsum;
        float4 xv = *(const float4*)(xin + (size_t)row * D_ + col4);
        float v0 = a0 * inv + xv.x;
        float v1 = a1 * inv + xv.y;
        float v2 = a2 * inv + xv.z;
        float v3 = a3 * inv + xv.w;
        float mean = half_sum(v0 + v1 + v2 + v3) * (1.0f / D_);
        float dx = v0 - mean, dy = v1 - mean, dz = v2 - mean, dw = v3 - mean;
        float var = half_sum(dx * dx + dy * dy + dz * dz + dw * dw) * (1.0f / D_);
        float rstd = rsqrtf(var + 1e-5f);
        float4 gv = *(const float4*)(g + col4);
        float4 bv = *(const float4*)(bt + col4);
        float4 o;
        o.x = dx * rstd * gv.x + bv.x;
        o.y = dy * rstd * gv.y + bv.y;
        o.z = dz * rstd * gv.z + bv.z;
        o.w = dw * rstd * gv.w + bv.w;
        *(float4*)&Xs[rowl * 128 + col4] = o;
        if (blockIdx.y == 0)
            *(float4*)(xln + (size_t)row * D_ + col4) = o;
    }
    float4 acc = *(const float4*)(bias + col0 + col4);
    for (int c0 = 0; c0 < 128; c0 += 64) {
        __syncthreads();
        #pragma unroll
        for (int i = 0; i < 8; ++i) {
            int flat = tid + i * 256;
            int wr = flat >> 5, wc = (flat & 31) << 2;
            *(float4*)&Ws[wr][wc] =
                *(const float4*)(W + (size_t)(c0 + wr) * 512 + col0 + wc);
        }
        __syncthreads();
        const float* xrow = Xs + rowl * 128 + c0;
        #pragma unroll
        for (int c = 0; c < 64; ++c) {
            float xv = xrow[c];
            float4 w = *(const float4*)&Ws[c][col4];
            acc.x += xv * w.x; acc.y += xv * w.y;
            acc.z += xv * w.z; acc.w += xv * w.w;
        }
    }
    acc.x = fmaxf(acc.x, 0.f); acc.y = fmaxf(acc.y, 0.f);
    acc.z = fmaxf(acc.z, 0.f); acc.w = fmaxf(acc.w, 0.f);
    int row = row0 + rowl;
    *(float4*)(Y + (size_t)row * 512 + col0 + col4) = acc;
}

// fused QKV: 3 W-panels via blockIdx.y; outputs stored HEAD-MAJOR [bh][n][16]
__global__ __launch_bounds__(256) void qkv3_kernel(
        const float* __restrict__ X,
        const float* __restrict__ Wq, const float* __restrict__ bq,
        const float* __restrict__ Wk, const float* __restrict__ bk,
        const float* __restrict__ Wv, const float* __restrict__ bv,
        float* __restrict__ Q, float* __restrict__ K, float* __restrict__ V) {
    const float* W; const float* bias; float* Y;
    if (blockIdx.y == 0)      { W = Wq; bias = bq; Y = Q; }
    else if (blockIdx.y == 1) { W = Wk; bias = bk; Y = K; }
    else                      { W = Wv; bias = bv; Y = V; }
    float4 acc = gemm_body<128, false, false>(X, W, bias, 128, 0);
    int col4 = (threadIdx.x & 31) << 2;
    int row = blockIdx.x * 8 + (threadIdx.x >> 5);
    int b = row >> 10, n = row & (N_ - 1);
    int h = col4 >> 4, d = col4 & 15;
    *(float4*)(Y + (((size_t)(b * 8 + h) * N_ + n) << 4) + d) = acc;
}

// ---------------- KNN pass 1: per-chunk partial top-16 ---------------------
__global__ void knn_part_kernel(const float* __restrict__ coords,
                                float* __restrict__ pd, int* __restrict__ pi) {
    int blk = blockIdx.x;
    int qb = blk & 15;
    int ch = (blk >> 4) & 15;
    int b = blk >> 8;
    int lane = threadIdx.x;
    int q = qb * 64 + lane;
    __shared__ float4 sc[64];
    const float* cb = coords + (size_t)b * N_ * 3;
    {
        int m = ch * 64 + lane;
        float x = cb[m * 3], y = cb[m * 3 + 1], z = cb[m * 3 + 2];
        sc[lane] = make_float4(x, y, z, x * x + y * y + z * z);
    }
    __syncthreads();
    float qx = cb[q * 3], qy = cb[q * 3 + 1], qz = cb[q * 3 + 2];
    float q2 = qx * qx + qy * qy + qz * qz;
    float bd[KG_]; int bi[KG_];
    #pragma unroll
    for (int j = 0; j < KG_; ++j) { bd[j] = 3e38f; bi[j] = 0; }
    for (int j = 0; j < 64; ++j) {
        int m = ch * 64 + j;
        float4 c = sc[j];
        float dot = qx * c.x + qy * c.y + qz * c.z;
        float d = (q2 - 2.0f * dot) + c.w;
        d = (m == q) ? 3e38f : d;
        if (d < bd[KG_ - 1]) {
            #pragma unroll
            for (int jj = KG_ - 1; jj > 0; --jj) {
                bool shf = d < bd[jj - 1];
                bool plc = !shf && (d < bd[jj]);
                bd[jj] = shf ? bd[jj - 1] : (plc ? d : bd[jj]);
                bi[jj] = shf ? bi[jj - 1] : (plc ? m : bi[jj]);
            }
            if (d < bd[0]) { bd[0] = d; bi[0] = m; }
        }
    }
    size_t base = (((size_t)b * N_ + q) * NCH_ + ch) * KG_;
    #pragma unroll
    for (int j = 0; j < KG_; ++j) { pd[base + j] = bd[j]; pi[base + j] = bi[j]; }
}

// ---------------- KNN pass 2: wave-parallel min-extraction merge -----------
__global__ __launch_bounds__(256) void knn_merge_kernel(
        const float* __restrict__ pd, const int* __restrict__ pi,
        int* __restrict__ knn) {
    int wid = threadIdx.x >> 6;
    int lane = threadIdx.x & 63;
    size_t q = (size_t)blockIdx.x * 4 + wid;
    const float* cd = pd + q * (NCH_ * KG_);
    const int* ci = pi + q * (NCH_ * KG_);
    float ld[4]; int li[4];
    #pragma unroll
    for (int j = 0; j < 4; ++j) { ld[j] = cd[lane + j * 64]; li[j] = ci[lane + j * 64]; }
    int* o = knn + q * KG_;
    #pragma unroll
    for (int r = 0; r < KG_; ++r) {
        float dm = ld[0]; int im = li[0];
        #pragma unroll
        for (int j = 1; j < 4; ++j) {
            bool lt = (ld[j] < dm) || (ld[j] == dm && li[j] < im);
            dm = lt ? ld[j] : dm; im = lt ? li[j] : im;
        }
        #pragma unroll
        for (int off = 32; off > 0; off >>= 1) {
            float d2 = __shfl_xor(dm, off); int i2 = __shfl_xor(im, off);
            bool lt = (d2 < dm) || (d2 == dm && i2 < im);
            dm = lt ? d2 : dm; im = lt ? i2 : im;
        }
        if (lane == 0) o[r] = im;
        #pragma unroll
        for (int j = 0; j < 4; ++j) if (li[j] == im) ld[j] = 3e38f;
    }
}

// ---------------- local KNN pass 1 (k=8) -----------------------------------
__global__ void loc_part_kernel(const float* __restrict__ part,
                                const float* __restrict__ pred,
                                float* __restrict__ pd, int* __restrict__ pi,
                                int Nq) {
    int qb = blockIdx.x, ch = blockIdx.y, b = blockIdx.z;
    int lane = threadIdx.x;
    int q = qb * 64 + lane;
    __shared__ float4 sc[64];
    const float* pb = part + (size_t)b * N_ * 3;
    {
        int m = ch * 64 + lane;
        float x = pb[m * 3], y = pb[m * 3 + 1], z = pb[m * 3 + 2];
        sc[lane] = make_float4(x, y, z, x * x + y * y + z * z);
    }
    __syncthreads();
    const float* pr = pred + ((size_t)b * Nq + q) * 3;
    float qx = pr[0], qy = pr[1], qz = pr[2];
    float q2 = qx * qx + qy * qy + qz * qz;
    float bd[KLOC_]; int bi[KLOC_];
    #pragma unroll
    for (int j = 0; j < KLOC_; ++j) { bd[j] = 3e38f; bi[j] = 0; }
    for (int j = 0; j < 64; ++j) {
        float4 c = sc[j];
        float dot = qx * c.x + qy * c.y + qz * c.z;
        float d = (q2 - 2.0f * dot) + c.w;
        if (d < bd[KLOC_ - 1]) {
            int m = ch * 64 + j;
            #pragma unroll
            for (int jj = KLOC_ - 1; jj > 0; --jj) {
                bool shf = d < bd[jj - 1];
                bool plc = !shf && (d < bd[jj]);
                bd[jj] = shf ? bd[jj - 1] : (plc ? d : bd[jj]);
                bi[jj] = shf ? bi[jj - 1] : (plc ? m : bi[jj]);
            }
            if (d < bd[0]) { bd[0] = d; bi[0] = m; }
        }
    }
    size_t base = (((size_t)b * Nq + q) * NCH_ + ch) * KLOC_;
    #pragma unroll
    for (int j = 0; j < KLOC_; ++j) { pd[base + j] = bd[j]; pi[base + j] = bi[j]; }
}

// ---------------- local KNN pass 2: wave-parallel merge + mean + comb ------
__global__ __launch_bounds__(256) void loc_merge_kernel(
        const float* __restrict__ part, const float* __restrict__ pred,
        const float* __restrict__ pd, const int* __restrict__ pi,
        float* __restrict__ comb, int Nq) {
    int wid = threadIdx.x >> 6;
    int lane = threadIdx.x & 63;
    size_t q = (size_t)blockIdx.x * 4 + wid;
    const float* cd = pd + q * (NCH_ * KLOC_);
    const int* ci = pi + q * (NCH_ * KLOC_);
    float ld0 = cd[lane], ld1 = cd[lane + 64];
    int li0 = ci[lane], li1 = ci[lane + 64];
    int b = (int)(q / Nq);
    const float* pb = part + (size_t)b * N_ * 3;
    float sx = 0.f, sy = 0.f, sz = 0.f;
    #pragma unroll
    for (int r = 0; r < KLOC_; ++r) {
        float dm = ld0; int im = li0;
        {
            bool lt = (ld1 < dm) || (ld1 == dm && li1 < im);
            dm = lt ? ld1 : dm; im = lt ? li1 : im;
        }
        #pragma unroll
        for (int off = 32; off > 0; off >>= 1) {
            float d2 = __shfl_xor(dm, off); int i2 = __shfl_xor(im, off);
            bool lt = (d2 < dm) || (d2 == dm && i2 < im);
            dm = lt ? d2 : dm; im = lt ? i2 : im;
        }
        sx += pb[im * 3]; sy += pb[im * 3 + 1]; sz += pb[im * 3 + 2];
        if (li0 == im) ld0 = 3e38f;
        if (li1 == im) ld1 = 3e38f;
    }
    if (lane == 0) {
        const float* pr = pred + q * 3;
        float* o = comb + q * 6;
        o[0] = pr[0]; o[1] = pr[1]; o[2] = pr[2];
        o[3] = sx * (1.0f / KLOC_); o[4] = sy * (1.0f / KLOC_); o[5] = sz * (1.0f / KLOC_);
    }
}

// ---------------- GCN aggregation: (x + sum_nb) / (k+1) --------------------
__global__ void gcn_agg_kernel(const float* __restrict__ x,
                               const int* __restrict__ knn,
                               float* __restrict__ agg, int C) {
    int i = blockIdx.x * blockDim.x + threadIdx.x;
    if (i >= B_ * N_ * C) return;
    int c = i % C;
    int n = (i / C) % N_;
    int b = i / (C * N_);
    const int* id = knn + ((size_t)b * N_ + n) * KG_;
    float s = x[((size_t)b * N_ + n) * C + c];
    #pragma unroll
    for (int j = 0; j < KG_; ++j) s += x[((size_t)b * N_ + id[j]) * C + c];
    agg[i] = s * (1.0f / (KG_ + 1));
}

// ---------------- linear: 4 outputs per thread (small cases) ---------------
template <bool RELU>
__global__ void linear4_kernel(const float* __restrict__ X,
                               const float* __restrict__ W,
                               const float* __restrict__ bias,
                               float* __restrict__ Y,
                               int rows, int Cin, int Cout) {
    int co4 = Cout >> 2;
    int idx = blockIdx.x * blockDim.x + threadIdx.x;
    if (idx >= rows * co4) return;
    int r = idx / co4, o4 = (idx - r * co4) << 2;
    const float* x = X + (size_t)r * Cin;
    float4 acc = *(const float4*)(bias + o4);
    #pragma unroll 4
    for (int c = 0; c < Cin; ++c) {
        float xv = x[c];
        float4 w = *(const float4*)(W + (size_t)c * Cout + o4);
        acc.x += xv * w.x; acc.y += xv * w.y; acc.z += xv * w.z; acc.w += xv * w.w;
    }
    if (RELU) {
        acc.x = fmaxf(acc.x, 0.f); acc.y = fmaxf(acc.y, 0.f);
        acc.z = fmaxf(acc.z, 0.f); acc.w = fmaxf(acc.w, 0.f);
    }
    *(float4*)(Y + (size_t)r * Cout + o4) = acc;
}

// ---------------- attention: 4 queries/lane, LDS-staged K/V ----------------
__global__ __launch_bounds__(512) void attn_part(
        const float* __restrict__ q,
        const float* __restrict__ k,
        const float* __restrict__ v,
        const float* __restrict__ coords,
        const float* __restrict__ alphap, int layer,
        float* __restrict__ pp) {
    __shared__ float smem[10304];    // stage 8192 | merge: ssum 2048 + sacc 8256
    float* kst = smem;               // [256][16]
    float* vst = smem + 4096;        // [256][16]
    float* ssum = smem;              // [8][256]   (merge phase)
    float* sacc = smem + 2048;       // [64][129]
    int bh = blockIdx.x & 15;        // b*8 + h
    int t = blockIdx.x >> 4;         // nb*KSP + ks
    int ks = t & (KSP_ - 1);
    int nb = t >> 2;                 // [0, 4)
    int b = bh >> 3;
    int wid = threadIdx.x >> 6;
    int lane = threadIdx.x & 63;
    float alpha = alphap[layer];
    {
        const float4* kg = (const float4*)(k + (((size_t)bh * N_ + ks * 256) << 4));
        const float4* vg = (const float4*)(v + (((size_t)bh * N_ + ks * 256) << 4));
        float4* ks4 = (float4*)kst;
        float4* vs4 = (float4*)vst;
        #pragma unroll
        for (int i = 0; i < 2; ++i) {
            int idx = threadIdx.x + i * 512;
            ks4[idx] = kg[idx];
            vs4[idx] = vg[idx];
        }
    }
    int n0 = nb * 256 + lane;        // queries n0 + u*64, u=0..3
    const float* cb = coords + (size_t)b * N_ * 3;
    float qv[QPL_][DK_];
    float cx[QPL_], cy[QPL_], cz[QPL_];
    #pragma unroll
    for (int u = 0; u < QPL_; ++u) {
        const float* qp = q + (((size_t)bh * N_ + n0 + u * 64) << 4);
        #pragma unroll
        for (int d = 0; d < DK_; ++d) qv[u][d] = qp[d];
        int nn = n0 + u * 64;
        cx[u] = cb[nn * 3]; cy[u] = cb[nn * 3 + 1]; cz[u] = cb[nn * 3 + 2];
    }
    float sm[QPL_];
    float acc[QPL_][DK_];
    #pragma unroll
    for (int u = 0; u < QPL_; ++u) {
        sm[u] = 0.f;
        #pragma unroll
        for (int d = 0; d < DK_; ++d) acc[u][d] = 0.f;
    }
    __syncthreads();                 // stage visible
    int mbase = ks * 256 + wid * 32;
    int lbase = wid * 32;
    #pragma unroll 2
    for (int j = 0; j < 32; ++j) {
        float kk[16];
        {
            const float4* kr = (const float4*)(kst + ((lbase + j) << 4));
            *(float4*)&kk[0] = kr[0]; *(float4*)&kk[4] = kr[1];
            *(float4*)&kk[8] = kr[2]; *(float4*)&kk[12] = kr[3];
        }
        int m = mbase + j;
        float wx = cb[m * 3], wy = cb[m * 3 + 1], wz = cb[m * 3 + 2];
        float p[QPL_];
        #pragma unroll
        for (int u = 0; u < QPL_; ++u) {
            float dot = 0.f;
            #pragma unroll
            for (int d = 0; d < DK_; ++d) dot += qv[u][d] * kk[d];
            p[u] = __expf(dot * 0.25f + alpha * (wx * cx[u] + wy * cy[u] + wz * cz[u]));
            sm[u] += p[u];
        }
        float vv[16];
        {
            const float4* vr = (const float4*)(vst + ((lbase + j) << 4));
            *(float4*)&vv[0] = vr[0]; *(float4*)&vv[4] = vr[1];
            *(float4*)&vv[8] = vr[2]; *(float4*)&vv[12] = vr[3];
        }
        #pragma unroll
        for (int u = 0; u < QPL_; ++u)
            #pragma unroll
            for (int d = 0; d < DK_; ++d) acc[u][d] += p[u] * vv[d];
    }
    __syncthreads();                 // done reading stage
    #pragma unroll
    for (int u = 0; u < QPL_; ++u) ssum[wid * 256 + u * 64 + lane] = sm[u];
    int qi = threadIdx.x & 63;
    int dq = threadIdx.x >> 6;       // 0..7, 2 d's each
    #pragma unroll
    for (int r = 0; r < QPL_; ++r) {
        #pragma unroll
        for (int d = 0; d < DK_; ++d) sacc[lane * 129 + wid * DK_ + d] = acc[r][d];
        __syncthreads();
        int n = nb * 256 + r * 64 + qi;
        float* o = pp + (((size_t)bh * N_ + n) * KSP_ + ks) * PREC_;
        if (dq == 0) {
            float gsum = 0.f;
            #pragma unroll
            for (int w = 0; w < AW_; ++w) gsum += ssum[w * 256 + r * 64 + qi];
            o[0] = gsum;
        }
        #pragma unroll
        for (int dd = 0; dd < 2; ++dd) {
            int d = dq * 2 + dd;
            float a = 0.f;
            #pragma unroll
            for (int w = 0; w < AW_; ++w) a += sacc[qi * 129 + w * DK_ + d];
            o[1 + d] = a;
        }
        __syncthreads();
    }
}

// ---------------- column mean over N (global feature) ----------------------
__global__ void colmean_kernel(const float* __restrict__ x,
                               float* __restrict__ gc) {
    int b = blockIdx.x;
    int d = threadIdx.x & 127;
    int sl = threadIdx.x >> 7;
    __shared__ float part[4][128];
    float s = 0.f;
    const float* xb = x + (size_t)b * N_ * D_;
    for (int n = sl * 256; n < sl * 256 + 256; ++n) s += xb[(size_t)n * D_ + d];
    part[sl][d] = s;
    __syncthreads();
    if (sl == 0)
        gc[b * D_ + d] = (part[0][d] + part[1][d] + part[2][d] + part[3][d]) * (1.0f / N_);
}

// ---------------- child = pred + (h . cw + cb), interleaved x2 -------------
__global__ void child_kernel(const float* __restrict__ h,
                             const float* __restrict__ cw,
                             const float* __restrict__ cb,
                             const float* __restrict__ pred,
                             float* __restrict__ outp, int Nq) {
    int idx = blockIdx.x * blockDim.x + threadIdx.x;
    if (idx >= B_ * Nq * 6) return;
    int p = idx % 3;
    int t = (idx / 3) & 1;
    int n = (idx / 6) % Nq;
    int b = idx / (6 * Nq);
    const float* hr = h + ((size_t)b * Nq + n) * 256;
    float acc = cb[p];
    #pragma unroll 4
    for (int o = 0; o < 128; ++o) acc += hr[o * 2 + t] * cw[p * 128 + o];
    outp[idx] = pred[((size_t)b * Nq + n) * 3 + p] + acc;
}

// ---------------------------------------------------------------------------
static inline int cdiv(int a, int b) { return (a + b - 1) / b; }

extern "C" void kernel_launch(void* const* d_in, const int* in_sizes, int n_in,
                              void* d_out, int out_size, void* d_ws, size_t ws_size,
                              hipStream_t stream) {
    (void)in_sizes; (void)n_in; (void)out_size; (void)ws_size;
    const float* coords = (const float*)d_in[0];
    const float* gcn_w0 = (const float*)d_in[1];
    const float* gcn_b0 = (const float*)d_in[2];
    const float* gcn_w1 = (const float*)d_in[3];
    const float* gcn_b1 = (const float*)d_in[4];
    const float* enc_fw = (const float*)d_in[5];
    const float* enc_fb = (const float*)d_in[6];
    const float* t_wq   = (const float*)d_in[7];
    const float* t_bq   = (const float*)d_in[8];
    const float* t_wk   = (const float*)d_in[9];
    const float* t_bk   = (const float*)d_in[10];
    const float* t_wv   = (const float*)d_in[11];
    const float* t_bv   = (const float*)d_in[12];
    const float* t_alpha= (const float*)d_in[13];
    const float* t_f1w  = (const float*)d_in[14];
    const float* t_f1b  = (const float*)d_in[15];
    const float* t_f2w  = (const float*)d_in[16];
    const float* t_f2b  = (const float*)d_in[17];
    const float* t_ln1g = (const float*)d_in[18];
    const float* t_ln1b = (const float*)d_in[19];
    const float* t_ln2g = (const float*)d_in[20];
    const float* t_ln2b = (const float*)d_in[21];
    const float* dec_w1 = (const float*)d_in[22];
    const float* dec_b1 = (const float*)d_in[23];
    const float* dec_w2 = (const float*)d_in[24];
    const float* dec_b2 = (const float*)d_in[25];
    const float* st_sw1 = (const float*)d_in[26];
    const float* st_sb1 = (const float*)d_in[27];
    const float* st_sw2 = (const float*)d_in[28];
    const float* st_sb2 = (const float*)d_in[29];
    const float* st_dw  = (const float*)d_in[30];
    const float* st_db  = (const float*)d_in[31];
    const float* st_cw  = (const float*)d_in[32];
    const float* st_cb  = (const float*)d_in[33];
    float* out = (float*)d_out;

    // ---- workspace carve ----
    char* ws = (char*)d_ws;
    size_t off = 0;
    auto alloc = [&](size_t bytes) -> void* {
        void* p = ws + off;
        off += (bytes + 255) & ~(size_t)255;
        return p;
    };
    int*   knn   = (int*)  alloc((size_t)B_ * N_ * KG_ * 4);
    float* ppd   = (float*)alloc((size_t)B_ * 2048 * NCH_ * KG_ * 4);
    int*   ppi   = (int*)  alloc((size_t)B_ * 2048 * NCH_ * KG_ * 4);
    float* app   = (float*)alloc((size_t)B_ * H_ * N_ * KSP_ * PREC_ * 4);
    float* agg   = (float*)alloc((size_t)B_ * N_ * 64 * 4);
    float* x64   = (float*)alloc((size_t)B_ * N_ * 64 * 4);
    float* xb    = (float*)alloc((size_t)B_ * N_ * D_ * 4);
    float* x     = (float*)alloc((size_t)B_ * N_ * D_ * 4);
    float* q     = (float*)alloc((size_t)B_ * N_ * D_ * 4);
    float* k     = (float*)alloc((size_t)B_ * N_ * D_ * 4);
    float* v     = (float*)alloc((size_t)B_ * N_ * D_ * 4);
    float* ffh   = (float*)alloc((size_t)B_ * N_ * 512 * 4);
    float* gc    = (float*)alloc((size_t)B_ * D_ * 4);
    float* dech  = (float*)alloc((size_t)B_ * D_ * 4);
    float* pts0  = (float*)alloc((size_t)B_ * COARSE_ * 3 * 4);
    float* pts1  = (float*)alloc((size_t)B_ * 1024 * 3 * 4);
    float* pts2  = (float*)alloc((size_t)B_ * 2048 * 3 * 4);
    float* comb  = (float*)alloc((size_t)B_ * 2048 * 6 * 4);
    float* seedh = (float*)alloc((size_t)B_ * 2048 * 128 * 4);
    float* seed  = (float*)alloc((size_t)B_ * 2048 * 128 * 4);
    float* hb    = (float*)alloc((size_t)B_ * 2048 * 256 * 4);

    const int rows = B_ * N_;   // 2048

    // ---- graph encoder ----
    knn_part_kernel<<<B_ * NCH_ * 16, 64, 0, stream>>>(coords, ppd, ppi);
    knn_merge_kernel<<<B_ * N_ / 4, 256, 0, stream>>>(ppd, ppi, knn);
    gcn_agg_kernel<<<cdiv(rows * 3, 256), 256, 0, stream>>>(coords, knn, agg, 3);
    linear4_kernel<true><<<cdiv(rows * 16, 256), 256, 0, stream>>>(agg, gcn_w0, gcn_b0, x64, rows, 3, 64);
    gcn_agg_kernel<<<cdiv(rows * 64, 256), 256, 0, stream>>>(x64, knn, agg, 64);
    gemm128_kernel<64, true, false><<<dim3(rows / 8, 1), 256, 0, stream>>>(agg, gcn_w1, gcn_b1, xb, 128, 128);
    gemm128_kernel<128, false, false><<<dim3(rows / 8, 1), 256, 0, stream>>>(xb, enc_fw, enc_fb, x, 128, 128);

    // ---- transformer ----
    for (int i = 0; i < L_; ++i) {
        qkv3_kernel<<<dim3(rows / 8, 3), 256, 0, stream>>>(
            x, t_wq + i * 16384, t_bq + i * 128, t_wk + i * 16384, t_bk + i * 128,
            t_wv + i * 16384, t_bv + i * 128, q, k, v);
        attn_part<<<B_ * H_ * (N_ / 256) * KSP_, 512, 0, stream>>>(q, k, v, coords, t_alpha, i, app);
        // FFN1 with fused attn-merge + residual + LN1 (LN rows -> xb)
        gemm_ffn1_kernel<<<dim3(rows / 8, 4), 256, 0, stream>>>(
            app, x, t_ln1g + i * 128, t_ln1b + i * 128,
            t_f1w + i * 128 * 512, t_f1b + i * 512, xb, ffh);
        gemm_ln_kernel<512><<<rows / 8, 256, 0, stream>>>(ffh, t_f2w + i * 512 * 128, t_f2b + i * 128, xb, t_ln2g + i * 128, t_ln2b + i * 128, x);
    }

    // ---- decoder coarse ----
    colmean_kernel<<<B_, 512, 0, stream>>>(x, gc);
    linear4_kernel<true><<<cdiv(B_ * 32, 256), 256, 0, stream>>>(gc, dec_w1, dec_b1, dech, B_, 128, 128);
    linear4_kernel<false><<<cdiv(B_ * 384, 256), 256, 0, stream>>>(dech, dec_w2, dec_b2, pts0, B_, 128, 1536);

    // ---- refine stages ----
    const float* pred = pts0;
    float* outs[3] = { pts1, pts2, out };
    int Nq = COARSE_;
    for (int s = 0; s < 3; ++s) {
        loc_part_kernel<<<dim3(Nq / 64, NCH_, B_), 64, 0, stream>>>(coords, pred, ppd, ppi, Nq);
        loc_merge_kernel<<<(B_ * Nq) / 4, 256, 0, stream>>>(coords, pred, ppd, ppi, comb, Nq);
        int srows = B_ * Nq;
        linear4_kernel<true><<<cdiv(srows * 32, 256), 256, 0, stream>>>(comb, st_sw1 + s * 6 * 128, st_sb1 + s * 128, seedh, srows, 6, 128);
        gemm128_kernel<128, false, false><<<dim3(srows / 8, 1), 256, 0, stream>>>(seedh, st_sw2 + s * 128 * 128, st_sb2 + s * 128, seed, 128, 128);
        gemm128_kernel<128, true, true><<<dim3(srows / 8, 2), 256, 0, stream>>>(seed, st_dw + s * 128 * 256, st_db + s * 128, hb, 256, 256);
        child_kernel<<<cdiv(srows * 6, 256), 256, 0, stream>>>(hb, st_cw + s * 3 * 128, st_cb + s * 3, pred, outs[s], Nq);
        pred = outs[s];
        Nq <<= 1;
    }
}

// Round 18
// 422.435 us; speedup vs baseline: 1.5545x; 1.1532x over previous
//
#include <hip/hip_runtime.h>

// ---------------------------------------------------------------------------
// FullModelSnowflake.  R17: single-kernel KNNs — one wave scans all 1024
// candidates (16/lane, index = (j<<6)|lane so invalidation is static),
// butterfly min-extraction.  Kills knn_part/loc_part + partial-list traffic;
// refine stage also fuses the 6->128 seed linear (comb lives in registers on
// all lanes).  44 -> 37 launches.
// ---------------------------------------------------------------------------

#define B_ 2
#define N_ 1024
#define D_ 128
#define H_ 8
#define DK_ 16
#define L_ 4
#define KG_ 16
#define KLOC_ 8
#define COARSE_ 512
#define AW_ 8            // waves per attention block
#define KSP_ 4           // block-level key splits
#define PREC_ 17         // floats per attention partial (sum + 16 acc)
#define QPL_ 4           // queries per lane

static __device__ __forceinline__ float wave_sum(float v) {
    #pragma unroll
    for (int off = 32; off > 0; off >>= 1) v += __shfl_xor(v, off);
    return v;
}
static __device__ __forceinline__ float half_sum(float v) {
    #pragma unroll
    for (int off = 16; off > 0; off >>= 1) v += __shfl_xor(v, off);
    return v;
}

// ---------------- LDS-staged GEMM body: returns this thread's acc ----------
template <int CIN, bool RELU, bool BIAS_HALF>
static __device__ __forceinline__ float4 gemm_body(
        const float* __restrict__ X, const float* __restrict__ W,
        const float* __restrict__ bias, int wstride, int col0) {
    __shared__ float Xs[8 * CIN];
    __shared__ float Ws[64][128];
    int tid = threadIdx.x;
    int row0 = blockIdx.x * 8;
    constexpr int NX4 = 2 * CIN;
    {
        const float4* xg = (const float4*)(X + (size_t)row0 * CIN);
        float4* xs4 = (float4*)Xs;
        #pragma unroll
        for (int i = 0; i < (NX4 + 255) / 256; ++i) {
            int t = tid + i * 256;
            if ((NX4 % 256 == 0) || t < NX4) xs4[t] = xg[t];
        }
    }
    int col4 = (tid & 31) << 2;
    int rowl = tid >> 5;
    float4 acc;
    if (BIAS_HALF) {
        acc.x = bias[(col0 + col4) >> 1];
        acc.y = bias[(col0 + col4 + 1) >> 1];
        acc.z = bias[(col0 + col4 + 2) >> 1];
        acc.w = bias[(col0 + col4 + 3) >> 1];
    } else {
        acc = *(const float4*)(bias + col0 + col4);
    }
    for (int c0 = 0; c0 < CIN; c0 += 64) {
        __syncthreads();
        #pragma unroll
        for (int i = 0; i < 8; ++i) {
            int flat = tid + i * 256;
            int wr = flat >> 5, wc = (flat & 31) << 2;
            *(float4*)&Ws[wr][wc] =
                *(const float4*)(W + (size_t)(c0 + wr) * wstride + col0 + wc);
        }
        __syncthreads();
        const float* xrow = Xs + rowl * CIN + c0;
        #pragma unroll
        for (int c = 0; c < 64; ++c) {
            float xv = xrow[c];
            float4 w = *(const float4*)&Ws[c][col4];
            acc.x += xv * w.x; acc.y += xv * w.y;
            acc.z += xv * w.z; acc.w += xv * w.w;
        }
    }
    if (RELU) {
        acc.x = fmaxf(acc.x, 0.f); acc.y = fmaxf(acc.y, 0.f);
        acc.z = fmaxf(acc.z, 0.f); acc.w = fmaxf(acc.w, 0.f);
    }
    return acc;
}

template <int CIN, bool RELU, bool BIAS_HALF>
__global__ __launch_bounds__(256) void gemm128_kernel(
        const float* __restrict__ X, const float* __restrict__ W,
        const float* __restrict__ bias, float* __restrict__ Y,
        int wstride, int ystride) {
    int col0 = blockIdx.y * 128;
    float4 acc = gemm_body<CIN, RELU, BIAS_HALF>(X, W, bias, wstride, col0);
    int col4 = (threadIdx.x & 31) << 2;
    int row = blockIdx.x * 8 + (threadIdx.x >> 5);
    *(float4*)(Y + (size_t)row * ystride + col0 + col4) = acc;
}

// GEMM (Cout=128) fused with residual-add + LayerNorm epilogue.
template <int CIN>
__global__ __launch_bounds__(256) void gemm_ln_kernel(
        const float* __restrict__ X, const float* __restrict__ W,
        const float* __restrict__ bias, const float* __restrict__ res,
        const float* __restrict__ g, const float* __restrict__ bt,
        float* __restrict__ Y) {
    float4 acc = gemm_body<CIN, false, false>(X, W, bias, 128, 0);
    int col4 = (threadIdx.x & 31) << 2;
    int row = blockIdx.x * 8 + (threadIdx.x >> 5);
    float4 r = *(const float4*)(res + (size_t)row * D_ + col4);
    acc.x += r.x; acc.y += r.y; acc.z += r.z; acc.w += r.w;
    float mean = half_sum(acc.x + acc.y + acc.z + acc.w) * (1.0f / D_);
    float dx = acc.x - mean, dy = acc.y - mean, dz = acc.z - mean, dw = acc.w - mean;
    float var = half_sum(dx * dx + dy * dy + dz * dz + dw * dw) * (1.0f / D_);
    float rstd = rsqrtf(var + 1e-5f);
    float4 gv = *(const float4*)(g + col4);
    float4 bv = *(const float4*)(bt + col4);
    float4 o;
    o.x = dx * rstd * gv.x + bv.x;
    o.y = dy * rstd * gv.y + bv.y;
    o.z = dz * rstd * gv.z + bv.z;
    o.w = dw * rstd * gv.w + bv.w;
    *(float4*)(Y + (size_t)row * D_ + col4) = o;
}

// FFN1 GEMM with fused attn-final-merge + residual + LN in the X-stage.
__global__ __launch_bounds__(256) void gemm_ffn1_kernel(
        const float* __restrict__ pp, const float* __restrict__ xin,
        const float* __restrict__ g, const float* __restrict__ bt,
        const float* __restrict__ W, const float* __restrict__ bias,
        float* __restrict__ xln, float* __restrict__ Y) {
    __shared__ float Xs[8 * 128];
    __shared__ float Ws[64][128];
    int tid = threadIdx.x;
    int row0 = blockIdx.x * 8;
    int col0 = blockIdx.y * 128;
    int col4 = (tid & 31) << 2;
    int rowl = tid >> 5;
    {
        int row = row0 + rowl;
        int b = row >> 10, n = row & (N_ - 1);
        int h = col4 >> 4, d0 = col4 & 15;
        const float* p = pp + (((size_t)(b * 8 + h) * N_ + n) * KSP_) * PREC_;
        float gsum = 0.f, a0 = 0.f, a1 = 0.f, a2 = 0.f, a3 = 0.f;
        #pragma unroll
        for (int s = 0; s < KSP_; ++s) {
            const float* ps = p + s * PREC_;
            gsum += ps[0];
            a0 += ps[1 + d0]; a1 += ps[2 + d0]; a2 += ps[3 + d0]; a3 += ps[4 + d0];
        }
        float inv = 1.0f / gsum;
        float4 xv = *(const float4*)(xin + (size_t)row * D_ + col4);
        float v0 = a0 * inv + xv.x;
        float v1 = a1 * inv + xv.y;
        float v2 = a2 * inv + xv.z;
        float v3 = a3 * inv + xv.w;
        float mean = half_sum(v0 + v1 + v2 + v3) * (1.0f / D_);
        float dx = v0 - mean, dy = v1 - mean, dz = v2 - mean, dw = v3 - mean;
        float var = half_sum(dx * dx + dy * dy + dz * dz + dw * dw) * (1.0f / D_);
        float rstd = rsqrtf(var + 1e-5f);
        float4 gv = *(const float4*)(g + col4);
        float4 bv = *(const float4*)(bt + col4);
        float4 o;
        o.x = dx * rstd * gv.x + bv.x;
        o.y = dy * rstd * gv.y + bv.y;
        o.z = dz * rstd * gv.z + bv.z;
        o.w = dw * rstd * gv.w + bv.w;
        *(float4*)&Xs[rowl * 128 + col4] = o;
        if (blockIdx.y == 0)
            *(float4*)(xln + (size_t)row * D_ + col4) = o;
    }
    float4 acc = *(const float4*)(bias + col0 + col4);
    for (int c0 = 0; c0 < 128; c0 += 64) {
        __syncthreads();
        #pragma unroll
        for (int i = 0; i < 8; ++i) {
            int flat = tid + i * 256;
            int wr = flat >> 5, wc = (flat & 31) << 2;
            *(float4*)&Ws[wr][wc] =
                *(const float4*)(W + (size_t)(c0 + wr) * 512 + col0 + wc);
        }
        __syncthreads();
        const float* xrow = Xs + rowl * 128 + c0;
        #pragma unroll
        for (int c = 0; c < 64; ++c) {
            float xv = xrow[c];
            float4 w = *(const float4*)&Ws[c][col4];
            acc.x += xv * w.x; acc.y += xv * w.y;
            acc.z += xv * w.z; acc.w += xv * w.w;
        }
    }
    acc.x = fmaxf(acc.x, 0.f); acc.y = fmaxf(acc.y, 0.f);
    acc.z = fmaxf(acc.z, 0.f); acc.w = fmaxf(acc.w, 0.f);
    int row = row0 + rowl;
    *(float4*)(Y + (size_t)row * 512 + col0 + col4) = acc;
}

// fused QKV: 3 W-panels via blockIdx.y; outputs stored HEAD-MAJOR [bh][n][16]
__global__ __launch_bounds__(256) void qkv3_kernel(
        const float* __restrict__ X,
        const float* __restrict__ Wq, const float* __restrict__ bq,
        const float* __restrict__ Wk, const float* __restrict__ bk,
        const float* __restrict__ Wv, const float* __restrict__ bv,
        float* __restrict__ Q, float* __restrict__ K, float* __restrict__ V) {
    const float* W; const float* bias; float* Y;
    if (blockIdx.y == 0)      { W = Wq; bias = bq; Y = Q; }
    else if (blockIdx.y == 1) { W = Wk; bias = bk; Y = K; }
    else                      { W = Wv; bias = bv; Y = V; }
    float4 acc = gemm_body<128, false, false>(X, W, bias, 128, 0);
    int col4 = (threadIdx.x & 31) << 2;
    int row = blockIdx.x * 8 + (threadIdx.x >> 5);
    int b = row >> 10, n = row & (N_ - 1);
    int h = col4 >> 4, d = col4 & 15;
    *(float4*)(Y + (((size_t)(b * 8 + h) * N_ + n) << 4) + d) = acc;
}

// ---------------- single-kernel self-KNN: one wave per query ---------------
// Lane holds 16 candidate distances (m = (j<<6)|lane); 16 rounds of
// butterfly min-extraction on (d, idx); invalidation via static-index test.
__global__ __launch_bounds__(256) void knn_fused_kernel(
        const float* __restrict__ coords, int* __restrict__ knn) {
    __shared__ float4 sc[N_];
    int wid = threadIdx.x >> 6;
    int lane = threadIdx.x & 63;
    size_t q = (size_t)blockIdx.x * 4 + wid;
    int b = (int)(q >> 10), n = (int)(q & (N_ - 1));
    const float* cb = coords + (size_t)b * N_ * 3;
    for (int i = threadIdx.x; i < N_; i += 256) {
        float x = cb[i * 3], y = cb[i * 3 + 1], z = cb[i * 3 + 2];
        sc[i] = make_float4(x, y, z, x * x + y * y + z * z);
    }
    __syncthreads();
    float4 qc = sc[n];
    float qx = qc.x, qy = qc.y, qz = qc.z, q2 = qc.w;
    float ld[16];
    #pragma unroll
    for (int j = 0; j < 16; ++j) {
        int m = (j << 6) | lane;
        float4 c = sc[m];
        float dot = qx * c.x + qy * c.y + qz * c.z;
        float d = (q2 - 2.0f * dot) + c.w;
        ld[j] = (m == n) ? 3e38f : d;
    }
    int* o = knn + q * KG_;
    #pragma unroll
    for (int r = 0; r < KG_; ++r) {
        float dm = ld[0]; int im = lane;
        #pragma unroll
        for (int j = 1; j < 16; ++j) {
            int mj = (j << 6) | lane;
            bool lt = (ld[j] < dm) || (ld[j] == dm && mj < im);
            dm = lt ? ld[j] : dm; im = lt ? mj : im;
        }
        #pragma unroll
        for (int off = 32; off > 0; off >>= 1) {
            float d2 = __shfl_xor(dm, off); int i2 = __shfl_xor(im, off);
            bool lt = (d2 < dm) || (d2 == dm && i2 < im);
            dm = lt ? d2 : dm; im = lt ? i2 : im;
        }
        if (lane == 0) o[r] = im;
        if ((im & 63) == lane) {
            #pragma unroll
            for (int j = 0; j < 16; ++j) if ((im >> 6) == j) ld[j] = 3e38f;
        }
    }
}

// ---------------- single-kernel local-KNN + mean + seed linear -------------
// One wave per query; after extraction every lane holds comb = [pred, nm];
// fused 6->128 seed linear (relu) writes seedh (2 cols/lane).
__global__ __launch_bounds__(256) void loc_fused_kernel(
        const float* __restrict__ part, const float* __restrict__ pred,
        const float* __restrict__ sw1, const float* __restrict__ sb1,
        float* __restrict__ seedh, int Nq) {
    __shared__ float4 sc[N_];
    int wid = threadIdx.x >> 6;
    int lane = threadIdx.x & 63;
    size_t q = (size_t)blockIdx.x * 4 + wid;
    int b = (int)(q / Nq);
    const float* pb = part + (size_t)b * N_ * 3;
    for (int i = threadIdx.x; i < N_; i += 256) {
        float x = pb[i * 3], y = pb[i * 3 + 1], z = pb[i * 3 + 2];
        sc[i] = make_float4(x, y, z, x * x + y * y + z * z);
    }
    __syncthreads();
    const float* pr = pred + q * 3;
    float qx = pr[0], qy = pr[1], qz = pr[2];
    float q2 = qx * qx + qy * qy + qz * qz;
    float ld[16];
    #pragma unroll
    for (int j = 0; j < 16; ++j) {
        int m = (j << 6) | lane;
        float4 c = sc[m];
        float dot = qx * c.x + qy * c.y + qz * c.z;
        ld[j] = (q2 - 2.0f * dot) + c.w;
    }
    float sx = 0.f, sy = 0.f, sz = 0.f;
    #pragma unroll
    for (int r = 0; r < KLOC_; ++r) {
        float dm = ld[0]; int im = lane;
        #pragma unroll
        for (int j = 1; j < 16; ++j) {
            int mj = (j << 6) | lane;
            bool lt = (ld[j] < dm) || (ld[j] == dm && mj < im);
            dm = lt ? ld[j] : dm; im = lt ? mj : im;
        }
        #pragma unroll
        for (int off = 32; off > 0; off >>= 1) {
            float d2 = __shfl_xor(dm, off); int i2 = __shfl_xor(im, off);
            bool lt = (d2 < dm) || (d2 == dm && i2 < im);
            dm = lt ? d2 : dm; im = lt ? i2 : im;
        }
        float4 w = sc[im];               // broadcast
        sx += w.x; sy += w.y; sz += w.z;
        if ((im & 63) == lane) {
            #pragma unroll
            for (int j = 0; j < 16; ++j) if ((im >> 6) == j) ld[j] = 3e38f;
        }
    }
    // every lane holds comb; fused seed linear (6 -> 128, relu), 2 cols/lane
    float comb[6];
    comb[0] = qx; comb[1] = qy; comb[2] = qz;
    comb[3] = sx * (1.0f / KLOC_);
    comb[4] = sy * (1.0f / KLOC_);
    comb[5] = sz * (1.0f / KLOC_);
    float* so = seedh + q * 128;
    #pragma unroll
    for (int half = 0; half < 2; ++half) {
        int c = lane + half * 64;
        float acc = sb1[c];
        #pragma unroll
        for (int i = 0; i < 6; ++i) acc += comb[i] * sw1[i * 128 + c];
        so[c] = fmaxf(acc, 0.f);
    }
}

// ---------------- GCN aggregation: (x + sum_nb) / (k+1) --------------------
__global__ void gcn_agg_kernel(const float* __restrict__ x,
                               const int* __restrict__ knn,
                               float* __restrict__ agg, int C) {
    int i = blockIdx.x * blockDim.x + threadIdx.x;
    if (i >= B_ * N_ * C) return;
    int c = i % C;
    int n = (i / C) % N_;
    int b = i / (C * N_);
    const int* id = knn + ((size_t)b * N_ + n) * KG_;
    float s = x[((size_t)b * N_ + n) * C + c];
    #pragma unroll
    for (int j = 0; j < KG_; ++j) s += x[((size_t)b * N_ + id[j]) * C + c];
    agg[i] = s * (1.0f / (KG_ + 1));
}

// ---------------- linear: 4 outputs per thread (small cases) ---------------
template <bool RELU>
__global__ void linear4_kernel(const float* __restrict__ X,
                               const float* __restrict__ W,
                               const float* __restrict__ bias,
                               float* __restrict__ Y,
                               int rows, int Cin, int Cout) {
    int co4 = Cout >> 2;
    int idx = blockIdx.x * blockDim.x + threadIdx.x;
    if (idx >= rows * co4) return;
    int r = idx / co4, o4 = (idx - r * co4) << 2;
    const float* x = X + (size_t)r * Cin;
    float4 acc = *(const float4*)(bias + o4);
    #pragma unroll 4
    for (int c = 0; c < Cin; ++c) {
        float xv = x[c];
        float4 w = *(const float4*)(W + (size_t)c * Cout + o4);
        acc.x += xv * w.x; acc.y += xv * w.y; acc.z += xv * w.z; acc.w += xv * w.w;
    }
    if (RELU) {
        acc.x = fmaxf(acc.x, 0.f); acc.y = fmaxf(acc.y, 0.f);
        acc.z = fmaxf(acc.z, 0.f); acc.w = fmaxf(acc.w, 0.f);
    }
    *(float4*)(Y + (size_t)r * Cout + o4) = acc;
}

// ---------------- attention: 4 queries/lane, LDS-staged K/V ----------------
__global__ __launch_bounds__(512) void attn_part(
        const float* __restrict__ q,
        const float* __restrict__ k,
        const float* __restrict__ v,
        const float* __restrict__ coords,
        const float* __restrict__ alphap, int layer,
        float* __restrict__ pp) {
    __shared__ float smem[10304];    // stage 8192 | merge: ssum 2048 + sacc 8256
    float* kst = smem;               // [256][16]
    float* vst = smem + 4096;        // [256][16]
    float* ssum = smem;              // [8][256]   (merge phase)
    float* sacc = smem + 2048;       // [64][129]
    int bh = blockIdx.x & 15;        // b*8 + h
    int t = blockIdx.x >> 4;         // nb*KSP + ks
    int ks = t & (KSP_ - 1);
    int nb = t >> 2;                 // [0, 4)
    int b = bh >> 3;
    int wid = threadIdx.x >> 6;
    int lane = threadIdx.x & 63;
    float alpha = alphap[layer];
    {
        const float4* kg = (const float4*)(k + (((size_t)bh * N_ + ks * 256) << 4));
        const float4* vg = (const float4*)(v + (((size_t)bh * N_ + ks * 256) << 4));
        float4* ks4 = (float4*)kst;
        float4* vs4 = (float4*)vst;
        #pragma unroll
        for (int i = 0; i < 2; ++i) {
            int idx = threadIdx.x + i * 512;
            ks4[idx] = kg[idx];
            vs4[idx] = vg[idx];
        }
    }
    int n0 = nb * 256 + lane;        // queries n0 + u*64, u=0..3
    const float* cb = coords + (size_t)b * N_ * 3;
    float qv[QPL_][DK_];
    float cx[QPL_], cy[QPL_], cz[QPL_];
    #pragma unroll
    for (int u = 0; u < QPL_; ++u) {
        const float* qp = q + (((size_t)bh * N_ + n0 + u * 64) << 4);
        #pragma unroll
        for (int d = 0; d < DK_; ++d) qv[u][d] = qp[d];
        int nn = n0 + u * 64;
        cx[u] = cb[nn * 3]; cy[u] = cb[nn * 3 + 1]; cz[u] = cb[nn * 3 + 2];
    }
    float sm[QPL_];
    float acc[QPL_][DK_];
    #pragma unroll
    for (int u = 0; u < QPL_; ++u) {
        sm[u] = 0.f;
        #pragma unroll
        for (int d = 0; d < DK_; ++d) acc[u][d] = 0.f;
    }
    __syncthreads();                 // stage visible
    int mbase = ks * 256 + wid * 32;
    int lbase = wid * 32;
    #pragma unroll 2
    for (int j = 0; j < 32; ++j) {
        float kk[16];
        {
            const float4* kr = (const float4*)(kst + ((lbase + j) << 4));
            *(float4*)&kk[0] = kr[0]; *(float4*)&kk[4] = kr[1];
            *(float4*)&kk[8] = kr[2]; *(float4*)&kk[12] = kr[3];
        }
        int m = mbase + j;
        float wx = cb[m * 3], wy = cb[m * 3 + 1], wz = cb[m * 3 + 2];
        float p[QPL_];
        #pragma unroll
        for (int u = 0; u < QPL_; ++u) {
            float dot = 0.f;
            #pragma unroll
            for (int d = 0; d < DK_; ++d) dot += qv[u][d] * kk[d];
            p[u] = __expf(dot * 0.25f + alpha * (wx * cx[u] + wy * cy[u] + wz * cz[u]));
            sm[u] += p[u];
        }
        float vv[16];
        {
            const float4* vr = (const float4*)(vst + ((lbase + j) << 4));
            *(float4*)&vv[0] = vr[0]; *(float4*)&vv[4] = vr[1];
            *(float4*)&vv[8] = vr[2]; *(float4*)&vv[12] = vr[3];
        }
        #pragma unroll
        for (int u = 0; u < QPL_; ++u)
            #pragma unroll
            for (int d = 0; d < DK_; ++d) acc[u][d] += p[u] * vv[d];
    }
    __syncthreads();                 // done reading stage
    #pragma unroll
    for (int u = 0; u < QPL_; ++u) ssum[wid * 256 + u * 64 + lane] = sm[u];
    int qi = threadIdx.x & 63;
    int dq = threadIdx.x >> 6;       // 0..7, 2 d's each
    #pragma unroll
    for (int r = 0; r < QPL_; ++r) {
        #pragma unroll
        for (int d = 0; d < DK_; ++d) sacc[lane * 129 + wid * DK_ + d] = acc[r][d];
        __syncthreads();
        int n = nb * 256 + r * 64 + qi;
        float* o = pp + (((size_t)bh * N_ + n) * KSP_ + ks) * PREC_;
        if (dq == 0) {
            float gsum = 0.f;
            #pragma unroll
            for (int w = 0; w < AW_; ++w) gsum += ssum[w * 256 + r * 64 + qi];
            o[0] = gsum;
        }
        #pragma unroll
        for (int dd = 0; dd < 2; ++dd) {
            int d = dq * 2 + dd;
            float a = 0.f;
            #pragma unroll
            for (int w = 0; w < AW_; ++w) a += sacc[qi * 129 + w * DK_ + d];
            o[1 + d] = a;
        }
        __syncthreads();
    }
}

// ---------------- column mean over N (global feature) ----------------------
__global__ void colmean_kernel(const float* __restrict__ x,
                               float* __restrict__ gc) {
    int b = blockIdx.x;
    int d = threadIdx.x & 127;
    int sl = threadIdx.x >> 7;
    __shared__ float part[4][128];
    float s = 0.f;
    const float* xb = x + (size_t)b * N_ * D_;
    for (int n = sl * 256; n < sl * 256 + 256; ++n) s += xb[(size_t)n * D_ + d];
    part[sl][d] = s;
    __syncthreads();
    if (sl == 0)
        gc[b * D_ + d] = (part[0][d] + part[1][d] + part[2][d] + part[3][d]) * (1.0f / N_);
}

// ---------------- child = pred + (h . cw + cb), interleaved x2 -------------
__global__ void child_kernel(const float* __restrict__ h,
                             const float* __restrict__ cw,
                             const float* __restrict__ cb,
                             const float* __restrict__ pred,
                             float* __restrict__ outp, int Nq) {
    int idx = blockIdx.x * blockDim.x + threadIdx.x;
    if (idx >= B_ * Nq * 6) return;
    int p = idx % 3;
    int t = (idx / 3) & 1;
    int n = (idx / 6) % Nq;
    int b = idx / (6 * Nq);
    const float* hr = h + ((size_t)b * Nq + n) * 256;
    float acc = cb[p];
    #pragma unroll 4
    for (int o = 0; o < 128; ++o) acc += hr[o * 2 + t] * cw[p * 128 + o];
    outp[idx] = pred[((size_t)b * Nq + n) * 3 + p] + acc;
}

// ---------------------------------------------------------------------------
static inline int cdiv(int a, int b) { return (a + b - 1) / b; }

extern "C" void kernel_launch(void* const* d_in, const int* in_sizes, int n_in,
                              void* d_out, int out_size, void* d_ws, size_t ws_size,
                              hipStream_t stream) {
    (void)in_sizes; (void)n_in; (void)out_size; (void)ws_size;
    const float* coords = (const float*)d_in[0];
    const float* gcn_w0 = (const float*)d_in[1];
    const float* gcn_b0 = (const float*)d_in[2];
    const float* gcn_w1 = (const float*)d_in[3];
    const float* gcn_b1 = (const float*)d_in[4];
    const float* enc_fw = (const float*)d_in[5];
    const float* enc_fb = (const float*)d_in[6];
    const float* t_wq   = (const float*)d_in[7];
    const float* t_bq   = (const float*)d_in[8];
    const float* t_wk   = (const float*)d_in[9];
    const float* t_bk   = (const float*)d_in[10];
    const float* t_wv   = (const float*)d_in[11];
    const float* t_bv   = (const float*)d_in[12];
    const float* t_alpha= (const float*)d_in[13];
    const float* t_f1w  = (const float*)d_in[14];
    const float* t_f1b  = (const float*)d_in[15];
    const float* t_f2w  = (const float*)d_in[16];
    const float* t_f2b  = (const float*)d_in[17];
    const float* t_ln1g = (const float*)d_in[18];
    const float* t_ln1b = (const float*)d_in[19];
    const float* t_ln2g = (const float*)d_in[20];
    const float* t_ln2b = (const float*)d_in[21];
    const float* dec_w1 = (const float*)d_in[22];
    const float* dec_b1 = (const float*)d_in[23];
    const float* dec_w2 = (const float*)d_in[24];
    const float* dec_b2 = (const float*)d_in[25];
    const float* st_sw1 = (const float*)d_in[26];
    const float* st_sb1 = (const float*)d_in[27];
    const float* st_sw2 = (const float*)d_in[28];
    const float* st_sb2 = (const float*)d_in[29];
    const float* st_dw  = (const float*)d_in[30];
    const float* st_db  = (const float*)d_in[31];
    const float* st_cw  = (const float*)d_in[32];
    const float* st_cb  = (const float*)d_in[33];
    float* out = (float*)d_out;

    // ---- workspace carve ----
    char* ws = (char*)d_ws;
    size_t off = 0;
    auto alloc = [&](size_t bytes) -> void* {
        void* p = ws + off;
        off += (bytes + 255) & ~(size_t)255;
        return p;
    };
    int*   knn   = (int*)  alloc((size_t)B_ * N_ * KG_ * 4);
    float* app   = (float*)alloc((size_t)B_ * H_ * N_ * KSP_ * PREC_ * 4);
    float* agg   = (float*)alloc((size_t)B_ * N_ * 64 * 4);
    float* x64   = (float*)alloc((size_t)B_ * N_ * 64 * 4);
    float* xb    = (float*)alloc((size_t)B_ * N_ * D_ * 4);
    float* x     = (float*)alloc((size_t)B_ * N_ * D_ * 4);
    float* q     = (float*)alloc((size_t)B_ * N_ * D_ * 4);
    float* k     = (float*)alloc((size_t)B_ * N_ * D_ * 4);
    float* v     = (float*)alloc((size_t)B_ * N_ * D_ * 4);
    float* ffh   = (float*)alloc((size_t)B_ * N_ * 512 * 4);
    float* gc    = (float*)alloc((size_t)B_ * D_ * 4);
    float* dech  = (float*)alloc((size_t)B_ * D_ * 4);
    float* pts0  = (float*)alloc((size_t)B_ * COARSE_ * 3 * 4);
    float* pts1  = (float*)alloc((size_t)B_ * 1024 * 3 * 4);
    float* pts2  = (float*)alloc((size_t)B_ * 2048 * 3 * 4);
    float* seedh = (float*)alloc((size_t)B_ * 2048 * 128 * 4);
    float* seed  = (float*)alloc((size_t)B_ * 2048 * 128 * 4);
    float* hb    = (float*)alloc((size_t)B_ * 2048 * 256 * 4);

    const int rows = B_ * N_;   // 2048

    // ---- graph encoder ----
    knn_fused_kernel<<<rows / 4, 256, 0, stream>>>(coords, knn);
    gcn_agg_kernel<<<cdiv(rows * 3, 256), 256, 0, stream>>>(coords, knn, agg, 3);
    linear4_kernel<true><<<cdiv(rows * 16, 256), 256, 0, stream>>>(agg, gcn_w0, gcn_b0, x64, rows, 3, 64);
    gcn_agg_kernel<<<cdiv(rows * 64, 256), 256, 0, stream>>>(x64, knn, agg, 64);
    gemm128_kernel<64, true, false><<<dim3(rows / 8, 1), 256, 0, stream>>>(agg, gcn_w1, gcn_b1, xb, 128, 128);
    gemm128_kernel<128, false, false><<<dim3(rows / 8, 1), 256, 0, stream>>>(xb, enc_fw, enc_fb, x, 128, 128);

    // ---- transformer ----
    for (int i = 0; i < L_; ++i) {
        qkv3_kernel<<<dim3(rows / 8, 3), 256, 0, stream>>>(
            x, t_wq + i * 16384, t_bq + i * 128, t_wk + i * 16384, t_bk + i * 128,
            t_wv + i * 16384, t_bv + i * 128, q, k, v);
        attn_part<<<B_ * H_ * (N_ / 256) * KSP_, 512, 0, stream>>>(q, k, v, coords, t_alpha, i, app);
        gemm_ffn1_kernel<<<dim3(rows / 8, 4), 256, 0, stream>>>(
            app, x, t_ln1g + i * 128, t_ln1b + i * 128,
            t_f1w + i * 128 * 512, t_f1b + i * 512, xb, ffh);
        gemm_ln_kernel<512><<<rows / 8, 256, 0, stream>>>(ffh, t_f2w + i * 512 * 128, t_f2b + i * 128, xb, t_ln2g + i * 128, t_ln2b + i * 128, x);
    }

    // ---- decoder coarse ----
    colmean_kernel<<<B_, 512, 0, stream>>>(x, gc);
    linear4_kernel<true><<<cdiv(B_ * 32, 256), 256, 0, stream>>>(gc, dec_w1, dec_b1, dech, B_, 128, 128);
    linear4_kernel<false><<<cdiv(B_ * 384, 256), 256, 0, stream>>>(dech, dec_w2, dec_b2, pts0, B_, 128, 1536);

    // ---- refine stages ----
    const float* pred = pts0;
    float* outs[3] = { pts1, pts2, out };
    int Nq = COARSE_;
    for (int s = 0; s < 3; ++s) {
        int srows = B_ * Nq;
        loc_fused_kernel<<<srows / 4, 256, 0, stream>>>(
            coords, pred, st_sw1 + s * 6 * 128, st_sb1 + s * 128, seedh, Nq);
        gemm128_kernel<128, false, false><<<dim3(srows / 8, 1), 256, 0, stream>>>(seedh, st_sw2 + s * 128 * 128, st_sb2 + s * 128, seed, 128, 128);
        gemm128_kernel<128, true, true><<<dim3(srows / 8, 2), 256, 0, stream>>>(seed, st_dw + s * 128 * 256, st_db + s * 128, hb, 256, 256);
        child_kernel<<<cdiv(srows * 6, 256), 256, 0, stream>>>(hb, st_cw + s * 3 * 128, st_cb + s * 3, pred, outs[s], Nq);
        pred = outs[s];
        Nq <<= 1;
    }
}

// Round 19
// 380.745 us; speedup vs baseline: 1.7247x; 1.1095x over previous
//
#include <hip/hip_runtime.h>

// ---------------------------------------------------------------------------
// FullModelSnowflake.  R18: launch-graph collapse — refine tail (seed GEMM +
// convt + child) in one kernel; gcn_agg fused into its consumers; decoder
// dec_w1+dec_w2 fused.  37 -> 28 launches.
// ---------------------------------------------------------------------------

#define B_ 2
#define N_ 1024
#define D_ 128
#define H_ 8
#define DK_ 16
#define L_ 4
#define KG_ 16
#define KLOC_ 8
#define COARSE_ 512
#define AW_ 8            // waves per attention block
#define KSP_ 4           // block-level key splits
#define PREC_ 17         // floats per attention partial (sum + 16 acc)
#define QPL_ 4           // queries per lane

static __device__ __forceinline__ float wave_sum(float v) {
    #pragma unroll
    for (int off = 32; off > 0; off >>= 1) v += __shfl_xor(v, off);
    return v;
}
static __device__ __forceinline__ float half_sum(float v) {
    #pragma unroll
    for (int off = 16; off > 0; off >>= 1) v += __shfl_xor(v, off);
    return v;
}

// ---------------- LDS-staged GEMM body: returns this thread's acc ----------
template <int CIN, bool RELU, bool BIAS_HALF>
static __device__ __forceinline__ float4 gemm_body(
        const float* __restrict__ X, const float* __restrict__ W,
        const float* __restrict__ bias, int wstride, int col0) {
    __shared__ float Xs[8 * CIN];
    __shared__ float Ws[64][128];
    int tid = threadIdx.x;
    int row0 = blockIdx.x * 8;
    constexpr int NX4 = 2 * CIN;
    {
        const float4* xg = (const float4*)(X + (size_t)row0 * CIN);
        float4* xs4 = (float4*)Xs;
        #pragma unroll
        for (int i = 0; i < (NX4 + 255) / 256; ++i) {
            int t = tid + i * 256;
            if ((NX4 % 256 == 0) || t < NX4) xs4[t] = xg[t];
        }
    }
    int col4 = (tid & 31) << 2;
    int rowl = tid >> 5;
    float4 acc;
    if (BIAS_HALF) {
        acc.x = bias[(col0 + col4) >> 1];
        acc.y = bias[(col0 + col4 + 1) >> 1];
        acc.z = bias[(col0 + col4 + 2) >> 1];
        acc.w = bias[(col0 + col4 + 3) >> 1];
    } else {
        acc = *(const float4*)(bias + col0 + col4);
    }
    for (int c0 = 0; c0 < CIN; c0 += 64) {
        __syncthreads();
        #pragma unroll
        for (int i = 0; i < 8; ++i) {
            int flat = tid + i * 256;
            int wr = flat >> 5, wc = (flat & 31) << 2;
            *(float4*)&Ws[wr][wc] =
                *(const float4*)(W + (size_t)(c0 + wr) * wstride + col0 + wc);
        }
        __syncthreads();
        const float* xrow = Xs + rowl * CIN + c0;
        #pragma unroll
        for (int c = 0; c < 64; ++c) {
            float xv = xrow[c];
            float4 w = *(const float4*)&Ws[c][col4];
            acc.x += xv * w.x; acc.y += xv * w.y;
            acc.z += xv * w.z; acc.w += xv * w.w;
        }
    }
    if (RELU) {
        acc.x = fmaxf(acc.x, 0.f); acc.y = fmaxf(acc.y, 0.f);
        acc.z = fmaxf(acc.z, 0.f); acc.w = fmaxf(acc.w, 0.f);
    }
    return acc;
}

template <int CIN, bool RELU, bool BIAS_HALF>
__global__ __launch_bounds__(256) void gemm128_kernel(
        const float* __restrict__ X, const float* __restrict__ W,
        const float* __restrict__ bias, float* __restrict__ Y,
        int wstride, int ystride) {
    int col0 = blockIdx.y * 128;
    float4 acc = gemm_body<CIN, RELU, BIAS_HALF>(X, W, bias, wstride, col0);
    int col4 = (threadIdx.x & 31) << 2;
    int row = blockIdx.x * 8 + (threadIdx.x >> 5);
    *(float4*)(Y + (size_t)row * ystride + col0 + col4) = acc;
}

// GCN layer-2 GEMM: X-stage does the knn gather-average (agg fused).
__global__ __launch_bounds__(256) void gemm_gcn_kernel(
        const float* __restrict__ x64, const int* __restrict__ knn,
        const float* __restrict__ W, const float* __restrict__ bias,
        float* __restrict__ Y) {
    __shared__ float Xs[8 * 64];
    __shared__ float Ws[64][128];
    int tid = threadIdx.x;
    int row0 = blockIdx.x * 8;
    // gather-stage: 512 elements, 2 per thread
    #pragma unroll
    for (int i = 0; i < 2; ++i) {
        int idx = tid + i * 256;
        int r = idx >> 6, c = idx & 63;
        int row = row0 + r;
        int b = row >> 10;
        const int* id = knn + (size_t)row * KG_;
        float val = x64[(size_t)row * 64 + c];
        #pragma unroll
        for (int j = 0; j < KG_; ++j)
            val += x64[((size_t)(b << 10) + id[j]) * 64 + c];
        Xs[idx] = val * (1.0f / (KG_ + 1));
    }
    int col4 = (tid & 31) << 2;
    int rowl = tid >> 5;
    float4 acc = *(const float4*)(bias + col4);
    __syncthreads();
    #pragma unroll
    for (int i = 0; i < 8; ++i) {
        int flat = tid + i * 256;
        int wr = flat >> 5, wc = (flat & 31) << 2;
        *(float4*)&Ws[wr][wc] = *(const float4*)(W + (size_t)wr * 128 + wc);
    }
    __syncthreads();
    const float* xrow = Xs + rowl * 64;
    #pragma unroll
    for (int c = 0; c < 64; ++c) {
        float xv = xrow[c];
        float4 w = *(const float4*)&Ws[c][col4];
        acc.x += xv * w.x; acc.y += xv * w.y;
        acc.z += xv * w.z; acc.w += xv * w.w;
    }
    acc.x = fmaxf(acc.x, 0.f); acc.y = fmaxf(acc.y, 0.f);
    acc.z = fmaxf(acc.z, 0.f); acc.w = fmaxf(acc.w, 0.f);
    int row = row0 + rowl;
    *(float4*)(Y + (size_t)row * 128 + col4) = acc;
}

// GCN layer-1: fused agg(C=3) + linear 3->64 + relu.  4 rows/block.
__global__ __launch_bounds__(256) void gcnlin0_kernel(
        const float* __restrict__ coords, const int* __restrict__ knn,
        const float* __restrict__ w0, const float* __restrict__ b0,
        float* __restrict__ x64) {
    int lane = threadIdx.x & 63;
    int row = blockIdx.x * 4 + (threadIdx.x >> 6);
    int b = row >> 10;
    const float* cb = coords + (size_t)(b << 10) * 3;
    int n = row & (N_ - 1);
    float ax = cb[n * 3], ay = cb[n * 3 + 1], az = cb[n * 3 + 2];
    const int* id = knn + (size_t)row * KG_;
    #pragma unroll
    for (int j = 0; j < KG_; ++j) {
        int m = id[j];
        ax += cb[m * 3]; ay += cb[m * 3 + 1]; az += cb[m * 3 + 2];
    }
    float s = 1.0f / (KG_ + 1);
    ax *= s; ay *= s; az *= s;
    float acc = b0[lane] + ax * w0[lane] + ay * w0[64 + lane] + az * w0[128 + lane];
    x64[(size_t)row * 64 + lane] = fmaxf(acc, 0.f);
}

// GEMM (Cout=128) fused with residual-add + LayerNorm epilogue.
template <int CIN>
__global__ __launch_bounds__(256) void gemm_ln_kernel(
        const float* __restrict__ X, const float* __restrict__ W,
        const float* __restrict__ bias, const float* __restrict__ res,
        const float* __restrict__ g, const float* __restrict__ bt,
        float* __restrict__ Y) {
    float4 acc = gemm_body<CIN, false, false>(X, W, bias, 128, 0);
    int col4 = (threadIdx.x & 31) << 2;
    int row = blockIdx.x * 8 + (threadIdx.x >> 5);
    float4 r = *(const float4*)(res + (size_t)row * D_ + col4);
    acc.x += r.x; acc.y += r.y; acc.z += r.z; acc.w += r.w;
    float mean = half_sum(acc.x + acc.y + acc.z + acc.w) * (1.0f / D_);
    float dx = acc.x - mean, dy = acc.y - mean, dz = acc.z - mean, dw = acc.w - mean;
    float var = half_sum(dx * dx + dy * dy + dz * dz + dw * dw) * (1.0f / D_);
    float rstd = rsqrtf(var + 1e-5f);
    float4 gv = *(const float4*)(g + col4);
    float4 bv = *(const float4*)(bt + col4);
    float4 o;
    o.x = dx * rstd * gv.x + bv.x;
    o.y = dy * rstd * gv.y + bv.y;
    o.z = dz * rstd * gv.z + bv.z;
    o.w = dw * rstd * gv.w + bv.w;
    *(float4*)(Y + (size_t)row * D_ + col4) = o;
}

// FFN1 GEMM with fused attn-final-merge + residual + LN in the X-stage.
__global__ __launch_bounds__(256) void gemm_ffn1_kernel(
        const float* __restrict__ pp, const float* __restrict__ xin,
        const float* __restrict__ g, const float* __restrict__ bt,
        const float* __restrict__ W, const float* __restrict__ bias,
        float* __restrict__ xln, float* __restrict__ Y) {
    __shared__ float Xs[8 * 128];
    __shared__ float Ws[64][128];
    int tid = threadIdx.x;
    int row0 = blockIdx.x * 8;
    int col0 = blockIdx.y * 128;
    int col4 = (tid & 31) << 2;
    int rowl = tid >> 5;
    {
        int row = row0 + rowl;
        int b = row >> 10, n = row & (N_ - 1);
        int h = col4 >> 4, d0 = col4 & 15;
        const float* p = pp + (((size_t)(b * 8 + h) * N_ + n) * KSP_) * PREC_;
        float gsum = 0.f, a0 = 0.f, a1 = 0.f, a2 = 0.f, a3 = 0.f;
        #pragma unroll
        for (int s = 0; s < KSP_; ++s) {
            const float* ps = p + s * PREC_;
            gsum += ps[0];
            a0 += ps[1 + d0]; a1 += ps[2 + d0]; a2 += ps[3 + d0]; a3 += ps[4 + d0];
        }
        float inv = 1.0f / gsum;
        float4 xv = *(const float4*)(xin + (size_t)row * D_ + col4);
        float v0 = a0 * inv + xv.x;
        float v1 = a1 * inv + xv.y;
        float v2 = a2 * inv + xv.z;
        float v3 = a3 * inv + xv.w;
        float mean = half_sum(v0 + v1 + v2 + v3) * (1.0f / D_);
        float dx = v0 - mean, dy = v1 - mean, dz = v2 - mean, dw = v3 - mean;
        float var = half_sum(dx * dx + dy * dy + dz * dz + dw * dw) * (1.0f / D_);
        float rstd = rsqrtf(var + 1e-5f);
        float4 gv = *(const float4*)(g + col4);
        float4 bv = *(const float4*)(bt + col4);
        float4 o;
        o.x = dx * rstd * gv.x + bv.x;
        o.y = dy * rstd * gv.y + bv.y;
        o.z = dz * rstd * gv.z + bv.z;
        o.w = dw * rstd * gv.w + bv.w;
        *(float4*)&Xs[rowl * 128 + col4] = o;
        if (blockIdx.y == 0)
            *(float4*)(xln + (size_t)row * D_ + col4) = o;
    }
    float4 acc = *(const float4*)(bias + col0 + col4);
    for (int c0 = 0; c0 < 128; c0 += 64) {
        __syncthreads();
        #pragma unroll
        for (int i = 0; i < 8; ++i) {
            int flat = tid + i * 256;
            int wr = flat >> 5, wc = (flat & 31) << 2;
            *(float4*)&Ws[wr][wc] =
                *(const float4*)(W + (size_t)(c0 + wr) * 512 + col0 + wc);
        }
        __syncthreads();
        const float* xrow = Xs + rowl * 128 + c0;
        #pragma unroll
        for (int c = 0; c < 64; ++c) {
            float xv = xrow[c];
            float4 w = *(const float4*)&Ws[c][col4];
            acc.x += xv * w.x; acc.y += xv * w.y;
            acc.z += xv * w.z; acc.w += xv * w.w;
        }
    }
    acc.x = fmaxf(acc.x, 0.f); acc.y = fmaxf(acc.y, 0.f);
    acc.z = fmaxf(acc.z, 0.f); acc.w = fmaxf(acc.w, 0.f);
    int row = row0 + rowl;
    *(float4*)(Y + (size_t)row * 512 + col0 + col4) = acc;
}

// fused QKV: 3 W-panels via blockIdx.y; outputs stored HEAD-MAJOR [bh][n][16]
__global__ __launch_bounds__(256) void qkv3_kernel(
        const float* __restrict__ X,
        const float* __restrict__ Wq, const float* __restrict__ bq,
        const float* __restrict__ Wk, const float* __restrict__ bk,
        const float* __restrict__ Wv, const float* __restrict__ bv,
        float* __restrict__ Q, float* __restrict__ K, float* __restrict__ V) {
    const float* W; const float* bias; float* Y;
    if (blockIdx.y == 0)      { W = Wq; bias = bq; Y = Q; }
    else if (blockIdx.y == 1) { W = Wk; bias = bk; Y = K; }
    else                      { W = Wv; bias = bv; Y = V; }
    float4 acc = gemm_body<128, false, false>(X, W, bias, 128, 0);
    int col4 = (threadIdx.x & 31) << 2;
    int row = blockIdx.x * 8 + (threadIdx.x >> 5);
    int b = row >> 10, n = row & (N_ - 1);
    int h = col4 >> 4, d = col4 & 15;
    *(float4*)(Y + (((size_t)(b * 8 + h) * N_ + n) << 4) + d) = acc;
}

// ---------------- single-kernel self-KNN: one wave per query ---------------
__global__ __launch_bounds__(256) void knn_fused_kernel(
        const float* __restrict__ coords, int* __restrict__ knn) {
    __shared__ float4 sc[N_];
    int wid = threadIdx.x >> 6;
    int lane = threadIdx.x & 63;
    size_t q = (size_t)blockIdx.x * 4 + wid;
    int b = (int)(q >> 10), n = (int)(q & (N_ - 1));
    const float* cb = coords + (size_t)b * N_ * 3;
    for (int i = threadIdx.x; i < N_; i += 256) {
        float x = cb[i * 3], y = cb[i * 3 + 1], z = cb[i * 3 + 2];
        sc[i] = make_float4(x, y, z, x * x + y * y + z * z);
    }
    __syncthreads();
    float4 qc = sc[n];
    float qx = qc.x, qy = qc.y, qz = qc.z, q2 = qc.w;
    float ld[16];
    #pragma unroll
    for (int j = 0; j < 16; ++j) {
        int m = (j << 6) | lane;
        float4 c = sc[m];
        float dot = qx * c.x + qy * c.y + qz * c.z;
        float d = (q2 - 2.0f * dot) + c.w;
        ld[j] = (m == n) ? 3e38f : d;
    }
    int* o = knn + q * KG_;
    #pragma unroll
    for (int r = 0; r < KG_; ++r) {
        float dm = ld[0]; int im = lane;
        #pragma unroll
        for (int j = 1; j < 16; ++j) {
            int mj = (j << 6) | lane;
            bool lt = (ld[j] < dm) || (ld[j] == dm && mj < im);
            dm = lt ? ld[j] : dm; im = lt ? mj : im;
        }
        #pragma unroll
        for (int off = 32; off > 0; off >>= 1) {
            float d2 = __shfl_xor(dm, off); int i2 = __shfl_xor(im, off);
            bool lt = (d2 < dm) || (d2 == dm && i2 < im);
            dm = lt ? d2 : dm; im = lt ? i2 : im;
        }
        if (lane == 0) o[r] = im;
        if ((im & 63) == lane) {
            #pragma unroll
            for (int j = 0; j < 16; ++j) if ((im >> 6) == j) ld[j] = 3e38f;
        }
    }
}

// ---------------- single-kernel local-KNN + mean + seed linear -------------
__global__ __launch_bounds__(256) void loc_fused_kernel(
        const float* __restrict__ part, const float* __restrict__ pred,
        const float* __restrict__ sw1, const float* __restrict__ sb1,
        float* __restrict__ seedh, int Nq) {
    __shared__ float4 sc[N_];
    int wid = threadIdx.x >> 6;
    int lane = threadIdx.x & 63;
    size_t q = (size_t)blockIdx.x * 4 + wid;
    int b = (int)(q / Nq);
    const float* pb = part + (size_t)b * N_ * 3;
    for (int i = threadIdx.x; i < N_; i += 256) {
        float x = pb[i * 3], y = pb[i * 3 + 1], z = pb[i * 3 + 2];
        sc[i] = make_float4(x, y, z, x * x + y * y + z * z);
    }
    __syncthreads();
    const float* pr = pred + q * 3;
    float qx = pr[0], qy = pr[1], qz = pr[2];
    float q2 = qx * qx + qy * qy + qz * qz;
    float ld[16];
    #pragma unroll
    for (int j = 0; j < 16; ++j) {
        int m = (j << 6) | lane;
        float4 c = sc[m];
        float dot = qx * c.x + qy * c.y + qz * c.z;
        ld[j] = (q2 - 2.0f * dot) + c.w;
    }
    float sx = 0.f, sy = 0.f, sz = 0.f;
    #pragma unroll
    for (int r = 0; r < KLOC_; ++r) {
        float dm = ld[0]; int im = lane;
        #pragma unroll
        for (int j = 1; j < 16; ++j) {
            int mj = (j << 6) | lane;
            bool lt = (ld[j] < dm) || (ld[j] == dm && mj < im);
            dm = lt ? ld[j] : dm; im = lt ? mj : im;
        }
        #pragma unroll
        for (int off = 32; off > 0; off >>= 1) {
            float d2 = __shfl_xor(dm, off); int i2 = __shfl_xor(im, off);
            bool lt = (d2 < dm) || (d2 == dm && i2 < im);
            dm = lt ? d2 : dm; im = lt ? i2 : im;
        }
        float4 w = sc[im];               // broadcast
        sx += w.x; sy += w.y; sz += w.z;
        if ((im & 63) == lane) {
            #pragma unroll
            for (int j = 0; j < 16; ++j) if ((im >> 6) == j) ld[j] = 3e38f;
        }
    }
    float comb[6];
    comb[0] = qx; comb[1] = qy; comb[2] = qz;
    comb[3] = sx * (1.0f / KLOC_);
    comb[4] = sy * (1.0f / KLOC_);
    comb[5] = sz * (1.0f / KLOC_);
    float* so = seedh + q * 128;
    #pragma unroll
    for (int half = 0; half < 2; ++half) {
        int c = lane + half * 64;
        float acc = sb1[c];
        #pragma unroll
        for (int i = 0; i < 6; ++i) acc += comb[i] * sw1[i * 128 + c];
        so[c] = fmaxf(acc, 0.f);
    }
}

// ---------------- refine tail: seed GEMM + convt + child in one kernel -----
// Block = 8 rows.  Phase1: seedh @ sw2 -> Sd (LDS).  Phase2: Sd @ dw (+db,
// relu) -> Hb (LDS, 256 cols via 2 panels).  Phase3: child from Hb.
__global__ __launch_bounds__(256) void refine_tail_kernel(
        const float* __restrict__ seedh,
        const float* __restrict__ sw2, const float* __restrict__ sb2,
        const float* __restrict__ dw, const float* __restrict__ db,
        const float* __restrict__ cw, const float* __restrict__ cb,
        const float* __restrict__ pred, float* __restrict__ outp) {
    __shared__ float Xs[8 * 128];
    __shared__ float Ws[64][128];
    __shared__ float Sd[8 * 128];
    __shared__ float Hb[8 * 256];
    int tid = threadIdx.x;
    int row0 = blockIdx.x * 8;
    int col4 = (tid & 31) << 2;
    int rowl = tid >> 5;
    // stage seedh rows
    {
        const float4* xg = (const float4*)(seedh + (size_t)row0 * 128);
        float4* xs4 = (float4*)Xs;
        xs4[tid] = xg[tid];
    }
    // phase 1: seed = seedh @ sw2 + sb2
    float4 acc = *(const float4*)(sb2 + col4);
    for (int c0 = 0; c0 < 128; c0 += 64) {
        __syncthreads();
        #pragma unroll
        for (int i = 0; i < 8; ++i) {
            int flat = tid + i * 256;
            int wr = flat >> 5, wc = (flat & 31) << 2;
            *(float4*)&Ws[wr][wc] =
                *(const float4*)(sw2 + (size_t)(c0 + wr) * 128 + wc);
        }
        __syncthreads();
        const float* xrow = Xs + rowl * 128 + c0;
        #pragma unroll
        for (int c = 0; c < 64; ++c) {
            float xv = xrow[c];
            float4 w = *(const float4*)&Ws[c][col4];
            acc.x += xv * w.x; acc.y += xv * w.y;
            acc.z += xv * w.z; acc.w += xv * w.w;
        }
    }
    __syncthreads();
    *(float4*)&Sd[rowl * 128 + col4] = acc;
    // phase 2: hb = relu(seed @ dw + db_half), 256 cols via 2 panels
    #pragma unroll
    for (int panel = 0; panel < 2; ++panel) {
        int col0 = panel * 128;
        float4 a2;
        a2.x = db[(col0 + col4) >> 1];
        a2.y = db[(col0 + col4 + 1) >> 1];
        a2.z = db[(col0 + col4 + 2) >> 1];
        a2.w = db[(col0 + col4 + 3) >> 1];
        for (int c0 = 0; c0 < 128; c0 += 64) {
            __syncthreads();
            #pragma unroll
            for (int i = 0; i < 8; ++i) {
                int flat = tid + i * 256;
                int wr = flat >> 5, wc = (flat & 31) << 2;
                *(float4*)&Ws[wr][wc] =
                    *(const float4*)(dw + (size_t)(c0 + wr) * 256 + col0 + wc);
            }
            __syncthreads();
            const float* xrow = Sd + rowl * 128 + c0;
            #pragma unroll
            for (int c = 0; c < 64; ++c) {
                float xv = xrow[c];
                float4 w = *(const float4*)&Ws[c][col4];
                a2.x += xv * w.x; a2.y += xv * w.y;
                a2.z += xv * w.z; a2.w += xv * w.w;
            }
        }
        a2.x = fmaxf(a2.x, 0.f); a2.y = fmaxf(a2.y, 0.f);
        a2.z = fmaxf(a2.z, 0.f); a2.w = fmaxf(a2.w, 0.f);
        __syncthreads();
        *(float4*)&Hb[rowl * 256 + col0 + col4] = a2;
    }
    __syncthreads();
    // phase 3: child = pred + Hb[o*2+t] . cw[p][o]   (48 outputs)
    if (tid < 48) {
        int r = tid / 6, rem = tid % 6;
        int t = rem / 3, p = rem % 3;
        const float* hr = Hb + r * 256;
        float a = cb[p];
        #pragma unroll 4
        for (int o = 0; o < 128; ++o) a += hr[o * 2 + t] * cw[p * 128 + o];
        size_t row = row0 + r;
        outp[row * 6 + t * 3 + p] = pred[row * 3 + p] + a;
    }
}

// ---------------- decoder: dec_w1 + dec_w2 fused ---------------------------
// 12 blocks: row = blk/6, 256-col slice of pts0 = (blk%6)*256.
__global__ __launch_bounds__(256) void dec12_kernel(
        const float* __restrict__ gc,
        const float* __restrict__ w1, const float* __restrict__ b1,
        const float* __restrict__ w2, const float* __restrict__ b2,
        float* __restrict__ pts0) {
    __shared__ float gcs[128];
    __shared__ float dech[128];
    int tid = threadIdx.x;
    int row = blockIdx.x / 6;
    int colb = (blockIdx.x % 6) * 256;
    if (tid < 128) gcs[tid] = gc[row * 128 + tid];
    __syncthreads();
    if (tid < 128) {
        float a = b1[tid];
        #pragma unroll 4
        for (int c = 0; c < 128; ++c) a += gcs[c] * w1[c * 128 + tid];
        dech[tid] = fmaxf(a, 0.f);
    }
    __syncthreads();
    int col = colb + tid;
    float a = b2[col];
    #pragma unroll 4
    for (int c = 0; c < 128; ++c) a += dech[c] * w2[(size_t)c * 1536 + col];
    pts0[(size_t)row * 1536 + col] = a;
}

// ---------------- attention: 4 queries/lane, LDS-staged K/V ----------------
__global__ __launch_bounds__(512) void attn_part(
        const float* __restrict__ q,
        const float* __restrict__ k,
        const float* __restrict__ v,
        const float* __restrict__ coords,
        const float* __restrict__ alphap, int layer,
        float* __restrict__ pp) {
    __shared__ float smem[10304];    // stage 8192 | merge: ssum 2048 + sacc 8256
    float* kst = smem;               // [256][16]
    float* vst = smem + 4096;        // [256][16]
    float* ssum = smem;              // [8][256]   (merge phase)
    float* sacc = smem + 2048;       // [64][129]
    int bh = blockIdx.x & 15;        // b*8 + h
    int t = blockIdx.x >> 4;         // nb*KSP + ks
    int ks = t & (KSP_ - 1);
    int nb = t >> 2;                 // [0, 4)
    int b = bh >> 3;
    int wid = threadIdx.x >> 6;
    int lane = threadIdx.x & 63;
    float alpha = alphap[layer];
    {
        const float4* kg = (const float4*)(k + (((size_t)bh * N_ + ks * 256) << 4));
        const float4* vg = (const float4*)(v + (((size_t)bh * N_ + ks * 256) << 4));
        float4* ks4 = (float4*)kst;
        float4* vs4 = (float4*)vst;
        #pragma unroll
        for (int i = 0; i < 2; ++i) {
            int idx = threadIdx.x + i * 512;
            ks4[idx] = kg[idx];
            vs4[idx] = vg[idx];
        }
    }
    int n0 = nb * 256 + lane;        // queries n0 + u*64, u=0..3
    const float* cb = coords + (size_t)b * N_ * 3;
    float qv[QPL_][DK_];
    float cx[QPL_], cy[QPL_], cz[QPL_];
    #pragma unroll
    for (int u = 0; u < QPL_; ++u) {
        const float* qp = q + (((size_t)bh * N_ + n0 + u * 64) << 4);
        #pragma unroll
        for (int d = 0; d < DK_; ++d) qv[u][d] = qp[d];
        int nn = n0 + u * 64;
        cx[u] = cb[nn * 3]; cy[u] = cb[nn * 3 + 1]; cz[u] = cb[nn * 3 + 2];
    }
    float sm[QPL_];
    float acc[QPL_][DK_];
    #pragma unroll
    for (int u = 0; u < QPL_; ++u) {
        sm[u] = 0.f;
        #pragma unroll
        for (int d = 0; d < DK_; ++d) acc[u][d] = 0.f;
    }
    __syncthreads();                 // stage visible
    int mbase = ks * 256 + wid * 32;
    int lbase = wid * 32;
    #pragma unroll 2
    for (int j = 0; j < 32; ++j) {
        float kk[16];
        {
            const float4* kr = (const float4*)(kst + ((lbase + j) << 4));
            *(float4*)&kk[0] = kr[0]; *(float4*)&kk[4] = kr[1];
            *(float4*)&kk[8] = kr[2]; *(float4*)&kk[12] = kr[3];
        }
        int m = mbase + j;
        float wx = cb[m * 3], wy = cb[m * 3 + 1], wz = cb[m * 3 + 2];
        float p[QPL_];
        #pragma unroll
        for (int u = 0; u < QPL_; ++u) {
            float dot = 0.f;
            #pragma unroll
            for (int d = 0; d < DK_; ++d) dot += qv[u][d] * kk[d];
            p[u] = __expf(dot * 0.25f + alpha * (wx * cx[u] + wy * cy[u] + wz * cz[u]));
            sm[u] += p[u];
        }
        float vv[16];
        {
            const float4* vr = (const float4*)(vst + ((lbase + j) << 4));
            *(float4*)&vv[0] = vr[0]; *(float4*)&vv[4] = vr[1];
            *(float4*)&vv[8] = vr[2]; *(float4*)&vv[12] = vr[3];
        }
        #pragma unroll
        for (int u = 0; u < QPL_; ++u)
            #pragma unroll
            for (int d = 0; d < DK_; ++d) acc[u][d] += p[u] * vv[d];
    }
    __syncthreads();                 // done reading stage
    #pragma unroll
    for (int u = 0; u < QPL_; ++u) ssum[wid * 256 + u * 64 + lane] = sm[u];
    int qi = threadIdx.x & 63;
    int dq = threadIdx.x >> 6;       // 0..7, 2 d's each
    #pragma unroll
    for (int r = 0; r < QPL_; ++r) {
        #pragma unroll
        for (int d = 0; d < DK_; ++d) sacc[lane * 129 + wid * DK_ + d] = acc[r][d];
        __syncthreads();
        int n = nb * 256 + r * 64 + qi;
        float* o = pp + (((size_t)bh * N_ + n) * KSP_ + ks) * PREC_;
        if (dq == 0) {
            float gsum = 0.f;
            #pragma unroll
            for (int w = 0; w < AW_; ++w) gsum += ssum[w * 256 + r * 64 + qi];
            o[0] = gsum;
        }
        #pragma unroll
        for (int dd = 0; dd < 2; ++dd) {
            int d = dq * 2 + dd;
            float a = 0.f;
            #pragma unroll
            for (int w = 0; w < AW_; ++w) a += sacc[qi * 129 + w * DK_ + d];
            o[1 + d] = a;
        }
        __syncthreads();
    }
}

// ---------------- column mean over N (global feature) ----------------------
__global__ void colmean_kernel(const float* __restrict__ x,
                               float* __restrict__ gc) {
    int b = blockIdx.x;
    int d = threadIdx.x & 127;
    int sl = threadIdx.x >> 7;
    __shared__ float part[4][128];
    float s = 0.f;
    const float* xb = x + (size_t)b * N_ * D_;
    for (int n = sl * 256; n < sl * 256 + 256; ++n) s += xb[(size_t)n * D_ + d];
    part[sl][d] = s;
    __syncthreads();
    if (sl == 0)
        gc[b * D_ + d] = (part[0][d] + part[1][d] + part[2][d] + part[3][d]) * (1.0f / N_);
}

// ---------------------------------------------------------------------------
static inline int cdiv(int a, int b) { return (a + b - 1) / b; }

extern "C" void kernel_launch(void* const* d_in, const int* in_sizes, int n_in,
                              void* d_out, int out_size, void* d_ws, size_t ws_size,
                              hipStream_t stream) {
    (void)in_sizes; (void)n_in; (void)out_size; (void)ws_size;
    const float* coords = (const float*)d_in[0];
    const float* gcn_w0 = (const float*)d_in[1];
    const float* gcn_b0 = (const float*)d_in[2];
    const float* gcn_w1 = (const float*)d_in[3];
    const float* gcn_b1 = (const float*)d_in[4];
    const float* enc_fw = (const float*)d_in[5];
    const float* enc_fb = (const float*)d_in[6];
    const float* t_wq   = (const float*)d_in[7];
    const float* t_bq   = (const float*)d_in[8];
    const float* t_wk   = (const float*)d_in[9];
    const float* t_bk   = (const float*)d_in[10];
    const float* t_wv   = (const float*)d_in[11];
    const float* t_bv   = (const float*)d_in[12];
    const float* t_alpha= (const float*)d_in[13];
    const float* t_f1w  = (const float*)d_in[14];
    const float* t_f1b  = (const float*)d_in[15];
    const float* t_f2w  = (const float*)d_in[16];
    const float* t_f2b  = (const float*)d_in[17];
    const float* t_ln1g = (const float*)d_in[18];
    const float* t_ln1b = (const float*)d_in[19];
    const float* t_ln2g = (const float*)d_in[20];
    const float* t_ln2b = (const float*)d_in[21];
    const float* dec_w1 = (const float*)d_in[22];
    const float* dec_b1 = (const float*)d_in[23];
    const float* dec_w2 = (const float*)d_in[24];
    const float* dec_b2 = (const float*)d_in[25];
    const float* st_sw1 = (const float*)d_in[26];
    const float* st_sb1 = (const float*)d_in[27];
    const float* st_sw2 = (const float*)d_in[28];
    const float* st_sb2 = (const float*)d_in[29];
    const float* st_dw  = (const float*)d_in[30];
    const float* st_db  = (const float*)d_in[31];
    const float* st_cw  = (const float*)d_in[32];
    const float* st_cb  = (const float*)d_in[33];
    float* out = (float*)d_out;

    // ---- workspace carve ----
    char* ws = (char*)d_ws;
    size_t off = 0;
    auto alloc = [&](size_t bytes) -> void* {
        void* p = ws + off;
        off += (bytes + 255) & ~(size_t)255;
        return p;
    };
    int*   knn   = (int*)  alloc((size_t)B_ * N_ * KG_ * 4);
    float* app   = (float*)alloc((size_t)B_ * H_ * N_ * KSP_ * PREC_ * 4);
    float* x64   = (float*)alloc((size_t)B_ * N_ * 64 * 4);
    float* xb    = (float*)alloc((size_t)B_ * N_ * D_ * 4);
    float* x     = (float*)alloc((size_t)B_ * N_ * D_ * 4);
    float* q     = (float*)alloc((size_t)B_ * N_ * D_ * 4);
    float* k     = (float*)alloc((size_t)B_ * N_ * D_ * 4);
    float* v     = (float*)alloc((size_t)B_ * N_ * D_ * 4);
    float* ffh   = (float*)alloc((size_t)B_ * N_ * 512 * 4);
    float* gc    = (float*)alloc((size_t)B_ * D_ * 4);
    float* pts0  = (float*)alloc((size_t)B_ * COARSE_ * 3 * 4);
    float* pts1  = (float*)alloc((size_t)B_ * 1024 * 3 * 4);
    float* pts2  = (float*)alloc((size_t)B_ * 2048 * 3 * 4);
    float* seedh = (float*)alloc((size_t)B_ * 2048 * 128 * 4);

    const int rows = B_ * N_;   // 2048

    // ---- graph encoder ----
    knn_fused_kernel<<<rows / 4, 256, 0, stream>>>(coords, knn);
    gcnlin0_kernel<<<rows / 4, 256, 0, stream>>>(coords, knn, gcn_w0, gcn_b0, x64);
    gemm_gcn_kernel<<<rows / 8, 256, 0, stream>>>(x64, knn, gcn_w1, gcn_b1, xb);
    gemm128_kernel<128, false, false><<<dim3(rows / 8, 1), 256, 0, stream>>>(xb, enc_fw, enc_fb, x, 128, 128);

    // ---- transformer ----
    for (int i = 0; i < L_; ++i) {
        qkv3_kernel<<<dim3(rows / 8, 3), 256, 0, stream>>>(
            x, t_wq + i * 16384, t_bq + i * 128, t_wk + i * 16384, t_bk + i * 128,
            t_wv + i * 16384, t_bv + i * 128, q, k, v);
        attn_part<<<B_ * H_ * (N_ / 256) * KSP_, 512, 0, stream>>>(q, k, v, coords, t_alpha, i, app);
        gemm_ffn1_kernel<<<dim3(rows / 8, 4), 256, 0, stream>>>(
            app, x, t_ln1g + i * 128, t_ln1b + i * 128,
            t_f1w + i * 128 * 512, t_f1b + i * 512, xb, ffh);
        gemm_ln_kernel<512><<<rows / 8, 256, 0, stream>>>(ffh, t_f2w + i * 512 * 128, t_f2b + i * 128, xb, t_ln2g + i * 128, t_ln2b + i * 128, x);
    }

    // ---- decoder coarse ----
    colmean_kernel<<<B_, 512, 0, stream>>>(x, gc);
    dec12_kernel<<<12, 256, 0, stream>>>(gc, dec_w1, dec_b1, dec_w2, dec_b2, pts0);

    // ---- refine stages ----
    const float* pred = pts0;
    float* outs[3] = { pts1, pts2, out };
    int Nq = COARSE_;
    for (int s = 0; s < 3; ++s) {
        int srows = B_ * Nq;
        loc_fused_kernel<<<srows / 4, 256, 0, stream>>>(
            coords, pred, st_sw1 + s * 6 * 128, st_sb1 + s * 128, seedh, Nq);
        refine_tail_kernel<<<srows / 8, 256, 0, stream>>>(
            seedh, st_sw2 + s * 128 * 128, st_sb2 + s * 128,
            st_dw + s * 128 * 256, st_db + s * 128,
            st_cw + s * 3 * 128, st_cb + s * 3, pred, outs[s]);
        pred = outs[s];
        Nq <<= 1;
    }
}